// Round 1
// baseline (2004.469 us; speedup 1.0000x reference)
//
#include <hip/hip_runtime.h>
#include <stdint.h>

// ---- problem constants ----
#define B_   4
#define L_   2048
#define DM   1024
#define DIN  2048
#define NH   32
#define HD   64
#define DSTATE 64
#define DCONV  7
#define CONV_DIM 2176            // DIN + 2*DSTATE
#define DPROJ 4288               // 2*DIN + 2*DSTATE + 2*NH
#define NPAD 4352                // DPROJ padded to 128
#define BL   8192                // B_*L_
#define EPS  1e-5f

typedef unsigned short u16;
typedef unsigned int   u32;
typedef __bf16 bf16x8 __attribute__((ext_vector_type(8)));
typedef float  f32x4  __attribute__((ext_vector_type(4)));

__device__ __forceinline__ float b2f(u32 b) { return __uint_as_float(b << 16); }
__device__ __forceinline__ u16 f2b(float f) {
    u32 u = __float_as_uint(f);
    u32 r = (u + 0x7fffu + ((u >> 16) & 1u)) >> 16;
    return (u16)r;
}
__device__ __forceinline__ void unpack8(uint4 v, float* f) {
    f[0] = b2f(v.x & 0xffffu); f[1] = b2f(v.x >> 16);
    f[2] = b2f(v.y & 0xffffu); f[3] = b2f(v.y >> 16);
    f[4] = b2f(v.z & 0xffffu); f[5] = b2f(v.z >> 16);
    f[6] = b2f(v.w & 0xffffu); f[7] = b2f(v.w >> 16);
}
__device__ __forceinline__ uint4 pack8(const float* f) {
    uint4 v;
    v.x = (u32)f2b(f[0]) | ((u32)f2b(f[1]) << 16);
    v.y = (u32)f2b(f[2]) | ((u32)f2b(f[3]) << 16);
    v.z = (u32)f2b(f[4]) | ((u32)f2b(f[5]) << 16);
    v.w = (u32)f2b(f[6]) | ((u32)f2b(f[7]) << 16);
    return v;
}

// ---------- weight conversion ----------
__global__ __launch_bounds__(256) void k_cvt_win(const float* __restrict__ W, u16* __restrict__ Wb) {
    int idx = blockIdx.x * 256 + threadIdx.x;      // over NPAD*DM
    int n = idx >> 10;                              // DM = 1024
    float v = (n < DPROJ) ? W[(size_t)n * DM + (idx & 1023)] : 0.f;
    Wb[idx] = f2b(v);
}
__global__ __launch_bounds__(256) void k_cvt_wout(const float* __restrict__ W, u16* __restrict__ Wb) {
    int idx = blockIdx.x * 256 + threadIdx.x;      // over DM*DIN
    Wb[idx] = f2b(W[idx]);
}

// ---------- layernorm -> bf16 ----------
__global__ __launch_bounds__(256) void k_ln(const float* __restrict__ x, const float* __restrict__ g,
                                            const float* __restrict__ be, u16* __restrict__ u) {
    int row = blockIdx.x, tid = threadIdx.x;
    const float4* xr = (const float4*)(x + (size_t)row * DM);
    float4 v = xr[tid];
    float s1 = v.x + v.y + v.z + v.w;
    float s2 = v.x * v.x + v.y * v.y + v.z * v.z + v.w * v.w;
    for (int o = 32; o; o >>= 1) { s1 += __shfl_down(s1, o); s2 += __shfl_down(s2, o); }
    __shared__ float ls1[4], ls2[4];
    int w = tid >> 6;
    if ((tid & 63) == 0) { ls1[w] = s1; ls2[w] = s2; }
    __syncthreads();
    float t1 = ls1[0] + ls1[1] + ls1[2] + ls1[3];
    float t2 = ls2[0] + ls2[1] + ls2[2] + ls2[3];
    float mu = t1 * (1.f / DM);
    float var = t2 * (1.f / DM) - mu * mu;
    float rs = rsqrtf(var + EPS);
    float4 gv = ((const float4*)g)[tid];
    float4 bv = ((const float4*)be)[tid];
    float o0 = (v.x - mu) * rs * gv.x + bv.x;
    float o1 = (v.y - mu) * rs * gv.y + bv.y;
    float o2 = (v.z - mu) * rs * gv.z + bv.z;
    float o3 = (v.w - mu) * rs * gv.w + bv.w;
    uint2 p;
    p.x = (u32)f2b(o0) | ((u32)f2b(o1) << 16);
    p.y = (u32)f2b(o2) | ((u32)f2b(o3) << 16);
    ((uint2*)(u + (size_t)row * DM))[tid] = p;
}

// ---------- bf16 MFMA GEMM, C[m,n] = sum_k A[m,k]*B[n,k]  (B^T layout) ----------
// out_bf16: write bf16 to obf (ldo); else fp32 ofp = acc + res
__global__ __launch_bounds__(256) void k_gemm_bt(const u16* __restrict__ A, const u16* __restrict__ Bw,
                                                 int M, int N, int K, int out_bf16,
                                                 u16* __restrict__ obf, int ldo,
                                                 float* __restrict__ ofp, const float* __restrict__ res) {
    __shared__ __align__(16) u16 As[128 * 32];
    __shared__ __align__(16) u16 Bs[128 * 32];
    int tid = threadIdx.x;
    int m0 = blockIdx.y * 128, n0 = blockIdx.x * 128;
    int w = tid >> 6, lane = tid & 63;
    int wm = (w >> 1) * 64, wn = (w & 1) * 64;
    int lr = lane & 15, lq = lane >> 4;

    f32x4 acc[4][4];
    #pragma unroll
    for (int i = 0; i < 4; i++)
        #pragma unroll
        for (int j = 0; j < 4; j++) acc[i][j] = (f32x4){0.f, 0.f, 0.f, 0.f};

    for (int kt = 0; kt < K; kt += 32) {
        #pragma unroll
        for (int it = 0; it < 2; it++) {
            int chunk = tid + it * 256;
            int r = chunk >> 2, kc = chunk & 3;
            ((uint4*)As)[chunk] = *(const uint4*)(A + (size_t)(m0 + r) * K + kt + kc * 8);
            ((uint4*)Bs)[chunk] = *(const uint4*)(Bw + (size_t)(n0 + r) * K + kt + kc * 8);
        }
        __syncthreads();
        bf16x8 af[4], bfr[4];
        #pragma unroll
        for (int i = 0; i < 4; i++) af[i] = *(const bf16x8*)&As[(wm + 16 * i + lr) * 32 + lq * 8];
        #pragma unroll
        for (int j = 0; j < 4; j++) bfr[j] = *(const bf16x8*)&Bs[(wn + 16 * j + lr) * 32 + lq * 8];
        #pragma unroll
        for (int i = 0; i < 4; i++)
            #pragma unroll
            for (int j = 0; j < 4; j++)
                acc[i][j] = __builtin_amdgcn_mfma_f32_16x16x32_bf16(af[i], bfr[j], acc[i][j], 0, 0, 0);
        __syncthreads();
    }
    // epilogue: C/D layout col=lane&15, row=lq*4+r  [verified m89]
    #pragma unroll
    for (int i = 0; i < 4; i++) {
        #pragma unroll
        for (int j = 0; j < 4; j++) {
            #pragma unroll
            for (int r = 0; r < 4; r++) {
                int m = m0 + wm + 16 * i + lq * 4 + r;
                int n = n0 + wn + 16 * j + lr;
                float v = acc[i][j][r];
                if (out_bf16) obf[(size_t)m * ldo + n] = f2b(v);
                else          ofp[(size_t)m * ldo + n] = v + res[(size_t)m * ldo + n];
            }
        }
    }
}

// ---------- depthwise conv7 (same-pad) + bias + SiLU, split xs / BC ----------
__global__ __launch_bounds__(256) void k_conv(const u16* __restrict__ zx, const float* __restrict__ cw,
                                              const float* __restrict__ cb, u16* __restrict__ xs,
                                              float* __restrict__ BC) {
    __shared__ u16 sh[262 * 64];
    int c0 = blockIdx.x * 64, t0 = blockIdx.y * 256, b = blockIdx.z;
    int tid = threadIdx.x;
    int c = tid & 63, tg = tid >> 6;
    for (int it = 0; it < 66; it++) {
        int r = it * 4 + tg;
        if (r < 262) {
            int t = t0 + r - 3;
            u16 v = 0;
            if (t >= 0 && t < L_) v = zx[(size_t)(b * L_ + t) * NPAD + DIN + c0 + c];
            sh[r * 64 + c] = v;
        }
    }
    float wgt[7];
    #pragma unroll
    for (int k = 0; k < 7; k++) wgt[k] = cw[(c0 + c) * 7 + k];
    float bias = cb[c0 + c];
    __syncthreads();
    int cg = c0 + c;
    for (int tt = 0; tt < 64; tt++) {
        int tl = tt * 4 + tg;
        float a = bias;
        #pragma unroll
        for (int k = 0; k < 7; k++) a += b2f(sh[(tl + k) * 64 + c]) * wgt[k];
        float v = a / (1.f + __expf(-a));   // silu
        size_t row = (size_t)b * L_ + (t0 + tl);
        if (cg < DIN) xs[row * DIN + cg] = f2b(v);
        else          BC[row * 128 + (cg - DIN)] = v;   // B at [0,64), C at [64,128)
    }
}

// ---------- dt2/dA precompute ----------
__global__ __launch_bounds__(256) void k_dt(const u16* __restrict__ zx, const float* __restrict__ dt_bias,
                                            const float* __restrict__ A_log, float* __restrict__ dtA) {
    int idx = blockIdx.x * 256 + threadIdx.x;   // over BL*64
    int row = idx >> 6, j = idx & 63;
    float draw = b2f(zx[(size_t)row * NPAD + (DIN + CONV_DIM) + j]);
    float xb = draw + dt_bias[j & 31];
    float dt2 = (xb > 20.f) ? xb : log1pf(__expf(xb));
    float dA = __expf(-__expf(A_log[j & 31]) * dt2);
    dtA[(size_t)idx * 2]     = dt2;
    dtA[(size_t)idx * 2 + 1] = dA;
}

// ---------- bidirectional selective scan ----------
// block = (dir, b, h); 4 waves each own 16 states of n; lane = p (HEADDIM)
__global__ __launch_bounds__(256) void k_scan(const u16* __restrict__ xs, const float* __restrict__ BC,
                                              const float* __restrict__ dtA,
                                              u16* __restrict__ y0, u16* __restrict__ y1) {
    int blk = blockIdx.x;
    int dir = blk >> 7, b = (blk >> 5) & 3, hh = blk & 31;
    int tid = threadIdx.x, w = tid >> 6, lane = tid & 63;
    int nc0 = w * 16;
    u16* yo = dir ? y1 : y0;
    float hs[16];
    #pragma unroll
    for (int j = 0; j < 16; j++) hs[j] = 0.f;
    __shared__ float yred[256];
    float yprev = 0.f;
    const size_t brow = (size_t)b * L_;
    const int dth = (dir * 32 + hh) * 2;
    const int xoff = hh * 64 + lane;

    int t = dir ? (L_ - 1) : 0;
    float xp = b2f(xs[(brow + t) * DIN + xoff]);
    for (int s = 0; s < L_; s++) {
        size_t row = brow + t;
        int tn = dir ? (L_ - 2 - s) : (s + 1);
        float xpn = 0.f;
        if (s < L_ - 1) xpn = b2f(xs[(brow + tn) * DIN + xoff]);  // prefetch next x
        float dt2 = dtA[row * 128 + dth];
        float dA  = dtA[row * 128 + dth + 1];
        const float* bc = BC + row * 128 + nc0;
        float cxc = dt2 * xp;
        float yp = 0.f;
        #pragma unroll
        for (int j = 0; j < 16; j++) {
            hs[j] = dA * hs[j] + cxc * bc[j];
            yp += hs[j] * bc[64 + j];
        }
        yred[lane * 4 + w] = yp;
        __syncthreads();
        if (w == 0) {
            float4 p4 = *(const float4*)&yred[lane * 4];
            float ycur = p4.x + p4.y + p4.z + p4.w;
            u16 val = f2b((s == 0) ? 0.f : yprev);   // y shifted by one step; s==0 writes the zero row
            yo[row * DIN + xoff] = val;
            yprev = ycur;
        }
        __syncthreads();
        t = tn; xp = xpn;
    }
}

// ---------- D-proj + gate + RMSNorm -> bf16 ----------
__global__ __launch_bounds__(256) void k_gate(const u16* __restrict__ xs, const u16* __restrict__ zx,
                                              const u16* __restrict__ y0, const u16* __restrict__ y1,
                                              const float* __restrict__ fcw, const float* __restrict__ Dv,
                                              const float* __restrict__ nw, u16* __restrict__ yn) {
    int row = blockIdx.x, tid = threadIdx.x;
    __shared__ float xsl[DIN];
    __shared__ float sD[NH];
    __shared__ float red[4];
    size_t base = (size_t)row * DIN;
    uint4 xv = ((const uint4*)(xs + base))[tid];
    float xf[8]; unpack8(xv, xf);
    #pragma unroll
    for (int i = 0; i < 8; i++) xsl[tid * 8 + i] = xf[i];
    __syncthreads();
    // Ddata[h] = dot(xs_row, fc_D_w[h]) + D[h] : 8 threads per head
    int hh = tid >> 3, gs = tid & 7;
    const float* fr = fcw + (size_t)hh * DIN;
    float part = 0.f;
    for (int k = gs; k < DIN; k += 8) part += xsl[k] * fr[k];
    part += __shfl_down(part, 4);
    part += __shfl_down(part, 2);
    part += __shfl_down(part, 1);
    if (gs == 0) sD[hh] = part + Dv[hh];
    __syncthreads();

    uint4 zv = ((const uint4*)(zx + (size_t)row * NPAD))[tid];   // z = cols [0,DIN)
    uint4 a0 = ((const uint4*)(y0 + base))[tid];
    uint4 a1 = ((const uint4*)(y1 + base))[tid];
    float zf[8], f0[8], f1[8];
    unpack8(zv, zf); unpack8(a0, f0); unpack8(a1, f1);
    int d0 = tid * 8;
    float g[8]; float ss = 0.f;
    #pragma unroll
    for (int i = 0; i < 8; i++) {
        float yv = f0[i] + f1[i] + xf[i] * sD[(d0 + i) >> 6];
        float z = zf[i];
        float gg = yv * (z / (1.f + __expf(-z)));
        g[i] = gg; ss += gg * gg;
    }
    for (int o = 32; o; o >>= 1) ss += __shfl_down(ss, o);
    if ((tid & 63) == 0) red[tid >> 6] = ss;
    __syncthreads();
    float tot = red[0] + red[1] + red[2] + red[3];
    float r = rsqrtf(tot * (1.f / DIN) + EPS);
    float o8[8];
    #pragma unroll
    for (int i = 0; i < 8; i++) o8[i] = g[i] * r * nw[d0 + i];
    ((uint4*)(yn + base))[tid] = pack8(o8);
}

// ---------- workspace layout (bytes) ----------
#define OFF_U     ((size_t)0)                       // BL*DM bf16        = 16,777,216
#define OFF_WIN   ((size_t)16777216)                // NPAD*DM bf16      =  8,912,896
#define OFF_WOUT  ((size_t)25690112)                // DM*DIN bf16       =  4,194,304
#define OFF_ZX    ((size_t)29884416)                // BL*NPAD bf16      = 71,303,168
#define OFF_XS    ((size_t)101187584)               // BL*DIN bf16       = 33,554,432
#define OFF_BC    ((size_t)134742016)               // BL*128 f32        =  4,194,304
#define OFF_DTA   ((size_t)138936320)               // BL*64*2 f32       =  4,194,304
#define OFF_Y0    ((size_t)143130624)               // BL*DIN bf16       = 33,554,432
#define OFF_Y1    ((size_t)176685056)               // BL*DIN bf16       = 33,554,432
#define OFF_YN    ((size_t)210239488)               // BL*DIN bf16       = 33,554,432
// total 243,793,920 bytes

extern "C" void kernel_launch(void* const* d_in, const int* in_sizes, int n_in,
                              void* d_out, int out_size, void* d_ws, size_t ws_size,
                              hipStream_t stream) {
    const float* x       = (const float*)d_in[0];
    const float* ln_g    = (const float*)d_in[1];
    const float* ln_b    = (const float*)d_in[2];
    const float* W_in    = (const float*)d_in[3];
    const float* conv_w  = (const float*)d_in[4];
    const float* conv_b  = (const float*)d_in[5];
    const float* dt_bias = (const float*)d_in[6];
    const float* A_log   = (const float*)d_in[7];
    const float* fc_D_w  = (const float*)d_in[8];
    const float* Dv      = (const float*)d_in[9];
    const float* norm_w  = (const float*)d_in[10];
    const float* W_out   = (const float*)d_in[11];

    char* ws = (char*)d_ws;
    u16*   u_bf  = (u16*)(ws + OFF_U);
    u16*   winb  = (u16*)(ws + OFF_WIN);
    u16*   woutb = (u16*)(ws + OFF_WOUT);
    u16*   zx    = (u16*)(ws + OFF_ZX);
    u16*   xs    = (u16*)(ws + OFF_XS);
    float* BC    = (float*)(ws + OFF_BC);
    float* dtA   = (float*)(ws + OFF_DTA);
    u16*   y0b   = (u16*)(ws + OFF_Y0);
    u16*   y1b   = (u16*)(ws + OFF_Y1);
    u16*   ynb   = (u16*)(ws + OFF_YN);

    k_cvt_win <<<(NPAD * DM) / 256, 256, 0, stream>>>(W_in, winb);
    k_cvt_wout<<<(DM * DIN) / 256, 256, 0, stream>>>(W_out, woutb);
    k_ln      <<<BL, 256, 0, stream>>>(x, ln_g, ln_b, u_bf);
    k_gemm_bt <<<dim3(NPAD / 128, BL / 128), 256, 0, stream>>>(u_bf, winb, BL, NPAD, DM, 1, zx, NPAD, nullptr, nullptr);
    k_conv    <<<dim3(CONV_DIM / 64, L_ / 256, B_), 256, 0, stream>>>(zx, conv_w, conv_b, xs, BC);
    k_dt      <<<(BL * 64) / 256, 256, 0, stream>>>(zx, dt_bias, A_log, dtA);
    k_scan    <<<256, 256, 0, stream>>>(xs, BC, dtA, y0b, y1b);
    k_gate    <<<BL, 256, 0, stream>>>(xs, zx, y0b, y1b, fc_D_w, Dv, norm_w, ynb);
    k_gemm_bt <<<dim3(DM / 128, BL / 128), 256, 0, stream>>>(ynb, woutb, BL, DM, DIN, 0, nullptr, DM, (float*)d_out, x);
}

// Round 2
// 729.442 us; speedup vs baseline: 2.7479x; 2.7479x over previous
//
#include <hip/hip_runtime.h>
#include <stdint.h>

// ---- problem constants ----
#define B_   4
#define L_   2048
#define DM   1024
#define DIN  2048
#define NH   32
#define HD   64
#define DSTATE 64
#define DCONV  7
#define CONV_DIM 2176            // DIN + 2*DSTATE
#define DPROJ 4288               // 2*DIN + 2*DSTATE + 2*NH
#define NPAD 4352                // DPROJ padded to 128
#define BL   8192                // B_*L_
#define EPS  1e-5f
#define QC   128                 // scan chunk length
#define NCH  16                  // chunks per sequence

typedef unsigned short u16;
typedef unsigned int   u32;
typedef __bf16 bf16x8 __attribute__((ext_vector_type(8)));
typedef float  f32x4  __attribute__((ext_vector_type(4)));

__device__ __forceinline__ float b2f(u32 b) { return __uint_as_float(b << 16); }
__device__ __forceinline__ u16 f2b(float f) {
    u32 u = __float_as_uint(f);
    u32 r = (u + 0x7fffu + ((u >> 16) & 1u)) >> 16;
    return (u16)r;
}
__device__ __forceinline__ void unpack8(uint4 v, float* f) {
    f[0] = b2f(v.x & 0xffffu); f[1] = b2f(v.x >> 16);
    f[2] = b2f(v.y & 0xffffu); f[3] = b2f(v.y >> 16);
    f[4] = b2f(v.z & 0xffffu); f[5] = b2f(v.z >> 16);
    f[6] = b2f(v.w & 0xffffu); f[7] = b2f(v.w >> 16);
}
__device__ __forceinline__ uint4 pack8(const float* f) {
    uint4 v;
    v.x = (u32)f2b(f[0]) | ((u32)f2b(f[1]) << 16);
    v.y = (u32)f2b(f[2]) | ((u32)f2b(f[3]) << 16);
    v.z = (u32)f2b(f[4]) | ((u32)f2b(f[5]) << 16);
    v.w = (u32)f2b(f[6]) | ((u32)f2b(f[7]) << 16);
    return v;
}

// ---------- weight conversion ----------
__global__ __launch_bounds__(256) void k_cvt_win(const float* __restrict__ W, u16* __restrict__ Wb) {
    int idx = blockIdx.x * 256 + threadIdx.x;      // over NPAD*DM
    int n = idx >> 10;                              // DM = 1024
    float v = (n < DPROJ) ? W[(size_t)n * DM + (idx & 1023)] : 0.f;
    Wb[idx] = f2b(v);
}
__global__ __launch_bounds__(256) void k_cvt_wout(const float* __restrict__ W, u16* __restrict__ Wb) {
    int idx = blockIdx.x * 256 + threadIdx.x;      // over DM*DIN
    Wb[idx] = f2b(W[idx]);
}

// ---------- layernorm -> bf16 ----------
__global__ __launch_bounds__(256) void k_ln(const float* __restrict__ x, const float* __restrict__ g,
                                            const float* __restrict__ be, u16* __restrict__ u) {
    int row = blockIdx.x, tid = threadIdx.x;
    const float4* xr = (const float4*)(x + (size_t)row * DM);
    float4 v = xr[tid];
    float s1 = v.x + v.y + v.z + v.w;
    float s2 = v.x * v.x + v.y * v.y + v.z * v.z + v.w * v.w;
    for (int o = 32; o; o >>= 1) { s1 += __shfl_down(s1, o); s2 += __shfl_down(s2, o); }
    __shared__ float ls1[4], ls2[4];
    int w = tid >> 6;
    if ((tid & 63) == 0) { ls1[w] = s1; ls2[w] = s2; }
    __syncthreads();
    float t1 = ls1[0] + ls1[1] + ls1[2] + ls1[3];
    float t2 = ls2[0] + ls2[1] + ls2[2] + ls2[3];
    float mu = t1 * (1.f / DM);
    float var = t2 * (1.f / DM) - mu * mu;
    float rs = rsqrtf(var + EPS);
    float4 gv = ((const float4*)g)[tid];
    float4 bv = ((const float4*)be)[tid];
    float o0 = (v.x - mu) * rs * gv.x + bv.x;
    float o1 = (v.y - mu) * rs * gv.y + bv.y;
    float o2 = (v.z - mu) * rs * gv.z + bv.z;
    float o3 = (v.w - mu) * rs * gv.w + bv.w;
    uint2 p;
    p.x = (u32)f2b(o0) | ((u32)f2b(o1) << 16);
    p.y = (u32)f2b(o2) | ((u32)f2b(o3) << 16);
    ((uint2*)(u + (size_t)row * DM))[tid] = p;
}

// ---------- bf16 MFMA GEMM, C[m,n] = sum_k A[m,k]*B[n,k]  (B^T layout) ----------
__global__ __launch_bounds__(256) void k_gemm_bt(const u16* __restrict__ A, const u16* __restrict__ Bw,
                                                 int M, int N, int K, int out_bf16,
                                                 u16* __restrict__ obf, int ldo,
                                                 float* __restrict__ ofp, const float* __restrict__ res) {
    __shared__ __align__(16) u16 As[128 * 32];
    __shared__ __align__(16) u16 Bs[128 * 32];
    int tid = threadIdx.x;
    int m0 = blockIdx.y * 128, n0 = blockIdx.x * 128;
    int w = tid >> 6, lane = tid & 63;
    int wm = (w >> 1) * 64, wn = (w & 1) * 64;
    int lr = lane & 15, lq = lane >> 4;

    f32x4 acc[4][4];
    #pragma unroll
    for (int i = 0; i < 4; i++)
        #pragma unroll
        for (int j = 0; j < 4; j++) acc[i][j] = (f32x4){0.f, 0.f, 0.f, 0.f};

    for (int kt = 0; kt < K; kt += 32) {
        #pragma unroll
        for (int it = 0; it < 2; it++) {
            int chunk = tid + it * 256;
            int r = chunk >> 2, kc = chunk & 3;
            ((uint4*)As)[chunk] = *(const uint4*)(A + (size_t)(m0 + r) * K + kt + kc * 8);
            ((uint4*)Bs)[chunk] = *(const uint4*)(Bw + (size_t)(n0 + r) * K + kt + kc * 8);
        }
        __syncthreads();
        bf16x8 af[4], bfr[4];
        #pragma unroll
        for (int i = 0; i < 4; i++) af[i] = *(const bf16x8*)&As[(wm + 16 * i + lr) * 32 + lq * 8];
        #pragma unroll
        for (int j = 0; j < 4; j++) bfr[j] = *(const bf16x8*)&Bs[(wn + 16 * j + lr) * 32 + lq * 8];
        #pragma unroll
        for (int i = 0; i < 4; i++)
            #pragma unroll
            for (int j = 0; j < 4; j++)
                acc[i][j] = __builtin_amdgcn_mfma_f32_16x16x32_bf16(af[i], bfr[j], acc[i][j], 0, 0, 0);
        __syncthreads();
    }
    #pragma unroll
    for (int i = 0; i < 4; i++) {
        #pragma unroll
        for (int j = 0; j < 4; j++) {
            #pragma unroll
            for (int r = 0; r < 4; r++) {
                int m = m0 + wm + 16 * i + lq * 4 + r;
                int n = n0 + wn + 16 * j + lr;
                float v = acc[i][j][r];
                if (out_bf16) obf[(size_t)m * ldo + n] = f2b(v);
                else          ofp[(size_t)m * ldo + n] = v + res[(size_t)m * ldo + n];
            }
        }
    }
}

// ---------- depthwise conv7 (same-pad) + bias + SiLU, split xs / BC ----------
__global__ __launch_bounds__(256) void k_conv(const u16* __restrict__ zx, const float* __restrict__ cw,
                                              const float* __restrict__ cb, u16* __restrict__ xs,
                                              float* __restrict__ BC) {
    __shared__ u16 sh[262 * 64];
    int c0 = blockIdx.x * 64, t0 = blockIdx.y * 256, b = blockIdx.z;
    int tid = threadIdx.x;
    int c = tid & 63, tg = tid >> 6;
    for (int it = 0; it < 66; it++) {
        int r = it * 4 + tg;
        if (r < 262) {
            int t = t0 + r - 3;
            u16 v = 0;
            if (t >= 0 && t < L_) v = zx[(size_t)(b * L_ + t) * NPAD + DIN + c0 + c];
            sh[r * 64 + c] = v;
        }
    }
    float wgt[7];
    #pragma unroll
    for (int k = 0; k < 7; k++) wgt[k] = cw[(c0 + c) * 7 + k];
    float bias = cb[c0 + c];
    __syncthreads();
    int cg = c0 + c;
    for (int tt = 0; tt < 64; tt++) {
        int tl = tt * 4 + tg;
        float a = bias;
        #pragma unroll
        for (int k = 0; k < 7; k++) a += b2f(sh[(tl + k) * 64 + c]) * wgt[k];
        float v = a / (1.f + __expf(-a));   // silu
        size_t row = (size_t)b * L_ + (t0 + tl);
        if (cg < DIN) xs[row * DIN + cg] = f2b(v);
        else          BC[row * 128 + (cg - DIN)] = v;   // B at [0,64), C at [64,128)
    }
}

// ---------- dt2 / log-dA precompute ----------
__global__ __launch_bounds__(256) void k_dt(const u16* __restrict__ zx, const float* __restrict__ dt_bias,
                                            const float* __restrict__ A_log, float* __restrict__ dtA) {
    int idx = blockIdx.x * 256 + threadIdx.x;   // over BL*64
    int row = idx >> 6, j = idx & 63;
    float draw = b2f(zx[(size_t)row * NPAD + (DIN + CONV_DIM) + j]);
    float xb = draw + dt_bias[j & 31];
    float dt2 = (xb > 20.f) ? xb : log1pf(__expf(xb));
    dtA[(size_t)idx * 2]     = dt2;
    dtA[(size_t)idx * 2 + 1] = -__expf(A_log[j & 31]) * dt2;   // log dA
}

// ======================================================================
// Chunked SSD scan: block = (dir,b,h,chunk).  Q=128, DSTATE=64, HD=64.
// k_chunk: G=C*B^T ; S=M.*G ; Y_intra=S*X ; writes Y_intra bf16 + exp(cum)+decay
// ======================================================================
__global__ __launch_bounds__(256) void k_chunk(const u16* __restrict__ xs, const float* __restrict__ BC,
                                               const float* __restrict__ dtA, u16* __restrict__ y0,
                                               u16* __restrict__ y1, float* __restrict__ wout,
                                               float* __restrict__ decay) {
    __shared__ __align__(16) u16 ab[18432];      // Cs [0,9216) stride 72, Bs [9216,18432); S overlays, stride 136
    __shared__ __align__(16) u16 XT[64 * 136];   // X^T [p][s]
    __shared__ __align__(16) float dts_s[128];
    __shared__ __align__(16) float lda_s[128];
    __shared__ __align__(16) double cumd[128];

    const int blk = blockIdx.x;
    const int c = blk & 15, dbh = blk >> 4;
    const int h = dbh & 31, b = (dbh >> 5) & 3, dir = dbh >> 7;
    const int tid = threadIdx.x, w = tid >> 6, lane = tid & 63, lr = lane & 15, lq = lane >> 4;
    const int s0 = c * QC;
    u16* yo = dir ? y1 : y0;

    if (tid < 128) {
        int s = s0 + tid;
        int t = dir ? (L_ - 1 - s) : s;
        size_t di = ((size_t)(b * L_ + t) * 64 + dir * 32 + h) * 2;
        dts_s[tid] = dtA[di];
        lda_s[tid] = dtA[di + 1];
    }
    {   // stage Cs, Bs (bf16), XT (transposed)
        int sl0 = tid >> 3, ng = (tid & 7) * 8;
        #pragma unroll
        for (int it = 0; it < 4; it++) {
            int sl = sl0 + it * 32;
            int s = s0 + sl;
            int t = dir ? (L_ - 1 - s) : s;
            size_t row = (size_t)b * L_ + t;
            const float* bcr = BC + row * 128;
            float f[8];
            float4 v0 = *(const float4*)(bcr + 64 + ng);
            float4 v1 = *(const float4*)(bcr + 64 + ng + 4);
            f[0]=v0.x; f[1]=v0.y; f[2]=v0.z; f[3]=v0.w; f[4]=v1.x; f[5]=v1.y; f[6]=v1.z; f[7]=v1.w;
            *(uint4*)&ab[sl * 72 + ng] = pack8(f);
            v0 = *(const float4*)(bcr + ng);
            v1 = *(const float4*)(bcr + ng + 4);
            f[0]=v0.x; f[1]=v0.y; f[2]=v0.z; f[3]=v0.w; f[4]=v1.x; f[5]=v1.y; f[6]=v1.z; f[7]=v1.w;
            *(uint4*)&ab[9216 + sl * 72 + ng] = pack8(f);
            uint4 xv = *(const uint4*)(xs + row * DIN + h * 64 + ng);
            u16 xh[8] = {(u16)(xv.x & 0xffffu), (u16)(xv.x >> 16), (u16)(xv.y & 0xffffu), (u16)(xv.y >> 16),
                         (u16)(xv.z & 0xffffu), (u16)(xv.z >> 16), (u16)(xv.w & 0xffffu), (u16)(xv.w >> 16)};
            #pragma unroll
            for (int i = 0; i < 8; i++) XT[(ng + i) * 136 + sl] = xh[i];
        }
    }
    __syncthreads();
    if (w == 0) {   // double-precision inclusive prefix of log-dA (wave 0)
        double v0 = (double)lda_s[lane];
        double v1 = (double)lda_s[64 + lane];
        #pragma unroll
        for (int o = 1; o < 64; o <<= 1) {
            double t0 = __shfl_up(v0, o);
            double t1 = __shfl_up(v1, o);
            if (lane >= o) { v0 += t0; v1 += t1; }
        }
        double tot0 = __shfl(v0, 63);
        cumd[lane] = v0;
        cumd[64 + lane] = tot0 + v1;
    }
    // G = C * B^T  (wave w owns t-rows [w*32, w*32+32))
    bf16x8 af[2][2];
    #pragma unroll
    for (int ti = 0; ti < 2; ti++)
        #pragma unroll
        for (int ks = 0; ks < 2; ks++)
            af[ti][ks] = *(const bf16x8*)&ab[(w * 32 + ti * 16 + lr) * 72 + ks * 32 + lq * 8];
    f32x4 accg[2][8];
    #pragma unroll
    for (int ti = 0; ti < 2; ti++)
        #pragma unroll
        for (int si = 0; si < 8; si++) accg[ti][si] = (f32x4){0.f, 0.f, 0.f, 0.f};
    #pragma unroll
    for (int si = 0; si < 8; si++)
        #pragma unroll
        for (int ks = 0; ks < 2; ks++) {
            bf16x8 bf = *(const bf16x8*)&ab[9216 + (si * 16 + lr) * 72 + ks * 32 + lq * 8];
            accg[0][si] = __builtin_amdgcn_mfma_f32_16x16x32_bf16(af[0][ks], bf, accg[0][si], 0, 0, 0);
            accg[1][si] = __builtin_amdgcn_mfma_f32_16x16x32_bf16(af[1][ks], bf, accg[1][si], 0, 0, 0);
        }
    __syncthreads();   // all G frag reads done; cumd ready
    // S = M .* G  -> overlay into ab (stride 136)
    {
        double cumt_d[8];
        #pragma unroll
        for (int ti = 0; ti < 2; ti++)
            #pragma unroll
            for (int r = 0; r < 4; r++) cumt_d[ti * 4 + r] = cumd[w * 32 + ti * 16 + lq * 4 + r];
        double cums_d[8]; float dts_l[8];
        #pragma unroll
        for (int si = 0; si < 8; si++) { cums_d[si] = cumd[si * 16 + lr]; dts_l[si] = dts_s[si * 16 + lr]; }
        #pragma unroll
        for (int ti = 0; ti < 2; ti++)
            #pragma unroll
            for (int si = 0; si < 8; si++)
                #pragma unroll
                for (int r = 0; r < 4; r++) {
                    int t_l = w * 32 + ti * 16 + lq * 4 + r;
                    int s_l = si * 16 + lr;
                    float v = 0.f;
                    if (s_l <= t_l)
                        v = __expf((float)(cumt_d[ti * 4 + r] - cums_d[si])) * dts_l[si] * accg[ti][si][r];
                    ab[t_l * 136 + s_l] = f2b(v);
                }
    }
    __syncthreads();
    // Y_intra = S * X^T
    f32x4 acc[2][4];
    #pragma unroll
    for (int ti = 0; ti < 2; ti++)
        #pragma unroll
        for (int pj = 0; pj < 4; pj++) acc[ti][pj] = (f32x4){0.f, 0.f, 0.f, 0.f};
    #pragma unroll
    for (int ks = 0; ks < 4; ks++) {
        bf16x8 a0 = *(const bf16x8*)&ab[(w * 32 + lr) * 136 + ks * 32 + lq * 8];
        bf16x8 a1 = *(const bf16x8*)&ab[(w * 32 + 16 + lr) * 136 + ks * 32 + lq * 8];
        #pragma unroll
        for (int pj = 0; pj < 4; pj++) {
            bf16x8 bf = *(const bf16x8*)&XT[(pj * 16 + lr) * 136 + ks * 32 + lq * 8];
            acc[0][pj] = __builtin_amdgcn_mfma_f32_16x16x32_bf16(a0, bf, acc[0][pj], 0, 0, 0);
            acc[1][pj] = __builtin_amdgcn_mfma_f32_16x16x32_bf16(a1, bf, acc[1][pj], 0, 0, 0);
        }
    }
    #pragma unroll
    for (int ti = 0; ti < 2; ti++)
        #pragma unroll
        for (int pj = 0; pj < 4; pj++)
            #pragma unroll
            for (int r = 0; r < 4; r++) {
                int t_l = w * 32 + ti * 16 + lq * 4 + r;
                int s = s0 + t_l;
                int t = dir ? (L_ - 1 - s) : s;
                yo[((size_t)b * L_ + t) * DIN + h * 64 + pj * 16 + lr] = f2b(acc[ti][pj][r]);
            }
    if (tid < 128) wout[dbh * 2048 + s0 + tid] = __expf((float)cumd[tid]);
    if (tid == 0)  decay[blk] = __expf((float)cumd[127]);
}

// k_state: S_c[p][n] = sum_s exp(cumEnd-cum[s])*dt[s]*x[s][p]*B[s][n]  (bf16 out)
__global__ __launch_bounds__(256) void k_state(const u16* __restrict__ xs, const float* __restrict__ BC,
                                               const float* __restrict__ dtA, u16* __restrict__ scb) {
    __shared__ __align__(16) u16 XT[64 * 136];
    __shared__ __align__(16) u16 BT[64 * 136];
    __shared__ __align__(16) float dts_s[128];
    __shared__ __align__(16) float lda_s[128];
    __shared__ __align__(16) float wend[128];

    const int blk = blockIdx.x;
    const int c = blk & 15, dbh = blk >> 4;
    const int h = dbh & 31, b = (dbh >> 5) & 3, dir = dbh >> 7;
    const int tid = threadIdx.x, w = tid >> 6, lane = tid & 63, lr = lane & 15, lq = lane >> 4;
    const int s0 = c * QC;

    if (tid < 128) {
        int s = s0 + tid;
        int t = dir ? (L_ - 1 - s) : s;
        size_t di = ((size_t)(b * L_ + t) * 64 + dir * 32 + h) * 2;
        dts_s[tid] = dtA[di];
        lda_s[tid] = dtA[di + 1];
    }
    {
        int sl0 = tid >> 3, ng = (tid & 7) * 8;
        #pragma unroll
        for (int it = 0; it < 4; it++) {
            int sl = sl0 + it * 32;
            int s = s0 + sl;
            int t = dir ? (L_ - 1 - s) : s;
            size_t row = (size_t)b * L_ + t;
            const float* bcr = BC + row * 128;
            float4 v0 = *(const float4*)(bcr + ng);
            float4 v1 = *(const float4*)(bcr + ng + 4);
            float f[8] = {v0.x, v0.y, v0.z, v0.w, v1.x, v1.y, v1.z, v1.w};
            #pragma unroll
            for (int i = 0; i < 8; i++) BT[(ng + i) * 136 + sl] = f2b(f[i]);
            uint4 xv = *(const uint4*)(xs + row * DIN + h * 64 + ng);
            u16 xh[8] = {(u16)(xv.x & 0xffffu), (u16)(xv.x >> 16), (u16)(xv.y & 0xffffu), (u16)(xv.y >> 16),
                         (u16)(xv.z & 0xffffu), (u16)(xv.z >> 16), (u16)(xv.w & 0xffffu), (u16)(xv.w >> 16)};
            #pragma unroll
            for (int i = 0; i < 8; i++) XT[(ng + i) * 136 + sl] = xh[i];
        }
    }
    __syncthreads();
    if (w == 0) {
        double v0 = (double)lda_s[lane];
        double v1 = (double)lda_s[64 + lane];
        #pragma unroll
        for (int o = 1; o < 64; o <<= 1) {
            double t0 = __shfl_up(v0, o);
            double t1 = __shfl_up(v1, o);
            if (lane >= o) { v0 += t0; v1 += t1; }
        }
        double tot0 = __shfl(v0, 63);
        double tot  = tot0 + __shfl(v1, 63);
        wend[lane]      = __expf((float)(tot - v0)) * dts_s[lane];
        wend[64 + lane] = __expf((float)(tot - (tot0 + v1))) * dts_s[64 + lane];
    }
    __syncthreads();
    f32x4 acc[4];
    #pragma unroll
    for (int nj = 0; nj < 4; nj++) acc[nj] = (f32x4){0.f, 0.f, 0.f, 0.f};
    #pragma unroll
    for (int ks = 0; ks < 4; ks++) {
        uint4 xv = *(const uint4*)&XT[(w * 16 + lr) * 136 + ks * 32 + lq * 8];
        float xf[8]; unpack8(xv, xf);
        float4 w0 = *(const float4*)&wend[ks * 32 + lq * 8];
        float4 w1 = *(const float4*)&wend[ks * 32 + lq * 8 + 4];
        float fs[8] = {xf[0]*w0.x, xf[1]*w0.y, xf[2]*w0.z, xf[3]*w0.w,
                       xf[4]*w1.x, xf[5]*w1.y, xf[6]*w1.z, xf[7]*w1.w};
        bf16x8 a = __builtin_bit_cast(bf16x8, pack8(fs));
        #pragma unroll
        for (int nj = 0; nj < 4; nj++) {
            bf16x8 bb = *(const bf16x8*)&BT[(nj * 16 + lr) * 136 + ks * 32 + lq * 8];
            acc[nj] = __builtin_amdgcn_mfma_f32_16x16x32_bf16(a, bb, acc[nj], 0, 0, 0);
        }
    }
    #pragma unroll
    for (int nj = 0; nj < 4; nj++)
        #pragma unroll
        for (int r = 0; r < 4; r++) {
            int p = w * 16 + lq * 4 + r, n = nj * 16 + lr;
            scb[(size_t)blk * 4096 + p * 64 + n] = f2b(acc[nj][r]);
        }
}

// k_carry: sequential over 16 chunks: y_full = Y_intra + exp(cum)*C*h ; shift; h = decay*h + S_c
__global__ __launch_bounds__(256) void k_carry(const float* __restrict__ BC, const float* __restrict__ wout,
                                               const float* __restrict__ decay, const u16* __restrict__ scb,
                                               u16* __restrict__ y0, u16* __restrict__ y1) {
    __shared__ __align__(16) float hsh[64 * 68];     // h[p][n], row stride 68
    __shared__ __align__(16) u16 Csc[128 * 72];      // exp(cum[s])*C[s][n]
    __shared__ __align__(16) u16 ybs[128 * 72];      // y_full rows (bf16)
    __shared__ __align__(16) u16 prevu[72];
    const int dbh = blockIdx.x;
    const int h = dbh & 31, b = (dbh >> 5) & 3, dir = dbh >> 7;
    const int tid = threadIdx.x, w = tid >> 6, lane = tid & 63, lr = lane & 15, lq = lane >> 4;
    u16* yo = dir ? y1 : y0;

    for (int i = tid; i < 64 * 68; i += 256) hsh[i] = 0.f;
    if (tid < 72) prevu[tid] = 0;
    __syncthreads();
    const int sl0 = tid >> 3, ng = (tid & 7) * 8;
    for (int c = 0; c < NCH; c++) {
        #pragma unroll
        for (int it = 0; it < 4; it++) {
            int sl = sl0 + it * 32;
            int s = c * QC + sl;
            int t = dir ? (L_ - 1 - s) : s;
            const float* bcr = BC + ((size_t)b * L_ + t) * 128 + 64 + ng;
            float sc = wout[dbh * 2048 + s];
            float4 v0 = *(const float4*)bcr;
            float4 v1 = *(const float4*)(bcr + 4);
            float f[8] = {v0.x*sc, v0.y*sc, v0.z*sc, v0.w*sc, v1.x*sc, v1.y*sc, v1.z*sc, v1.w*sc};
            *(uint4*)&Csc[sl * 72 + ng] = pack8(f);
        }
        bf16x8 hb[4][2];
        #pragma unroll
        for (int pj = 0; pj < 4; pj++)
            #pragma unroll
            for (int ks = 0; ks < 2; ks++) {
                const float* hp = &hsh[(pj * 16 + lr) * 68 + ks * 32 + lq * 8];
                float4 a0 = *(const float4*)hp;
                float4 a1 = *(const float4*)(hp + 4);
                float f[8] = {a0.x, a0.y, a0.z, a0.w, a1.x, a1.y, a1.z, a1.w};
                hb[pj][ks] = __builtin_bit_cast(bf16x8, pack8(f));
            }
        __syncthreads();
        f32x4 acc[2][4];
        #pragma unroll
        for (int ti = 0; ti < 2; ti++)
            #pragma unroll
            for (int pj = 0; pj < 4; pj++) acc[ti][pj] = (f32x4){0.f, 0.f, 0.f, 0.f};
        #pragma unroll
        for (int ks = 0; ks < 2; ks++) {
            bf16x8 a0 = *(const bf16x8*)&Csc[(w * 32 + lr) * 72 + ks * 32 + lq * 8];
            bf16x8 a1 = *(const bf16x8*)&Csc[(w * 32 + 16 + lr) * 72 + ks * 32 + lq * 8];
            #pragma unroll
            for (int pj = 0; pj < 4; pj++) {
                acc[0][pj] = __builtin_amdgcn_mfma_f32_16x16x32_bf16(a0, hb[pj][ks], acc[0][pj], 0, 0, 0);
                acc[1][pj] = __builtin_amdgcn_mfma_f32_16x16x32_bf16(a1, hb[pj][ks], acc[1][pj], 0, 0, 0);
            }
        }
        #pragma unroll
        for (int ti = 0; ti < 2; ti++)
            #pragma unroll
            for (int pj = 0; pj < 4; pj++)
                #pragma unroll
                for (int r = 0; r < 4; r++) {
                    int t_l = w * 32 + ti * 16 + lq * 4 + r;
                    int s = c * QC + t_l;
                    int t = dir ? (L_ - 1 - s) : s;
                    float yv = acc[ti][pj][r] + b2f(yo[((size_t)b * L_ + t) * DIN + h * 64 + pj * 16 + lr]);
                    ybs[t_l * 72 + pj * 16 + lr] = f2b(yv);
                }
        {   // h = decay*h + S_c
            float dk = decay[dbh * 16 + c];
            const u16* sg = scb + ((size_t)(dbh * 16 + c)) * 4096 + tid * 16;
            uint4 q0 = *(const uint4*)sg;
            uint4 q1 = *(const uint4*)(sg + 8);
            float sf[16]; unpack8(q0, sf); unpack8(q1, sf + 8);
            int p = (tid * 16) >> 6, n0 = (tid * 16) & 63;
            float* hp = &hsh[p * 68 + n0];
            #pragma unroll
            for (int i = 0; i < 16; i++) hp[i] = dk * hp[i] + sf[i];
        }
        __syncthreads();
        #pragma unroll
        for (int it = 0; it < 4; it++) {
            int sl = sl0 + it * 32;
            int s = c * QC + sl;
            int t = dir ? (L_ - 1 - s) : s;
            const u16* src = (sl == 0) ? (prevu + ng) : &ybs[(sl - 1) * 72 + ng];
            *(uint4*)&yo[((size_t)b * L_ + t) * DIN + h * 64 + ng] = *(const uint4*)src;
        }
        __syncthreads();
        if (tid < 8) *(uint4*)&prevu[tid * 8] = *(const uint4*)&ybs[127 * 72 + tid * 8];
    }
}

// ---------- D-proj + gate + RMSNorm -> bf16 ----------
__global__ __launch_bounds__(256) void k_gate(const u16* __restrict__ xs, const u16* __restrict__ zx,
                                              const u16* __restrict__ y0, const u16* __restrict__ y1,
                                              const float* __restrict__ fcw, const float* __restrict__ Dv,
                                              const float* __restrict__ nw, u16* __restrict__ yn) {
    int row = blockIdx.x, tid = threadIdx.x;
    __shared__ float xsl[DIN];
    __shared__ float sD[NH];
    __shared__ float red[4];
    size_t base = (size_t)row * DIN;
    uint4 xv = ((const uint4*)(xs + base))[tid];
    float xf[8]; unpack8(xv, xf);
    #pragma unroll
    for (int i = 0; i < 8; i++) xsl[tid * 8 + i] = xf[i];
    __syncthreads();
    int hh = tid >> 3, gs = tid & 7;
    const float* fr = fcw + (size_t)hh * DIN;
    float part = 0.f;
    for (int k = gs; k < DIN; k += 8) part += xsl[k] * fr[k];
    part += __shfl_down(part, 4);
    part += __shfl_down(part, 2);
    part += __shfl_down(part, 1);
    if (gs == 0) sD[hh] = part + Dv[hh];
    __syncthreads();

    uint4 zv = ((const uint4*)(zx + (size_t)row * NPAD))[tid];
    uint4 a0 = ((const uint4*)(y0 + base))[tid];
    uint4 a1 = ((const uint4*)(y1 + base))[tid];
    float zf[8], f0[8], f1[8];
    unpack8(zv, zf); unpack8(a0, f0); unpack8(a1, f1);
    int d0 = tid * 8;
    float g[8]; float ss = 0.f;
    #pragma unroll
    for (int i = 0; i < 8; i++) {
        float yv = f0[i] + f1[i] + xf[i] * sD[(d0 + i) >> 6];
        float z = zf[i];
        float gg = yv * (z / (1.f + __expf(-z)));
        g[i] = gg; ss += gg * gg;
    }
    for (int o = 32; o; o >>= 1) ss += __shfl_down(ss, o);
    if ((tid & 63) == 0) red[tid >> 6] = ss;
    __syncthreads();
    float tot = red[0] + red[1] + red[2] + red[3];
    float r = rsqrtf(tot * (1.f / DIN) + EPS);
    float o8[8];
    #pragma unroll
    for (int i = 0; i < 8; i++) o8[i] = g[i] * r * nw[d0 + i];
    ((uint4*)(yn + base))[tid] = pack8(o8);
}

// ---------- workspace layout (bytes) ----------
#define OFF_U     ((size_t)0)                       // BL*DM bf16        = 16,777,216 (dead after GEMM1)
#define OFF_WIN   ((size_t)16777216)                // NPAD*DM bf16
#define OFF_WOUT  ((size_t)25690112)                // DM*DIN bf16
#define OFF_ZX    ((size_t)29884416)                // BL*NPAD bf16
#define OFF_XS    ((size_t)101187584)               // BL*DIN bf16
#define OFF_BC    ((size_t)134742016)               // BL*128 f32
#define OFF_DTA   ((size_t)138936320)               // BL*64*2 f32
#define OFF_Y0    ((size_t)143130624)               // BL*DIN bf16
#define OFF_Y1    ((size_t)176685056)               // BL*DIN bf16
#define OFF_YN    ((size_t)210239488)               // BL*DIN bf16 (gate out); scb aliases here earlier
// aliases (lifetimes disjoint):
#define OFF_WO2   OFF_U                             // 256*2048 f32 exp(cum) = 2 MB (after GEMM1)
#define OFF_DEC   (OFF_U + 2097152)                 // 4096 f32 chunk decay
#define OFF_SCB   OFF_YN                            // 4096*4096 bf16 chunk states = 33.5 MB
// total 243,793,920 bytes

extern "C" void kernel_launch(void* const* d_in, const int* in_sizes, int n_in,
                              void* d_out, int out_size, void* d_ws, size_t ws_size,
                              hipStream_t stream) {
    const float* x       = (const float*)d_in[0];
    const float* ln_g    = (const float*)d_in[1];
    const float* ln_b    = (const float*)d_in[2];
    const float* W_in    = (const float*)d_in[3];
    const float* conv_w  = (const float*)d_in[4];
    const float* conv_b  = (const float*)d_in[5];
    const float* dt_bias = (const float*)d_in[6];
    const float* A_log   = (const float*)d_in[7];
    const float* fc_D_w  = (const float*)d_in[8];
    const float* Dv      = (const float*)d_in[9];
    const float* norm_w  = (const float*)d_in[10];
    const float* W_out   = (const float*)d_in[11];

    char* ws = (char*)d_ws;
    u16*   u_bf  = (u16*)(ws + OFF_U);
    u16*   winb  = (u16*)(ws + OFF_WIN);
    u16*   woutb = (u16*)(ws + OFF_WOUT);
    u16*   zx    = (u16*)(ws + OFF_ZX);
    u16*   xs    = (u16*)(ws + OFF_XS);
    float* BC    = (float*)(ws + OFF_BC);
    float* dtA   = (float*)(ws + OFF_DTA);
    u16*   y0b   = (u16*)(ws + OFF_Y0);
    u16*   y1b   = (u16*)(ws + OFF_Y1);
    u16*   ynb   = (u16*)(ws + OFF_YN);
    float* wo2   = (float*)(ws + OFF_WO2);
    float* dec   = (float*)(ws + OFF_DEC);
    u16*   scb   = (u16*)(ws + OFF_SCB);

    k_cvt_win <<<(NPAD * DM) / 256, 256, 0, stream>>>(W_in, winb);
    k_cvt_wout<<<(DM * DIN) / 256, 256, 0, stream>>>(W_out, woutb);
    k_ln      <<<BL, 256, 0, stream>>>(x, ln_g, ln_b, u_bf);
    k_gemm_bt <<<dim3(NPAD / 128, BL / 128), 256, 0, stream>>>(u_bf, winb, BL, NPAD, DM, 1, zx, NPAD, nullptr, nullptr);
    k_conv    <<<dim3(CONV_DIM / 64, L_ / 256, B_), 256, 0, stream>>>(zx, conv_w, conv_b, xs, BC);
    k_dt      <<<(BL * 64) / 256, 256, 0, stream>>>(zx, dt_bias, A_log, dtA);
    k_chunk   <<<4096, 256, 0, stream>>>(xs, BC, dtA, y0b, y1b, wo2, dec);
    k_state   <<<4096, 256, 0, stream>>>(xs, BC, dtA, scb);
    k_carry   <<<256, 256, 0, stream>>>(BC, wo2, dec, scb, y0b, y1b);
    k_gate    <<<BL, 256, 0, stream>>>(xs, zx, y0b, y1b, fc_D_w, Dv, norm_w, ynb);
    k_gemm_bt <<<dim3(DM / 128, BL / 128), 256, 0, stream>>>(ynb, woutb, BL, DM, DIN, 0, nullptr, DM, (float*)d_out, x);
}

// Round 3
// 594.101 us; speedup vs baseline: 3.3740x; 1.2278x over previous
//
#include <hip/hip_runtime.h>
#include <stdint.h>

// ---- problem constants ----
#define B_   4
#define L_   2048
#define DM   1024
#define DIN  2048
#define NH   32
#define HD   64
#define DSTATE 64
#define DCONV  7
#define CONV_DIM 2176            // DIN + 2*DSTATE
#define DPROJ 4288               // 2*DIN + 2*DSTATE + 2*NH
#define NPAD 4352                // DPROJ padded to 128
#define BL   8192                // B_*L_
#define EPS  1e-5f
#define QC   128                 // scan chunk length
#define NCH  16                  // chunks per sequence

typedef unsigned short u16;
typedef unsigned int   u32;
typedef __bf16 bf16x8 __attribute__((ext_vector_type(8)));
typedef float  f32x4  __attribute__((ext_vector_type(4)));

__device__ __forceinline__ float b2f(u32 b) { return __uint_as_float(b << 16); }
__device__ __forceinline__ u16 f2b(float f) {
    u32 u = __float_as_uint(f);
    u32 r = (u + 0x7fffu + ((u >> 16) & 1u)) >> 16;
    return (u16)r;
}
__device__ __forceinline__ void unpack8(uint4 v, float* f) {
    f[0] = b2f(v.x & 0xffffu); f[1] = b2f(v.x >> 16);
    f[2] = b2f(v.y & 0xffffu); f[3] = b2f(v.y >> 16);
    f[4] = b2f(v.z & 0xffffu); f[5] = b2f(v.z >> 16);
    f[6] = b2f(v.w & 0xffffu); f[7] = b2f(v.w >> 16);
}
__device__ __forceinline__ uint4 pack8(const float* f) {
    uint4 v;
    v.x = (u32)f2b(f[0]) | ((u32)f2b(f[1]) << 16);
    v.y = (u32)f2b(f[2]) | ((u32)f2b(f[3]) << 16);
    v.z = (u32)f2b(f[4]) | ((u32)f2b(f[5]) << 16);
    v.w = (u32)f2b(f[6]) | ((u32)f2b(f[7]) << 16);
    return v;
}
// async global->LDS, 16B per lane; lds base must be wave-uniform (HW adds lane*16)
__device__ __forceinline__ void gload_lds16(const u16* g, u16* l) {
    __builtin_amdgcn_global_load_lds((const __attribute__((address_space(1))) void*)g,
                                     (__attribute__((address_space(3))) void*)l, 16, 0, 0);
}

// ---------- weight conversion ----------
__global__ __launch_bounds__(256) void k_cvt_win(const float* __restrict__ W, u16* __restrict__ Wb) {
    int idx = blockIdx.x * 256 + threadIdx.x;      // over NPAD*DM
    int n = idx >> 10;                              // DM = 1024
    float v = (n < DPROJ) ? W[(size_t)n * DM + (idx & 1023)] : 0.f;
    Wb[idx] = f2b(v);
}
__global__ __launch_bounds__(256) void k_cvt_wout(const float* __restrict__ W, u16* __restrict__ Wb) {
    int idx = blockIdx.x * 256 + threadIdx.x;      // over DM*DIN
    Wb[idx] = f2b(W[idx]);
}
__global__ __launch_bounds__(256) void k_cvt_fcd(const float* __restrict__ W, u16* __restrict__ Wb) {
    int idx = blockIdx.x * 256 + threadIdx.x;      // over NH*DIN
    Wb[idx] = f2b(W[idx]);
}

// ---------- layernorm -> bf16 ----------
__global__ __launch_bounds__(256) void k_ln(const float* __restrict__ x, const float* __restrict__ g,
                                            const float* __restrict__ be, u16* __restrict__ u) {
    int row = blockIdx.x, tid = threadIdx.x;
    const float4* xr = (const float4*)(x + (size_t)row * DM);
    float4 v = xr[tid];
    float s1 = v.x + v.y + v.z + v.w;
    float s2 = v.x * v.x + v.y * v.y + v.z * v.z + v.w * v.w;
    for (int o = 32; o; o >>= 1) { s1 += __shfl_down(s1, o); s2 += __shfl_down(s2, o); }
    __shared__ float ls1[4], ls2[4];
    int w = tid >> 6;
    if ((tid & 63) == 0) { ls1[w] = s1; ls2[w] = s2; }
    __syncthreads();
    float t1 = ls1[0] + ls1[1] + ls1[2] + ls1[3];
    float t2 = ls2[0] + ls2[1] + ls2[2] + ls2[3];
    float mu = t1 * (1.f / DM);
    float var = t2 * (1.f / DM) - mu * mu;
    float rs = rsqrtf(var + EPS);
    float4 gv = ((const float4*)g)[tid];
    float4 bv = ((const float4*)be)[tid];
    float o0 = (v.x - mu) * rs * gv.x + bv.x;
    float o1 = (v.y - mu) * rs * gv.y + bv.y;
    float o2 = (v.z - mu) * rs * gv.z + bv.z;
    float o3 = (v.w - mu) * rs * gv.w + bv.w;
    uint2 p;
    p.x = (u32)f2b(o0) | ((u32)f2b(o1) << 16);
    p.y = (u32)f2b(o2) | ((u32)f2b(o3) << 16);
    ((uint2*)(u + (size_t)row * DM))[tid] = p;
}

// ---------- bf16 MFMA GEMM, C[m,n] = sum_k A[m,k]*B[n,k]  (B^T layout) ----------
// staging via global_load_lds width=16 (m97 structure)
__global__ __launch_bounds__(256) void k_gemm_bt(const u16* __restrict__ A, const u16* __restrict__ Bw,
                                                 int M, int N, int K, int out_bf16,
                                                 u16* __restrict__ obf, int ldo,
                                                 float* __restrict__ ofp, const float* __restrict__ res) {
    __shared__ __align__(16) u16 As[128 * 32];
    __shared__ __align__(16) u16 Bs[128 * 32];
    int tid = threadIdx.x;
    int m0 = blockIdx.y * 128, n0 = blockIdx.x * 128;
    int w = tid >> 6, lane = tid & 63;
    int wm = (w >> 1) * 64, wn = (w & 1) * 64;
    int lr = lane & 15, lq = lane >> 4;
    int r = (tid >> 2), kc = tid & 3;               // lane's chunk within it=0; it=1 adds 64 rows

    f32x4 acc[4][4];
    #pragma unroll
    for (int i = 0; i < 4; i++)
        #pragma unroll
        for (int j = 0; j < 4; j++) acc[i][j] = (f32x4){0.f, 0.f, 0.f, 0.f};

    for (int kt = 0; kt < K; kt += 32) {
        #pragma unroll
        for (int it = 0; it < 2; it++) {
            u16* lbase_a = &As[(it * 256 + w * 64) * 8];   // wave-uniform
            u16* lbase_b = &Bs[(it * 256 + w * 64) * 8];
            int rr = r + it * 64;
            gload_lds16(A + (size_t)(m0 + rr) * K + kt + kc * 8, lbase_a);
            gload_lds16(Bw + (size_t)(n0 + rr) * K + kt + kc * 8, lbase_b);
        }
        __syncthreads();
        bf16x8 af[4], bfr[4];
        #pragma unroll
        for (int i = 0; i < 4; i++) af[i] = *(const bf16x8*)&As[(wm + 16 * i + lr) * 32 + lq * 8];
        #pragma unroll
        for (int j = 0; j < 4; j++) bfr[j] = *(const bf16x8*)&Bs[(wn + 16 * j + lr) * 32 + lq * 8];
        #pragma unroll
        for (int i = 0; i < 4; i++)
            #pragma unroll
            for (int j = 0; j < 4; j++)
                acc[i][j] = __builtin_amdgcn_mfma_f32_16x16x32_bf16(af[i], bfr[j], acc[i][j], 0, 0, 0);
        __syncthreads();
    }
    #pragma unroll
    for (int i = 0; i < 4; i++) {
        #pragma unroll
        for (int j = 0; j < 4; j++) {
            #pragma unroll
            for (int rr = 0; rr < 4; rr++) {
                int m = m0 + wm + 16 * i + lq * 4 + rr;
                int n = n0 + wn + 16 * j + lr;
                float v = acc[i][j][rr];
                if (out_bf16) obf[(size_t)m * ldo + n] = f2b(v);
                else          ofp[(size_t)m * ldo + n] = v + res[(size_t)m * ldo + n];
            }
        }
    }
}

// ---------- D-projection GEMM: Dd[m][h] = dot(xs[m,:], fc_D_w[h,:]) + Dv[h] ----------
// grid 256 blocks x 32 rows; wave w handles (mtile=w&1, ntile=w>>1)
__global__ __launch_bounds__(256) void k_dproj(const u16* __restrict__ xs, const u16* __restrict__ fcb,
                                               const float* __restrict__ Dv, float* __restrict__ Dd) {
    __shared__ __align__(16) u16 As[32 * 64];
    __shared__ __align__(16) u16 Bs[32 * 64];
    int tid = threadIdx.x;
    int m0 = blockIdx.x * 32;
    int w = tid >> 6, lane = tid & 63, lr = lane & 15, lq = lane >> 4;
    int mt = (w & 1) * 16, nt = (w >> 1) * 16;
    int r = tid >> 3, kc = tid & 7;
    f32x4 acc = (f32x4){0.f, 0.f, 0.f, 0.f};
    for (int kt = 0; kt < DIN; kt += 64) {
        ((uint4*)As)[tid] = *(const uint4*)(xs + (size_t)(m0 + r) * DIN + kt + kc * 8);
        ((uint4*)Bs)[tid] = *(const uint4*)(fcb + (size_t)r * DIN + kt + kc * 8);
        __syncthreads();
        #pragma unroll
        for (int ks = 0; ks < 2; ks++) {
            bf16x8 a = *(const bf16x8*)&As[(mt + lr) * 64 + ks * 32 + lq * 8];
            bf16x8 b = *(const bf16x8*)&Bs[(nt + lr) * 64 + ks * 32 + lq * 8];
            acc = __builtin_amdgcn_mfma_f32_16x16x32_bf16(a, b, acc, 0, 0, 0);
        }
        __syncthreads();
    }
    #pragma unroll
    for (int rr = 0; rr < 4; rr++) {
        int m = m0 + mt + lq * 4 + rr;
        int n = nt + lr;
        Dd[(size_t)m * 32 + n] = acc[rr] + Dv[n];
    }
}

// ---------- depthwise conv7 (same-pad) + bias + SiLU, split xs / BC ----------
__global__ __launch_bounds__(256) void k_conv(const u16* __restrict__ zx, const float* __restrict__ cw,
                                              const float* __restrict__ cb, u16* __restrict__ xs,
                                              float* __restrict__ BC) {
    __shared__ u16 sh[262 * 64];
    int c0 = blockIdx.x * 64, t0 = blockIdx.y * 256, b = blockIdx.z;
    int tid = threadIdx.x;
    int c = tid & 63, tg = tid >> 6;
    for (int it = 0; it < 66; it++) {
        int r = it * 4 + tg;
        if (r < 262) {
            int t = t0 + r - 3;
            u16 v = 0;
            if (t >= 0 && t < L_) v = zx[(size_t)(b * L_ + t) * NPAD + DIN + c0 + c];
            sh[r * 64 + c] = v;
        }
    }
    float wgt[7];
    #pragma unroll
    for (int k = 0; k < 7; k++) wgt[k] = cw[(c0 + c) * 7 + k];
    float bias = cb[c0 + c];
    __syncthreads();
    int cg = c0 + c;
    for (int tt = 0; tt < 64; tt++) {
        int tl = tt * 4 + tg;
        float a = bias;
        #pragma unroll
        for (int k = 0; k < 7; k++) a += b2f(sh[(tl + k) * 64 + c]) * wgt[k];
        float v = a / (1.f + __expf(-a));   // silu
        size_t row = (size_t)b * L_ + (t0 + tl);
        if (cg < DIN) xs[row * DIN + cg] = f2b(v);
        else          BC[row * 128 + (cg - DIN)] = v;   // B at [0,64), C at [64,128)
    }
}

// ---------- dt2 / log-dA precompute ----------
__global__ __launch_bounds__(256) void k_dt(const u16* __restrict__ zx, const float* __restrict__ dt_bias,
                                            const float* __restrict__ A_log, float* __restrict__ dtA) {
    int idx = blockIdx.x * 256 + threadIdx.x;   // over BL*64
    int row = idx >> 6, j = idx & 63;
    float draw = b2f(zx[(size_t)row * NPAD + (DIN + CONV_DIM) + j]);
    float xb = draw + dt_bias[j & 31];
    float dt2 = (xb > 20.f) ? xb : log1pf(__expf(xb));
    dtA[(size_t)idx * 2]     = dt2;
    dtA[(size_t)idx * 2 + 1] = -__expf(A_log[j & 31]) * dt2;   // log dA
}

// ======================================================================
// Chunked SSD scan: block = (dir,b,h,chunk).  Q=128, DSTATE=64, HD=64.
// ======================================================================
__global__ __launch_bounds__(256) void k_chunk(const u16* __restrict__ xs, const float* __restrict__ BC,
                                               const float* __restrict__ dtA, u16* __restrict__ y0,
                                               u16* __restrict__ y1, float* __restrict__ wout,
                                               float* __restrict__ decay) {
    __shared__ __align__(16) u16 ab[18432];      // Cs [0,9216) stride 72, Bs [9216,18432); S overlays, stride 136
    __shared__ __align__(16) u16 XT[64 * 136];   // X^T [p][s]
    __shared__ __align__(16) float dts_s[128];
    __shared__ __align__(16) float lda_s[128];
    __shared__ __align__(16) double cumd[128];

    const int blk = blockIdx.x;
    const int c = blk & 15, dbh = blk >> 4;
    const int h = dbh & 31, b = (dbh >> 5) & 3, dir = dbh >> 7;
    const int tid = threadIdx.x, w = tid >> 6, lane = tid & 63, lr = lane & 15, lq = lane >> 4;
    const int s0 = c * QC;
    u16* yo = dir ? y1 : y0;

    if (tid < 128) {
        int s = s0 + tid;
        int t = dir ? (L_ - 1 - s) : s;
        size_t di = ((size_t)(b * L_ + t) * 64 + dir * 32 + h) * 2;
        dts_s[tid] = dtA[di];
        lda_s[tid] = dtA[di + 1];
    }
    {   // stage Cs, Bs (bf16), XT (transposed)
        int sl0 = tid >> 3, ng = (tid & 7) * 8;
        #pragma unroll
        for (int it = 0; it < 4; it++) {
            int sl = sl0 + it * 32;
            int s = s0 + sl;
            int t = dir ? (L_ - 1 - s) : s;
            size_t row = (size_t)b * L_ + t;
            const float* bcr = BC + row * 128;
            float f[8];
            float4 v0 = *(const float4*)(bcr + 64 + ng);
            float4 v1 = *(const float4*)(bcr + 64 + ng + 4);
            f[0]=v0.x; f[1]=v0.y; f[2]=v0.z; f[3]=v0.w; f[4]=v1.x; f[5]=v1.y; f[6]=v1.z; f[7]=v1.w;
            *(uint4*)&ab[sl * 72 + ng] = pack8(f);
            v0 = *(const float4*)(bcr + ng);
            v1 = *(const float4*)(bcr + ng + 4);
            f[0]=v0.x; f[1]=v0.y; f[2]=v0.z; f[3]=v0.w; f[4]=v1.x; f[5]=v1.y; f[6]=v1.z; f[7]=v1.w;
            *(uint4*)&ab[9216 + sl * 72 + ng] = pack8(f);
            uint4 xv = *(const uint4*)(xs + row * DIN + h * 64 + ng);
            u16 xh[8] = {(u16)(xv.x & 0xffffu), (u16)(xv.x >> 16), (u16)(xv.y & 0xffffu), (u16)(xv.y >> 16),
                         (u16)(xv.z & 0xffffu), (u16)(xv.z >> 16), (u16)(xv.w & 0xffffu), (u16)(xv.w >> 16)};
            #pragma unroll
            for (int i = 0; i < 8; i++) XT[(ng + i) * 136 + sl] = xh[i];
        }
    }
    __syncthreads();
    if (w == 0) {   // double-precision inclusive prefix of log-dA (wave 0)
        double v0 = (double)lda_s[lane];
        double v1 = (double)lda_s[64 + lane];
        #pragma unroll
        for (int o = 1; o < 64; o <<= 1) {
            double t0 = __shfl_up(v0, o);
            double t1 = __shfl_up(v1, o);
            if (lane >= o) { v0 += t0; v1 += t1; }
        }
        double tot0 = __shfl(v0, 63);
        cumd[lane] = v0;
        cumd[64 + lane] = tot0 + v1;
    }
    // G = C * B^T  (wave w owns t-rows [w*32, w*32+32))
    bf16x8 af[2][2];
    #pragma unroll
    for (int ti = 0; ti < 2; ti++)
        #pragma unroll
        for (int ks = 0; ks < 2; ks++)
            af[ti][ks] = *(const bf16x8*)&ab[(w * 32 + ti * 16 + lr) * 72 + ks * 32 + lq * 8];
    f32x4 accg[2][8];
    #pragma unroll
    for (int ti = 0; ti < 2; ti++)
        #pragma unroll
        for (int si = 0; si < 8; si++) accg[ti][si] = (f32x4){0.f, 0.f, 0.f, 0.f};
    #pragma unroll
    for (int si = 0; si < 8; si++)
        #pragma unroll
        for (int ks = 0; ks < 2; ks++) {
            bf16x8 bf = *(const bf16x8*)&ab[9216 + (si * 16 + lr) * 72 + ks * 32 + lq * 8];
            accg[0][si] = __builtin_amdgcn_mfma_f32_16x16x32_bf16(af[0][ks], bf, accg[0][si], 0, 0, 0);
            accg[1][si] = __builtin_amdgcn_mfma_f32_16x16x32_bf16(af[1][ks], bf, accg[1][si], 0, 0, 0);
        }
    __syncthreads();   // all G frag reads done; cumd ready
    // S = M .* G  -> overlay into ab (stride 136)
    {
        double cumt_d[8];
        #pragma unroll
        for (int ti = 0; ti < 2; ti++)
            #pragma unroll
            for (int r = 0; r < 4; r++) cumt_d[ti * 4 + r] = cumd[w * 32 + ti * 16 + lq * 4 + r];
        double cums_d[8]; float dts_l[8];
        #pragma unroll
        for (int si = 0; si < 8; si++) { cums_d[si] = cumd[si * 16 + lr]; dts_l[si] = dts_s[si * 16 + lr]; }
        #pragma unroll
        for (int ti = 0; ti < 2; ti++)
            #pragma unroll
            for (int si = 0; si < 8; si++)
                #pragma unroll
                for (int r = 0; r < 4; r++) {
                    int t_l = w * 32 + ti * 16 + lq * 4 + r;
                    int s_l = si * 16 + lr;
                    float v = 0.f;
                    if (s_l <= t_l)
                        v = __expf((float)(cumt_d[ti * 4 + r] - cums_d[si])) * dts_l[si] * accg[ti][si][r];
                    ab[t_l * 136 + s_l] = f2b(v);
                }
    }
    __syncthreads();
    // Y_intra = S * X^T
    f32x4 acc[2][4];
    #pragma unroll
    for (int ti = 0; ti < 2; ti++)
        #pragma unroll
        for (int pj = 0; pj < 4; pj++) acc[ti][pj] = (f32x4){0.f, 0.f, 0.f, 0.f};
    #pragma unroll
    for (int ks = 0; ks < 4; ks++) {
        bf16x8 a0 = *(const bf16x8*)&ab[(w * 32 + lr) * 136 + ks * 32 + lq * 8];
        bf16x8 a1 = *(const bf16x8*)&ab[(w * 32 + 16 + lr) * 136 + ks * 32 + lq * 8];
        #pragma unroll
        for (int pj = 0; pj < 4; pj++) {
            bf16x8 bf = *(const bf16x8*)&XT[(pj * 16 + lr) * 136 + ks * 32 + lq * 8];
            acc[0][pj] = __builtin_amdgcn_mfma_f32_16x16x32_bf16(a0, bf, acc[0][pj], 0, 0, 0);
            acc[1][pj] = __builtin_amdgcn_mfma_f32_16x16x32_bf16(a1, bf, acc[1][pj], 0, 0, 0);
        }
    }
    #pragma unroll
    for (int ti = 0; ti < 2; ti++)
        #pragma unroll
        for (int pj = 0; pj < 4; pj++)
            #pragma unroll
            for (int r = 0; r < 4; r++) {
                int t_l = w * 32 + ti * 16 + lq * 4 + r;
                int s = s0 + t_l;
                int t = dir ? (L_ - 1 - s) : s;
                yo[((size_t)b * L_ + t) * DIN + h * 64 + pj * 16 + lr] = f2b(acc[ti][pj][r]);
            }
    if (tid < 128) wout[dbh * 2048 + s0 + tid] = __expf((float)cumd[tid]);
    if (tid == 0)  decay[blk] = __expf((float)cumd[127]);
}

// k_state: S_c[p][n] = sum_s exp(cumEnd-cum[s])*dt[s]*x[s][p]*B[s][n]  (bf16 out)
__global__ __launch_bounds__(256) void k_state(const u16* __restrict__ xs, const float* __restrict__ BC,
                                               const float* __restrict__ dtA, u16* __restrict__ scb) {
    __shared__ __align__(16) u16 XT[64 * 136];
    __shared__ __align__(16) u16 BT[64 * 136];
    __shared__ __align__(16) float dts_s[128];
    __shared__ __align__(16) float lda_s[128];
    __shared__ __align__(16) float wend[128];

    const int blk = blockIdx.x;
    const int c = blk & 15, dbh = blk >> 4;
    const int h = dbh & 31, b = (dbh >> 5) & 3, dir = dbh >> 7;
    const int tid = threadIdx.x, w = tid >> 6, lane = tid & 63, lr = lane & 15, lq = lane >> 4;
    const int s0 = c * QC;

    if (tid < 128) {
        int s = s0 + tid;
        int t = dir ? (L_ - 1 - s) : s;
        size_t di = ((size_t)(b * L_ + t) * 64 + dir * 32 + h) * 2;
        dts_s[tid] = dtA[di];
        lda_s[tid] = dtA[di + 1];
    }
    {
        int sl0 = tid >> 3, ng = (tid & 7) * 8;
        #pragma unroll
        for (int it = 0; it < 4; it++) {
            int sl = sl0 + it * 32;
            int s = s0 + sl;
            int t = dir ? (L_ - 1 - s) : s;
            size_t row = (size_t)b * L_ + t;
            const float* bcr = BC + row * 128;
            float4 v0 = *(const float4*)(bcr + ng);
            float4 v1 = *(const float4*)(bcr + ng + 4);
            float f[8] = {v0.x, v0.y, v0.z, v0.w, v1.x, v1.y, v1.z, v1.w};
            #pragma unroll
            for (int i = 0; i < 8; i++) BT[(ng + i) * 136 + sl] = f2b(f[i]);
            uint4 xv = *(const uint4*)(xs + row * DIN + h * 64 + ng);
            u16 xh[8] = {(u16)(xv.x & 0xffffu), (u16)(xv.x >> 16), (u16)(xv.y & 0xffffu), (u16)(xv.y >> 16),
                         (u16)(xv.z & 0xffffu), (u16)(xv.z >> 16), (u16)(xv.w & 0xffffu), (u16)(xv.w >> 16)};
            #pragma unroll
            for (int i = 0; i < 8; i++) XT[(ng + i) * 136 + sl] = xh[i];
        }
    }
    __syncthreads();
    if (w == 0) {
        double v0 = (double)lda_s[lane];
        double v1 = (double)lda_s[64 + lane];
        #pragma unroll
        for (int o = 1; o < 64; o <<= 1) {
            double t0 = __shfl_up(v0, o);
            double t1 = __shfl_up(v1, o);
            if (lane >= o) { v0 += t0; v1 += t1; }
        }
        double tot0 = __shfl(v0, 63);
        double tot  = tot0 + __shfl(v1, 63);
        wend[lane]      = __expf((float)(tot - v0)) * dts_s[lane];
        wend[64 + lane] = __expf((float)(tot - (tot0 + v1))) * dts_s[64 + lane];
    }
    __syncthreads();
    f32x4 acc[4];
    #pragma unroll
    for (int nj = 0; nj < 4; nj++) acc[nj] = (f32x4){0.f, 0.f, 0.f, 0.f};
    #pragma unroll
    for (int ks = 0; ks < 4; ks++) {
        uint4 xv = *(const uint4*)&XT[(w * 16 + lr) * 136 + ks * 32 + lq * 8];
        float xf[8]; unpack8(xv, xf);
        float4 w0 = *(const float4*)&wend[ks * 32 + lq * 8];
        float4 w1 = *(const float4*)&wend[ks * 32 + lq * 8 + 4];
        float fs[8] = {xf[0]*w0.x, xf[1]*w0.y, xf[2]*w0.z, xf[3]*w0.w,
                       xf[4]*w1.x, xf[5]*w1.y, xf[6]*w1.z, xf[7]*w1.w};
        bf16x8 a = __builtin_bit_cast(bf16x8, pack8(fs));
        #pragma unroll
        for (int nj = 0; nj < 4; nj++) {
            bf16x8 bb = *(const bf16x8*)&BT[(nj * 16 + lr) * 136 + ks * 32 + lq * 8];
            acc[nj] = __builtin_amdgcn_mfma_f32_16x16x32_bf16(a, bb, acc[nj], 0, 0, 0);
        }
    }
    #pragma unroll
    for (int nj = 0; nj < 4; nj++)
        #pragma unroll
        for (int r = 0; r < 4; r++) {
            int p = w * 16 + lq * 4 + r, n = nj * 16 + lr;
            scb[(size_t)blk * 4096 + p * 64 + n] = f2b(acc[nj][r]);
        }
}

// k_carry: sequential over 16 chunks: y_full = Y_intra + exp(cum)*C*h ; shift; h = decay*h + S_c
__global__ __launch_bounds__(256) void k_carry(const float* __restrict__ BC, const float* __restrict__ wout,
                                               const float* __restrict__ decay, const u16* __restrict__ scb,
                                               u16* __restrict__ y0, u16* __restrict__ y1) {
    __shared__ __align__(16) float hsh[64 * 68];     // h[p][n], row stride 68
    __shared__ __align__(16) u16 Csc[128 * 72];      // exp(cum[s])*C[s][n]
    __shared__ __align__(16) u16 ybs[128 * 72];      // y_full rows (bf16)
    __shared__ __align__(16) u16 prevu[72];
    const int dbh = blockIdx.x;
    const int h = dbh & 31, b = (dbh >> 5) & 3, dir = dbh >> 7;
    const int tid = threadIdx.x, w = tid >> 6, lane = tid & 63, lr = lane & 15, lq = lane >> 4;
    u16* yo = dir ? y1 : y0;

    for (int i = tid; i < 64 * 68; i += 256) hsh[i] = 0.f;
    if (tid < 72) prevu[tid] = 0;
    __syncthreads();
    const int sl0 = tid >> 3, ng = (tid & 7) * 8;
    for (int c = 0; c < NCH; c++) {
        #pragma unroll
        for (int it = 0; it < 4; it++) {
            int sl = sl0 + it * 32;
            int s = c * QC + sl;
            int t = dir ? (L_ - 1 - s) : s;
            const float* bcr = BC + ((size_t)b * L_ + t) * 128 + 64 + ng;
            float sc = wout[dbh * 2048 + s];
            float4 v0 = *(const float4*)bcr;
            float4 v1 = *(const float4*)(bcr + 4);
            float f[8] = {v0.x*sc, v0.y*sc, v0.z*sc, v0.w*sc, v1.x*sc, v1.y*sc, v1.z*sc, v1.w*sc};
            *(uint4*)&Csc[sl * 72 + ng] = pack8(f);
        }
        bf16x8 hb[4][2];
        #pragma unroll
        for (int pj = 0; pj < 4; pj++)
            #pragma unroll
            for (int ks = 0; ks < 2; ks++) {
                const float* hp = &hsh[(pj * 16 + lr) * 68 + ks * 32 + lq * 8];
                float4 a0 = *(const float4*)hp;
                float4 a1 = *(const float4*)(hp + 4);
                float f[8] = {a0.x, a0.y, a0.z, a0.w, a1.x, a1.y, a1.z, a1.w};
                hb[pj][ks] = __builtin_bit_cast(bf16x8, pack8(f));
            }
        __syncthreads();
        f32x4 acc[2][4];
        #pragma unroll
        for (int ti = 0; ti < 2; ti++)
            #pragma unroll
            for (int pj = 0; pj < 4; pj++) acc[ti][pj] = (f32x4){0.f, 0.f, 0.f, 0.f};
        #pragma unroll
        for (int ks = 0; ks < 2; ks++) {
            bf16x8 a0 = *(const bf16x8*)&Csc[(w * 32 + lr) * 72 + ks * 32 + lq * 8];
            bf16x8 a1 = *(const bf16x8*)&Csc[(w * 32 + 16 + lr) * 72 + ks * 32 + lq * 8];
            #pragma unroll
            for (int pj = 0; pj < 4; pj++) {
                acc[0][pj] = __builtin_amdgcn_mfma_f32_16x16x32_bf16(a0, hb[pj][ks], acc[0][pj], 0, 0, 0);
                acc[1][pj] = __builtin_amdgcn_mfma_f32_16x16x32_bf16(a1, hb[pj][ks], acc[1][pj], 0, 0, 0);
            }
        }
        #pragma unroll
        for (int ti = 0; ti < 2; ti++)
            #pragma unroll
            for (int pj = 0; pj < 4; pj++)
                #pragma unroll
                for (int r = 0; r < 4; r++) {
                    int t_l = w * 32 + ti * 16 + lq * 4 + r;
                    int s = c * QC + t_l;
                    int t = dir ? (L_ - 1 - s) : s;
                    float yv = acc[ti][pj][r] + b2f(yo[((size_t)b * L_ + t) * DIN + h * 64 + pj * 16 + lr]);
                    ybs[t_l * 72 + pj * 16 + lr] = f2b(yv);
                }
        {   // h = decay*h + S_c
            float dk = decay[dbh * 16 + c];
            const u16* sg = scb + ((size_t)(dbh * 16 + c)) * 4096 + tid * 16;
            uint4 q0 = *(const uint4*)sg;
            uint4 q1 = *(const uint4*)(sg + 8);
            float sf[16]; unpack8(q0, sf); unpack8(q1, sf + 8);
            int p = (tid * 16) >> 6, n0 = (tid * 16) & 63;
            float* hp = &hsh[p * 68 + n0];
            #pragma unroll
            for (int i = 0; i < 16; i++) hp[i] = dk * hp[i] + sf[i];
        }
        __syncthreads();
        #pragma unroll
        for (int it = 0; it < 4; it++) {
            int sl = sl0 + it * 32;
            int s = c * QC + sl;
            int t = dir ? (L_ - 1 - s) : s;
            const u16* src = (sl == 0) ? (prevu + ng) : &ybs[(sl - 1) * 72 + ng];
            *(uint4*)&yo[((size_t)b * L_ + t) * DIN + h * 64 + ng] = *(const uint4*)src;
        }
        __syncthreads();
        if (tid < 8) *(uint4*)&prevu[tid * 8] = *(const uint4*)&ybs[127 * 72 + tid * 8];
    }
}

// ---------- gate + RMSNorm -> bf16 (D-projection hoisted to k_dproj) ----------
__global__ __launch_bounds__(256) void k_gate(const u16* __restrict__ xs, const u16* __restrict__ zx,
                                              const u16* __restrict__ y0, const u16* __restrict__ y1,
                                              const float* __restrict__ Dd,
                                              const float* __restrict__ nw, u16* __restrict__ yn) {
    int row = blockIdx.x, tid = threadIdx.x;
    __shared__ float red[4];
    size_t base = (size_t)row * DIN;
    uint4 xv = ((const uint4*)(xs + base))[tid];
    uint4 zv = ((const uint4*)(zx + (size_t)row * NPAD))[tid];
    uint4 a0 = ((const uint4*)(y0 + base))[tid];
    uint4 a1 = ((const uint4*)(y1 + base))[tid];
    float sD = Dd[(size_t)row * 32 + (tid >> 3)];    // head = (tid*8)>>6
    float xf[8], zf[8], f0[8], f1[8];
    unpack8(xv, xf); unpack8(zv, zf); unpack8(a0, f0); unpack8(a1, f1);
    int d0 = tid * 8;
    float g[8]; float ss = 0.f;
    #pragma unroll
    for (int i = 0; i < 8; i++) {
        float yv = f0[i] + f1[i] + xf[i] * sD;
        float z = zf[i];
        float gg = yv * (z / (1.f + __expf(-z)));
        g[i] = gg; ss += gg * gg;
    }
    for (int o = 32; o; o >>= 1) ss += __shfl_down(ss, o);
    if ((tid & 63) == 0) red[tid >> 6] = ss;
    __syncthreads();
    float tot = red[0] + red[1] + red[2] + red[3];
    float r = rsqrtf(tot * (1.f / DIN) + EPS);
    float o8[8];
    #pragma unroll
    for (int i = 0; i < 8; i++) o8[i] = g[i] * r * nw[d0 + i];
    ((uint4*)(yn + base))[tid] = pack8(o8);
}

// ---------- workspace layout (bytes) ----------
#define OFF_U     ((size_t)0)                       // BL*DM bf16 (dead after GEMM1)
#define OFF_WIN   ((size_t)16777216)                // NPAD*DM bf16
#define OFF_WOUT  ((size_t)25690112)                // DM*DIN bf16
#define OFF_ZX    ((size_t)29884416)                // BL*NPAD bf16
#define OFF_XS    ((size_t)101187584)               // BL*DIN bf16
#define OFF_BC    ((size_t)134742016)               // BL*128 f32
#define OFF_DTA   ((size_t)138936320)               // BL*64*2 f32
#define OFF_Y0    ((size_t)143130624)               // BL*DIN bf16
#define OFF_Y1    ((size_t)176685056)               // BL*DIN bf16
#define OFF_YN    ((size_t)210239488)               // BL*DIN bf16 (gate out); scb aliases earlier
// aliases inside dead OFF_U region (all used only after GEMM1):
#define OFF_WO2   OFF_U                             // 256*2048 f32 = 2 MB
#define OFF_DEC   (OFF_U + 2097152)                 // 4096 f32
#define OFF_FCB   (OFF_U + 2113536)                 // NH*DIN bf16 = 128 KB
#define OFF_DD    (OFF_U + 2244608)                 // BL*32 f32 = 1 MB
#define OFF_SCB   OFF_YN                            // 4096*4096 bf16 = 33.5 MB
// total 243,793,920 bytes

extern "C" void kernel_launch(void* const* d_in, const int* in_sizes, int n_in,
                              void* d_out, int out_size, void* d_ws, size_t ws_size,
                              hipStream_t stream) {
    const float* x       = (const float*)d_in[0];
    const float* ln_g    = (const float*)d_in[1];
    const float* ln_b    = (const float*)d_in[2];
    const float* W_in    = (const float*)d_in[3];
    const float* conv_w  = (const float*)d_in[4];
    const float* conv_b  = (const float*)d_in[5];
    const float* dt_bias = (const float*)d_in[6];
    const float* A_log   = (const float*)d_in[7];
    const float* fc_D_w  = (const float*)d_in[8];
    const float* Dv      = (const float*)d_in[9];
    const float* norm_w  = (const float*)d_in[10];
    const float* W_out   = (const float*)d_in[11];

    char* ws = (char*)d_ws;
    u16*   u_bf  = (u16*)(ws + OFF_U);
    u16*   winb  = (u16*)(ws + OFF_WIN);
    u16*   woutb = (u16*)(ws + OFF_WOUT);
    u16*   zx    = (u16*)(ws + OFF_ZX);
    u16*   xs    = (u16*)(ws + OFF_XS);
    float* BC    = (float*)(ws + OFF_BC);
    float* dtA   = (float*)(ws + OFF_DTA);
    u16*   y0b   = (u16*)(ws + OFF_Y0);
    u16*   y1b   = (u16*)(ws + OFF_Y1);
    u16*   ynb   = (u16*)(ws + OFF_YN);
    float* wo2   = (float*)(ws + OFF_WO2);
    float* dec   = (float*)(ws + OFF_DEC);
    u16*   fcb   = (u16*)(ws + OFF_FCB);
    float* Dd    = (float*)(ws + OFF_DD);
    u16*   scb   = (u16*)(ws + OFF_SCB);

    k_cvt_win <<<(NPAD * DM) / 256, 256, 0, stream>>>(W_in, winb);
    k_cvt_wout<<<(DM * DIN) / 256, 256, 0, stream>>>(W_out, woutb);
    k_ln      <<<BL, 256, 0, stream>>>(x, ln_g, ln_b, u_bf);
    k_gemm_bt <<<dim3(NPAD / 128, BL / 128), 256, 0, stream>>>(u_bf, winb, BL, NPAD, DM, 1, zx, NPAD, nullptr, nullptr);
    k_cvt_fcd <<<(NH * DIN) / 256, 256, 0, stream>>>(fc_D_w, fcb);   // after GEMM1 (aliases u_bf region)
    k_conv    <<<dim3(CONV_DIM / 64, L_ / 256, B_), 256, 0, stream>>>(zx, conv_w, conv_b, xs, BC);
    k_dt      <<<(BL * 64) / 256, 256, 0, stream>>>(zx, dt_bias, A_log, dtA);
    k_dproj   <<<BL / 32, 256, 0, stream>>>(xs, fcb, Dv, Dd);
    k_chunk   <<<4096, 256, 0, stream>>>(xs, BC, dtA, y0b, y1b, wo2, dec);
    k_state   <<<4096, 256, 0, stream>>>(xs, BC, dtA, scb);
    k_carry   <<<256, 256, 0, stream>>>(BC, wo2, dec, scb, y0b, y1b);
    k_gate    <<<BL, 256, 0, stream>>>(xs, zx, y0b, y1b, Dd, norm_w, ynb);
    k_gemm_bt <<<dim3(DM / 128, BL / 128), 256, 0, stream>>>(ynb, woutb, BL, DM, DIN, 0, nullptr, DM, (float*)d_out, x);
}

// Round 4
// 567.548 us; speedup vs baseline: 3.5318x; 1.0468x over previous
//
#include <hip/hip_runtime.h>
#include <stdint.h>

// ---- problem constants ----
#define B_   4
#define L_   2048
#define DM   1024
#define DIN  2048
#define NH   32
#define HD   64
#define DSTATE 64
#define DCONV  7
#define CONV_DIM 2176            // DIN + 2*DSTATE
#define DPROJ 4288               // 2*DIN + 2*DSTATE + 2*NH
#define NPAD 4352                // DPROJ padded to 128
#define BL   8192                // B_*L_
#define EPS  1e-5f
#define QC   128                 // scan chunk length
#define NCH  16                  // chunks per sequence

typedef unsigned short u16;
typedef unsigned int   u32;
typedef __bf16 bf16x8 __attribute__((ext_vector_type(8)));
typedef float  f32x4  __attribute__((ext_vector_type(4)));

__device__ __forceinline__ float b2f(u32 b) { return __uint_as_float(b << 16); }
__device__ __forceinline__ u16 f2b(float f) {
    u32 u = __float_as_uint(f);
    u32 r = (u + 0x7fffu + ((u >> 16) & 1u)) >> 16;
    return (u16)r;
}
__device__ __forceinline__ void unpack8(uint4 v, float* f) {
    f[0] = b2f(v.x & 0xffffu); f[1] = b2f(v.x >> 16);
    f[2] = b2f(v.y & 0xffffu); f[3] = b2f(v.y >> 16);
    f[4] = b2f(v.z & 0xffffu); f[5] = b2f(v.z >> 16);
    f[6] = b2f(v.w & 0xffffu); f[7] = b2f(v.w >> 16);
}
__device__ __forceinline__ uint4 pack8(const float* f) {
    uint4 v;
    v.x = (u32)f2b(f[0]) | ((u32)f2b(f[1]) << 16);
    v.y = (u32)f2b(f[2]) | ((u32)f2b(f[3]) << 16);
    v.z = (u32)f2b(f[4]) | ((u32)f2b(f[5]) << 16);
    v.w = (u32)f2b(f[6]) | ((u32)f2b(f[7]) << 16);
    return v;
}
// async global->LDS, 16B per lane; lds base must be wave-uniform (HW adds lane*16)
__device__ __forceinline__ void gload_lds16(const u16* g, u16* l) {
    __builtin_amdgcn_global_load_lds((const __attribute__((address_space(1))) void*)g,
                                     (__attribute__((address_space(3))) void*)l, 16, 0, 0);
}

// ---------- weight conversion ----------
__global__ __launch_bounds__(256) void k_cvt_win(const float* __restrict__ W, u16* __restrict__ Wb) {
    int idx = blockIdx.x * 256 + threadIdx.x;      // over NPAD*DM
    int n = idx >> 10;                              // DM = 1024
    float v = (n < DPROJ) ? W[(size_t)n * DM + (idx & 1023)] : 0.f;
    Wb[idx] = f2b(v);
}
__global__ __launch_bounds__(256) void k_cvt_wout(const float* __restrict__ W, u16* __restrict__ Wb) {
    int idx = blockIdx.x * 256 + threadIdx.x;      // over DM*DIN
    Wb[idx] = f2b(W[idx]);
}
__global__ __launch_bounds__(256) void k_cvt_fcd(const float* __restrict__ W, u16* __restrict__ Wb) {
    int idx = blockIdx.x * 256 + threadIdx.x;      // over NH*DIN
    Wb[idx] = f2b(W[idx]);
}

// ---------- layernorm -> bf16 ----------
__global__ __launch_bounds__(256) void k_ln(const float* __restrict__ x, const float* __restrict__ g,
                                            const float* __restrict__ be, u16* __restrict__ u) {
    int row = blockIdx.x, tid = threadIdx.x;
    const float4* xr = (const float4*)(x + (size_t)row * DM);
    float4 v = xr[tid];
    float s1 = v.x + v.y + v.z + v.w;
    float s2 = v.x * v.x + v.y * v.y + v.z * v.z + v.w * v.w;
    for (int o = 32; o; o >>= 1) { s1 += __shfl_down(s1, o); s2 += __shfl_down(s2, o); }
    __shared__ float ls1[4], ls2[4];
    int w = tid >> 6;
    if ((tid & 63) == 0) { ls1[w] = s1; ls2[w] = s2; }
    __syncthreads();
    float t1 = ls1[0] + ls1[1] + ls1[2] + ls1[3];
    float t2 = ls2[0] + ls2[1] + ls2[2] + ls2[3];
    float mu = t1 * (1.f / DM);
    float var = t2 * (1.f / DM) - mu * mu;
    float rs = rsqrtf(var + EPS);
    float4 gv = ((const float4*)g)[tid];
    float4 bv = ((const float4*)be)[tid];
    float o0 = (v.x - mu) * rs * gv.x + bv.x;
    float o1 = (v.y - mu) * rs * gv.y + bv.y;
    float o2 = (v.z - mu) * rs * gv.z + bv.z;
    float o3 = (v.w - mu) * rs * gv.w + bv.w;
    uint2 p;
    p.x = (u32)f2b(o0) | ((u32)f2b(o1) << 16);
    p.y = (u32)f2b(o2) | ((u32)f2b(o3) << 16);
    ((uint2*)(u + (size_t)row * DM))[tid] = p;
}

// ---------- bf16 MFMA GEMM, C[m,n] = sum_k A[m,k]*B[n,k]  (B^T layout) ----------
// global_load_lds width=16 staging + XOR bank swizzle:
//   LDS slot (row, kc) holds global chunk (row, kc ^ ((row>>1)&3)); reads un-swizzle.
__global__ __launch_bounds__(256) void k_gemm_bt(const u16* __restrict__ A, const u16* __restrict__ Bw,
                                                 int M, int N, int K, int out_bf16,
                                                 u16* __restrict__ obf, int ldo,
                                                 float* __restrict__ ofp, const float* __restrict__ res) {
    __shared__ __align__(16) u16 As[128 * 32];
    __shared__ __align__(16) u16 Bs[128 * 32];
    int tid = threadIdx.x;
    int m0 = blockIdx.y * 128, n0 = blockIdx.x * 128;
    int w = tid >> 6, lane = tid & 63;
    int wm = (w >> 1) * 64, wn = (w & 1) * 64;
    int lr = lane & 15, lq = lane >> 4;

    f32x4 acc[4][4];
    #pragma unroll
    for (int i = 0; i < 4; i++)
        #pragma unroll
        for (int j = 0; j < 4; j++) acc[i][j] = (f32x4){0.f, 0.f, 0.f, 0.f};

    for (int kt = 0; kt < K; kt += 32) {
        #pragma unroll
        for (int it = 0; it < 2; it++) {
            int s_idx = it * 256 + tid;
            int row = s_idx >> 2;
            int kcg = (s_idx & 3) ^ ((row >> 1) & 3);     // swizzled source chunk
            u16* lbase_a = &As[(it * 256 + w * 64) * 8];  // wave-uniform
            u16* lbase_b = &Bs[(it * 256 + w * 64) * 8];
            gload_lds16(A + (size_t)(m0 + row) * K + kt + kcg * 8, lbase_a);
            gload_lds16(Bw + (size_t)(n0 + row) * K + kt + kcg * 8, lbase_b);
        }
        __syncthreads();
        bf16x8 af[4], bfr[4];
        #pragma unroll
        for (int i = 0; i < 4; i++) {
            int row = wm + 16 * i + lr;
            af[i] = *(const bf16x8*)&As[row * 32 + (lq ^ ((row >> 1) & 3)) * 8];
        }
        #pragma unroll
        for (int j = 0; j < 4; j++) {
            int row = wn + 16 * j + lr;
            bfr[j] = *(const bf16x8*)&Bs[row * 32 + (lq ^ ((row >> 1) & 3)) * 8];
        }
        #pragma unroll
        for (int i = 0; i < 4; i++)
            #pragma unroll
            for (int j = 0; j < 4; j++)
                acc[i][j] = __builtin_amdgcn_mfma_f32_16x16x32_bf16(af[i], bfr[j], acc[i][j], 0, 0, 0);
        __syncthreads();
    }
    #pragma unroll
    for (int i = 0; i < 4; i++) {
        #pragma unroll
        for (int j = 0; j < 4; j++) {
            #pragma unroll
            for (int rr = 0; rr < 4; rr++) {
                int m = m0 + wm + 16 * i + lq * 4 + rr;
                int n = n0 + wn + 16 * j + lr;
                float v = acc[i][j][rr];
                if (out_bf16) obf[(size_t)m * ldo + n] = f2b(v);
                else          ofp[(size_t)m * ldo + n] = v + res[(size_t)m * ldo + n];
            }
        }
    }
}

// ---------- D-projection GEMM: Dd[m][h] = dot(xs[m,:], fc_D_w[h,:]) + Dv[h] ----------
// padded LDS stride 72 u16 (144 B) -> conflict-free frag reads
__global__ __launch_bounds__(256) void k_dproj(const u16* __restrict__ xs, const u16* __restrict__ fcb,
                                               const float* __restrict__ Dv, float* __restrict__ Dd) {
    __shared__ __align__(16) u16 As[32 * 72];
    __shared__ __align__(16) u16 Bs[32 * 72];
    int tid = threadIdx.x;
    int m0 = blockIdx.x * 32;
    int w = tid >> 6, lane = tid & 63, lr = lane & 15, lq = lane >> 4;
    int mt = (w & 1) * 16, nt = (w >> 1) * 16;
    int r = tid >> 3, kc = tid & 7;
    f32x4 acc = (f32x4){0.f, 0.f, 0.f, 0.f};
    for (int kt = 0; kt < DIN; kt += 64) {
        *(uint4*)&As[r * 72 + kc * 8] = *(const uint4*)(xs + (size_t)(m0 + r) * DIN + kt + kc * 8);
        *(uint4*)&Bs[r * 72 + kc * 8] = *(const uint4*)(fcb + (size_t)r * DIN + kt + kc * 8);
        __syncthreads();
        #pragma unroll
        for (int ks = 0; ks < 2; ks++) {
            bf16x8 a = *(const bf16x8*)&As[(mt + lr) * 72 + ks * 32 + lq * 8];
            bf16x8 b = *(const bf16x8*)&Bs[(nt + lr) * 72 + ks * 32 + lq * 8];
            acc = __builtin_amdgcn_mfma_f32_16x16x32_bf16(a, b, acc, 0, 0, 0);
        }
        __syncthreads();
    }
    #pragma unroll
    for (int rr = 0; rr < 4; rr++) {
        int m = m0 + mt + lq * 4 + rr;
        int n = nt + lr;
        Dd[(size_t)m * 32 + n] = acc[rr] + Dv[n];
    }
}

// ---------- depthwise conv7 (same-pad) + bias + SiLU, split xs / BC ----------
__global__ __launch_bounds__(256) void k_conv(const u16* __restrict__ zx, const float* __restrict__ cw,
                                              const float* __restrict__ cb, u16* __restrict__ xs,
                                              float* __restrict__ BC) {
    __shared__ u16 sh[262 * 64];
    int c0 = blockIdx.x * 64, t0 = blockIdx.y * 256, b = blockIdx.z;
    int tid = threadIdx.x;
    int c = tid & 63, tg = tid >> 6;
    for (int it = 0; it < 66; it++) {
        int r = it * 4 + tg;
        if (r < 262) {
            int t = t0 + r - 3;
            u16 v = 0;
            if (t >= 0 && t < L_) v = zx[(size_t)(b * L_ + t) * NPAD + DIN + c0 + c];
            sh[r * 64 + c] = v;
        }
    }
    float wgt[7];
    #pragma unroll
    for (int k = 0; k < 7; k++) wgt[k] = cw[(c0 + c) * 7 + k];
    float bias = cb[c0 + c];
    __syncthreads();
    int cg = c0 + c;
    for (int tt = 0; tt < 64; tt++) {
        int tl = tt * 4 + tg;
        float a = bias;
        #pragma unroll
        for (int k = 0; k < 7; k++) a += b2f(sh[(tl + k) * 64 + c]) * wgt[k];
        float v = a / (1.f + __expf(-a));   // silu
        size_t row = (size_t)b * L_ + (t0 + tl);
        if (cg < DIN) xs[row * DIN + cg] = f2b(v);
        else          BC[row * 128 + (cg - DIN)] = v;   // B at [0,64), C at [64,128)
    }
}

// ---------- dt2 / log-dA precompute ----------
__global__ __launch_bounds__(256) void k_dt(const u16* __restrict__ zx, const float* __restrict__ dt_bias,
                                            const float* __restrict__ A_log, float* __restrict__ dtA) {
    int idx = blockIdx.x * 256 + threadIdx.x;   // over BL*64
    int row = idx >> 6, j = idx & 63;
    float draw = b2f(zx[(size_t)row * NPAD + (DIN + CONV_DIM) + j]);
    float xb = draw + dt_bias[j & 31];
    float dt2 = (xb > 20.f) ? xb : log1pf(__expf(xb));
    dtA[(size_t)idx * 2]     = dt2;
    dtA[(size_t)idx * 2 + 1] = -__expf(A_log[j & 31]) * dt2;   // log dA
}

// ======================================================================
// Chunked SSD scan (merged intra-chunk + chunk-state): block = (dir,b,h,chunk).
// G=C*B^T ; S=M.*G ; Y_intra=S*X ; S_c=(wend*X)^T*B ; writes Y_intra, scb, exp(cum), decay
// ======================================================================
__global__ __launch_bounds__(256) void k_chunk(const u16* __restrict__ xs, const float* __restrict__ BC,
                                               const float* __restrict__ dtA, u16* __restrict__ y0,
                                               u16* __restrict__ y1, float* __restrict__ wout,
                                               float* __restrict__ decay, u16* __restrict__ scb) {
    __shared__ __align__(16) u16 ab[18432];      // Cs [0,9216) stride 72, Bs [9216,18432); S overlays, stride 136
    __shared__ __align__(16) u16 XT[64 * 136];   // X^T [p][s]
    __shared__ __align__(16) u16 BT[64 * 136];   // B^T [n][s]
    __shared__ __align__(16) float dts_s[128];
    __shared__ __align__(16) float lda_s[128];
    __shared__ __align__(16) float wend[128];
    __shared__ __align__(16) double cumd[128];

    const int blk = blockIdx.x;
    const int c = blk & 15, dbh = blk >> 4;
    const int h = dbh & 31, b = (dbh >> 5) & 3, dir = dbh >> 7;
    const int tid = threadIdx.x, w = tid >> 6, lane = tid & 63, lr = lane & 15, lq = lane >> 4;
    const int s0 = c * QC;
    u16* yo = dir ? y1 : y0;

    if (tid < 128) {
        int s = s0 + tid;
        int t = dir ? (L_ - 1 - s) : s;
        size_t di = ((size_t)(b * L_ + t) * 64 + dir * 32 + h) * 2;
        dts_s[tid] = dtA[di];
        lda_s[tid] = dtA[di + 1];
    }
    {   // stage Cs, Bs (bf16 row-major), BT, XT (transposed)
        int sl0 = tid >> 3, ng = (tid & 7) * 8;
        #pragma unroll
        for (int it = 0; it < 4; it++) {
            int sl = sl0 + it * 32;
            int s = s0 + sl;
            int t = dir ? (L_ - 1 - s) : s;
            size_t row = (size_t)b * L_ + t;
            const float* bcr = BC + row * 128;
            float f[8];
            float4 v0 = *(const float4*)(bcr + 64 + ng);
            float4 v1 = *(const float4*)(bcr + 64 + ng + 4);
            f[0]=v0.x; f[1]=v0.y; f[2]=v0.z; f[3]=v0.w; f[4]=v1.x; f[5]=v1.y; f[6]=v1.z; f[7]=v1.w;
            *(uint4*)&ab[sl * 72 + ng] = pack8(f);
            v0 = *(const float4*)(bcr + ng);
            v1 = *(const float4*)(bcr + ng + 4);
            f[0]=v0.x; f[1]=v0.y; f[2]=v0.z; f[3]=v0.w; f[4]=v1.x; f[5]=v1.y; f[6]=v1.z; f[7]=v1.w;
            uint4 pb = pack8(f);
            *(uint4*)&ab[9216 + sl * 72 + ng] = pb;
            u16 bh[8] = {(u16)(pb.x & 0xffffu), (u16)(pb.x >> 16), (u16)(pb.y & 0xffffu), (u16)(pb.y >> 16),
                         (u16)(pb.z & 0xffffu), (u16)(pb.z >> 16), (u16)(pb.w & 0xffffu), (u16)(pb.w >> 16)};
            #pragma unroll
            for (int i = 0; i < 8; i++) BT[(ng + i) * 136 + sl] = bh[i];
            uint4 xv = *(const uint4*)(xs + row * DIN + h * 64 + ng);
            u16 xh[8] = {(u16)(xv.x & 0xffffu), (u16)(xv.x >> 16), (u16)(xv.y & 0xffffu), (u16)(xv.y >> 16),
                         (u16)(xv.z & 0xffffu), (u16)(xv.z >> 16), (u16)(xv.w & 0xffffu), (u16)(xv.w >> 16)};
            #pragma unroll
            for (int i = 0; i < 8; i++) XT[(ng + i) * 136 + sl] = xh[i];
        }
    }
    __syncthreads();
    if (w == 0) {   // double-precision inclusive prefix of log-dA (wave 0)
        double v0 = (double)lda_s[lane];
        double v1 = (double)lda_s[64 + lane];
        #pragma unroll
        for (int o = 1; o < 64; o <<= 1) {
            double t0 = __shfl_up(v0, o);
            double t1 = __shfl_up(v1, o);
            if (lane >= o) { v0 += t0; v1 += t1; }
        }
        double tot0 = __shfl(v0, 63);
        cumd[lane] = v0;
        cumd[64 + lane] = tot0 + v1;
    }
    // G = C * B^T  (wave w owns t-rows [w*32, w*32+32))
    bf16x8 af[2][2];
    #pragma unroll
    for (int ti = 0; ti < 2; ti++)
        #pragma unroll
        for (int ks = 0; ks < 2; ks++)
            af[ti][ks] = *(const bf16x8*)&ab[(w * 32 + ti * 16 + lr) * 72 + ks * 32 + lq * 8];
    f32x4 accg[2][8];
    #pragma unroll
    for (int ti = 0; ti < 2; ti++)
        #pragma unroll
        for (int si = 0; si < 8; si++) accg[ti][si] = (f32x4){0.f, 0.f, 0.f, 0.f};
    #pragma unroll
    for (int si = 0; si < 8; si++)
        #pragma unroll
        for (int ks = 0; ks < 2; ks++) {
            bf16x8 bf = *(const bf16x8*)&ab[9216 + (si * 16 + lr) * 72 + ks * 32 + lq * 8];
            accg[0][si] = __builtin_amdgcn_mfma_f32_16x16x32_bf16(af[0][ks], bf, accg[0][si], 0, 0, 0);
            accg[1][si] = __builtin_amdgcn_mfma_f32_16x16x32_bf16(af[1][ks], bf, accg[1][si], 0, 0, 0);
        }
    __syncthreads();   // all G frag reads done; cumd ready
    // wend[s] = exp(cum[127]-cum[s])*dt[s]  (for chunk-state); visible after next barrier
    if (tid < 128) wend[tid] = __expf((float)(cumd[127] - cumd[tid])) * dts_s[tid];
    // S = M .* G  -> overlay into ab (stride 136)
    {
        double cumt_d[8];
        #pragma unroll
        for (int ti = 0; ti < 2; ti++)
            #pragma unroll
            for (int r = 0; r < 4; r++) cumt_d[ti * 4 + r] = cumd[w * 32 + ti * 16 + lq * 4 + r];
        double cums_d[8]; float dts_l[8];
        #pragma unroll
        for (int si = 0; si < 8; si++) { cums_d[si] = cumd[si * 16 + lr]; dts_l[si] = dts_s[si * 16 + lr]; }
        #pragma unroll
        for (int ti = 0; ti < 2; ti++)
            #pragma unroll
            for (int si = 0; si < 8; si++)
                #pragma unroll
                for (int r = 0; r < 4; r++) {
                    int t_l = w * 32 + ti * 16 + lq * 4 + r;
                    int s_l = si * 16 + lr;
                    float v = 0.f;
                    if (s_l <= t_l)
                        v = __expf((float)(cumt_d[ti * 4 + r] - cums_d[si])) * dts_l[si] * accg[ti][si][r];
                    ab[t_l * 136 + s_l] = f2b(v);
                }
    }
    __syncthreads();
    // Y_intra = S * X^T
    f32x4 acc[2][4];
    #pragma unroll
    for (int ti = 0; ti < 2; ti++)
        #pragma unroll
        for (int pj = 0; pj < 4; pj++) acc[ti][pj] = (f32x4){0.f, 0.f, 0.f, 0.f};
    #pragma unroll
    for (int ks = 0; ks < 4; ks++) {
        bf16x8 a0 = *(const bf16x8*)&ab[(w * 32 + lr) * 136 + ks * 32 + lq * 8];
        bf16x8 a1 = *(const bf16x8*)&ab[(w * 32 + 16 + lr) * 136 + ks * 32 + lq * 8];
        #pragma unroll
        for (int pj = 0; pj < 4; pj++) {
            bf16x8 bf = *(const bf16x8*)&XT[(pj * 16 + lr) * 136 + ks * 32 + lq * 8];
            acc[0][pj] = __builtin_amdgcn_mfma_f32_16x16x32_bf16(a0, bf, acc[0][pj], 0, 0, 0);
            acc[1][pj] = __builtin_amdgcn_mfma_f32_16x16x32_bf16(a1, bf, acc[1][pj], 0, 0, 0);
        }
    }
    #pragma unroll
    for (int ti = 0; ti < 2; ti++)
        #pragma unroll
        for (int pj = 0; pj < 4; pj++)
            #pragma unroll
            for (int r = 0; r < 4; r++) {
                int t_l = w * 32 + ti * 16 + lq * 4 + r;
                int s = s0 + t_l;
                int t = dir ? (L_ - 1 - s) : s;
                yo[((size_t)b * L_ + t) * DIN + h * 64 + pj * 16 + lr] = f2b(acc[ti][pj][r]);
            }
    // chunk state S_c[p][n] = sum_s wend[s]*x[s][p]*B[s][n]  (wave w owns p-rows [w*16,w*16+16))
    f32x4 accs[4];
    #pragma unroll
    for (int nj = 0; nj < 4; nj++) accs[nj] = (f32x4){0.f, 0.f, 0.f, 0.f};
    #pragma unroll
    for (int ks = 0; ks < 4; ks++) {
        uint4 xv = *(const uint4*)&XT[(w * 16 + lr) * 136 + ks * 32 + lq * 8];
        float xf[8]; unpack8(xv, xf);
        float4 w0 = *(const float4*)&wend[ks * 32 + lq * 8];
        float4 w1 = *(const float4*)&wend[ks * 32 + lq * 8 + 4];
        float fs[8] = {xf[0]*w0.x, xf[1]*w0.y, xf[2]*w0.z, xf[3]*w0.w,
                       xf[4]*w1.x, xf[5]*w1.y, xf[6]*w1.z, xf[7]*w1.w};
        bf16x8 a = __builtin_bit_cast(bf16x8, pack8(fs));
        #pragma unroll
        for (int nj = 0; nj < 4; nj++) {
            bf16x8 bb = *(const bf16x8*)&BT[(nj * 16 + lr) * 136 + ks * 32 + lq * 8];
            accs[nj] = __builtin_amdgcn_mfma_f32_16x16x32_bf16(a, bb, accs[nj], 0, 0, 0);
        }
    }
    #pragma unroll
    for (int nj = 0; nj < 4; nj++)
        #pragma unroll
        for (int r = 0; r < 4; r++) {
            int p = w * 16 + lq * 4 + r, n = nj * 16 + lr;
            scb[(size_t)blk * 4096 + p * 64 + n] = f2b(accs[nj][r]);
        }
    if (tid < 128) wout[dbh * 2048 + s0 + tid] = __expf((float)cumd[tid]);
    if (tid == 0)  decay[blk] = __expf((float)cumd[127]);
}

// k_carry: sequential over 16 chunks: y_full = Y_intra + exp(cum)*C*h ; shift; h = decay*h + S_c
__global__ __launch_bounds__(256) void k_carry(const float* __restrict__ BC, const float* __restrict__ wout,
                                               const float* __restrict__ decay, const u16* __restrict__ scb,
                                               u16* __restrict__ y0, u16* __restrict__ y1) {
    __shared__ __align__(16) float hsh[64 * 68];     // h[p][n], row stride 68
    __shared__ __align__(16) u16 Csc[128 * 72];      // exp(cum[s])*C[s][n]
    __shared__ __align__(16) u16 ybs[128 * 72];      // y_full rows (bf16)
    __shared__ __align__(16) u16 prevu[72];
    const int dbh = blockIdx.x;
    const int h = dbh & 31, b = (dbh >> 5) & 3, dir = dbh >> 7;
    const int tid = threadIdx.x, w = tid >> 6, lane = tid & 63, lr = lane & 15, lq = lane >> 4;
    u16* yo = dir ? y1 : y0;

    for (int i = tid; i < 64 * 68; i += 256) hsh[i] = 0.f;
    if (tid < 72) prevu[tid] = 0;
    __syncthreads();
    const int sl0 = tid >> 3, ng = (tid & 7) * 8;
    for (int c = 0; c < NCH; c++) {
        #pragma unroll
        for (int it = 0; it < 4; it++) {
            int sl = sl0 + it * 32;
            int s = c * QC + sl;
            int t = dir ? (L_ - 1 - s) : s;
            const float* bcr = BC + ((size_t)b * L_ + t) * 128 + 64 + ng;
            float sc = wout[dbh * 2048 + s];
            float4 v0 = *(const float4*)bcr;
            float4 v1 = *(const float4*)(bcr + 4);
            float f[8] = {v0.x*sc, v0.y*sc, v0.z*sc, v0.w*sc, v1.x*sc, v1.y*sc, v1.z*sc, v1.w*sc};
            *(uint4*)&Csc[sl * 72 + ng] = pack8(f);
        }
        bf16x8 hb[4][2];
        #pragma unroll
        for (int pj = 0; pj < 4; pj++)
            #pragma unroll
            for (int ks = 0; ks < 2; ks++) {
                const float* hp = &hsh[(pj * 16 + lr) * 68 + ks * 32 + lq * 8];
                float4 a0 = *(const float4*)hp;
                float4 a1 = *(const float4*)(hp + 4);
                float f[8] = {a0.x, a0.y, a0.z, a0.w, a1.x, a1.y, a1.z, a1.w};
                hb[pj][ks] = __builtin_bit_cast(bf16x8, pack8(f));
            }
        __syncthreads();
        f32x4 acc[2][4];
        #pragma unroll
        for (int ti = 0; ti < 2; ti++)
            #pragma unroll
            for (int pj = 0; pj < 4; pj++) acc[ti][pj] = (f32x4){0.f, 0.f, 0.f, 0.f};
        #pragma unroll
        for (int ks = 0; ks < 2; ks++) {
            bf16x8 a0 = *(const bf16x8*)&Csc[(w * 32 + lr) * 72 + ks * 32 + lq * 8];
            bf16x8 a1 = *(const bf16x8*)&Csc[(w * 32 + 16 + lr) * 72 + ks * 32 + lq * 8];
            #pragma unroll
            for (int pj = 0; pj < 4; pj++) {
                acc[0][pj] = __builtin_amdgcn_mfma_f32_16x16x32_bf16(a0, hb[pj][ks], acc[0][pj], 0, 0, 0);
                acc[1][pj] = __builtin_amdgcn_mfma_f32_16x16x32_bf16(a1, hb[pj][ks], acc[1][pj], 0, 0, 0);
            }
        }
        #pragma unroll
        for (int ti = 0; ti < 2; ti++)
            #pragma unroll
            for (int pj = 0; pj < 4; pj++)
                #pragma unroll
                for (int r = 0; r < 4; r++) {
                    int t_l = w * 32 + ti * 16 + lq * 4 + r;
                    int s = c * QC + t_l;
                    int t = dir ? (L_ - 1 - s) : s;
                    float yv = acc[ti][pj][r] + b2f(yo[((size_t)b * L_ + t) * DIN + h * 64 + pj * 16 + lr]);
                    ybs[t_l * 72 + pj * 16 + lr] = f2b(yv);
                }
        {   // h = decay*h + S_c
            float dk = decay[dbh * 16 + c];
            const u16* sg = scb + ((size_t)(dbh * 16 + c)) * 4096 + tid * 16;
            uint4 q0 = *(const uint4*)sg;
            uint4 q1 = *(const uint4*)(sg + 8);
            float sf[16]; unpack8(q0, sf); unpack8(q1, sf + 8);
            int p = (tid * 16) >> 6, n0 = (tid * 16) & 63;
            float* hp = &hsh[p * 68 + n0];
            #pragma unroll
            for (int i = 0; i < 16; i++) hp[i] = dk * hp[i] + sf[i];
        }
        __syncthreads();
        #pragma unroll
        for (int it = 0; it < 4; it++) {
            int sl = sl0 + it * 32;
            int s = c * QC + sl;
            int t = dir ? (L_ - 1 - s) : s;
            const u16* src = (sl == 0) ? (prevu + ng) : &ybs[(sl - 1) * 72 + ng];
            *(uint4*)&yo[((size_t)b * L_ + t) * DIN + h * 64 + ng] = *(const uint4*)src;
        }
        __syncthreads();
        if (tid < 8) *(uint4*)&prevu[tid * 8] = *(const uint4*)&ybs[127 * 72 + tid * 8];
    }
}

// ---------- gate + RMSNorm -> bf16 ----------
__global__ __launch_bounds__(256) void k_gate(const u16* __restrict__ xs, const u16* __restrict__ zx,
                                              const u16* __restrict__ y0, const u16* __restrict__ y1,
                                              const float* __restrict__ Dd,
                                              const float* __restrict__ nw, u16* __restrict__ yn) {
    int row = blockIdx.x, tid = threadIdx.x;
    __shared__ float red[4];
    size_t base = (size_t)row * DIN;
    uint4 xv = ((const uint4*)(xs + base))[tid];
    uint4 zv = ((const uint4*)(zx + (size_t)row * NPAD))[tid];
    uint4 a0 = ((const uint4*)(y0 + base))[tid];
    uint4 a1 = ((const uint4*)(y1 + base))[tid];
    float sD = Dd[(size_t)row * 32 + (tid >> 3)];    // head = (tid*8)>>6
    float xf[8], zf[8], f0[8], f1[8];
    unpack8(xv, xf); unpack8(zv, zf); unpack8(a0, f0); unpack8(a1, f1);
    int d0 = tid * 8;
    float g[8]; float ss = 0.f;
    #pragma unroll
    for (int i = 0; i < 8; i++) {
        float yv = f0[i] + f1[i] + xf[i] * sD;
        float z = zf[i];
        float gg = yv * (z / (1.f + __expf(-z)));
        g[i] = gg; ss += gg * gg;
    }
    for (int o = 32; o; o >>= 1) ss += __shfl_down(ss, o);
    if ((tid & 63) == 0) red[tid >> 6] = ss;
    __syncthreads();
    float tot = red[0] + red[1] + red[2] + red[3];
    float r = rsqrtf(tot * (1.f / DIN) + EPS);
    float o8[8];
    #pragma unroll
    for (int i = 0; i < 8; i++) o8[i] = g[i] * r * nw[d0 + i];
    ((uint4*)(yn + base))[tid] = pack8(o8);
}

// ---------- workspace layout (bytes) ----------
#define OFF_U     ((size_t)0)                       // BL*DM bf16 (dead after GEMM1)
#define OFF_WIN   ((size_t)16777216)                // NPAD*DM bf16
#define OFF_WOUT  ((size_t)25690112)                // DM*DIN bf16
#define OFF_ZX    ((size_t)29884416)                // BL*NPAD bf16
#define OFF_XS    ((size_t)101187584)               // BL*DIN bf16
#define OFF_BC    ((size_t)134742016)               // BL*128 f32
#define OFF_DTA   ((size_t)138936320)               // BL*64*2 f32
#define OFF_Y0    ((size_t)143130624)               // BL*DIN bf16
#define OFF_Y1    ((size_t)176685056)               // BL*DIN bf16
#define OFF_YN    ((size_t)210239488)               // BL*DIN bf16 (gate out); scb aliases earlier
// aliases inside dead OFF_U region (all used only after GEMM1):
#define OFF_WO2   OFF_U                             // 256*2048 f32 = 2 MB
#define OFF_DEC   (OFF_U + 2097152)                 // 4096 f32
#define OFF_FCB   (OFF_U + 2113536)                 // NH*DIN bf16 = 128 KB
#define OFF_DD    (OFF_U + 2244608)                 // BL*32 f32 = 1 MB
#define OFF_SCB   OFF_YN                            // 4096*4096 bf16 = 33.5 MB
// total 243,793,920 bytes

extern "C" void kernel_launch(void* const* d_in, const int* in_sizes, int n_in,
                              void* d_out, int out_size, void* d_ws, size_t ws_size,
                              hipStream_t stream) {
    const float* x       = (const float*)d_in[0];
    const float* ln_g    = (const float*)d_in[1];
    const float* ln_b    = (const float*)d_in[2];
    const float* W_in    = (const float*)d_in[3];
    const float* conv_w  = (const float*)d_in[4];
    const float* conv_b  = (const float*)d_in[5];
    const float* dt_bias = (const float*)d_in[6];
    const float* A_log   = (const float*)d_in[7];
    const float* fc_D_w  = (const float*)d_in[8];
    const float* Dv      = (const float*)d_in[9];
    const float* norm_w  = (const float*)d_in[10];
    const float* W_out   = (const float*)d_in[11];

    char* ws = (char*)d_ws;
    u16*   u_bf  = (u16*)(ws + OFF_U);
    u16*   winb  = (u16*)(ws + OFF_WIN);
    u16*   woutb = (u16*)(ws + OFF_WOUT);
    u16*   zx    = (u16*)(ws + OFF_ZX);
    u16*   xs    = (u16*)(ws + OFF_XS);
    float* BC    = (float*)(ws + OFF_BC);
    float* dtA   = (float*)(ws + OFF_DTA);
    u16*   y0b   = (u16*)(ws + OFF_Y0);
    u16*   y1b   = (u16*)(ws + OFF_Y1);
    u16*   ynb   = (u16*)(ws + OFF_YN);
    float* wo2   = (float*)(ws + OFF_WO2);
    float* dec   = (float*)(ws + OFF_DEC);
    u16*   fcb   = (u16*)(ws + OFF_FCB);
    float* Dd    = (float*)(ws + OFF_DD);
    u16*   scb   = (u16*)(ws + OFF_SCB);

    k_cvt_win <<<(NPAD * DM) / 256, 256, 0, stream>>>(W_in, winb);
    k_cvt_wout<<<(DM * DIN) / 256, 256, 0, stream>>>(W_out, woutb);
    k_ln      <<<BL, 256, 0, stream>>>(x, ln_g, ln_b, u_bf);
    k_gemm_bt <<<dim3(NPAD / 128, BL / 128), 256, 0, stream>>>(u_bf, winb, BL, NPAD, DM, 1, zx, NPAD, nullptr, nullptr);
    k_cvt_fcd <<<(NH * DIN) / 256, 256, 0, stream>>>(fc_D_w, fcb);   // after GEMM1 (aliases u_bf region)
    k_conv    <<<dim3(CONV_DIM / 64, L_ / 256, B_), 256, 0, stream>>>(zx, conv_w, conv_b, xs, BC);
    k_dt      <<<(BL * 64) / 256, 256, 0, stream>>>(zx, dt_bias, A_log, dtA);
    k_dproj   <<<BL / 32, 256, 0, stream>>>(xs, fcb, Dv, Dd);
    k_chunk   <<<4096, 256, 0, stream>>>(xs, BC, dtA, y0b, y1b, wo2, dec, scb);
    k_carry   <<<256, 256, 0, stream>>>(BC, wo2, dec, scb, y0b, y1b);
    k_gate    <<<BL, 256, 0, stream>>>(xs, zx, y0b, y1b, Dd, norm_w, ynb);
    k_gemm_bt <<<dim3(DM / 128, BL / 128), 256, 0, stream>>>(ynb, woutb, BL, DM, DIN, 0, nullptr, DM, (float*)d_out, x);
}

// Round 5
// 545.793 us; speedup vs baseline: 3.6726x; 1.0399x over previous
//
#include <hip/hip_runtime.h>
#include <stdint.h>

// ---- problem constants ----
#define B_   4
#define L_   2048
#define DM   1024
#define DIN  2048
#define NH   32
#define HD   64
#define DSTATE 64
#define DCONV  7
#define CONV_DIM 2176            // DIN + 2*DSTATE
#define DPROJ 4288               // 2*DIN + 2*DSTATE + 2*NH
#define NPAD 4352                // DPROJ padded to 128
#define BL   8192                // B_*L_
#define EPS  1e-5f
#define QC   128                 // scan chunk length
#define NCH  16                  // chunks per sequence

typedef unsigned short u16;
typedef unsigned int   u32;
typedef __bf16 bf16x8 __attribute__((ext_vector_type(8)));
typedef float  f32x4  __attribute__((ext_vector_type(4)));

__device__ __forceinline__ float b2f(u32 b) { return __uint_as_float(b << 16); }
__device__ __forceinline__ u16 f2b(float f) {
    u32 u = __float_as_uint(f);
    u32 r = (u + 0x7fffu + ((u >> 16) & 1u)) >> 16;
    return (u16)r;
}
__device__ __forceinline__ void unpack8(uint4 v, float* f) {
    f[0] = b2f(v.x & 0xffffu); f[1] = b2f(v.x >> 16);
    f[2] = b2f(v.y & 0xffffu); f[3] = b2f(v.y >> 16);
    f[4] = b2f(v.z & 0xffffu); f[5] = b2f(v.z >> 16);
    f[6] = b2f(v.w & 0xffffu); f[7] = b2f(v.w >> 16);
}
__device__ __forceinline__ uint4 pack8(const float* f) {
    uint4 v;
    v.x = (u32)f2b(f[0]) | ((u32)f2b(f[1]) << 16);
    v.y = (u32)f2b(f[2]) | ((u32)f2b(f[3]) << 16);
    v.z = (u32)f2b(f[4]) | ((u32)f2b(f[5]) << 16);
    v.w = (u32)f2b(f[6]) | ((u32)f2b(f[7]) << 16);
    return v;
}
// async global->LDS, 16B per lane; lds base must be wave-uniform (HW adds lane*16)
__device__ __forceinline__ void gload_lds16(const u16* g, u16* l) {
    __builtin_amdgcn_global_load_lds((const __attribute__((address_space(1))) void*)g,
                                     (__attribute__((address_space(3))) void*)l, 16, 0, 0);
}

// ---------- weight conversion ----------
__global__ __launch_bounds__(256) void k_cvt_win(const float* __restrict__ W, u16* __restrict__ Wb) {
    int idx = blockIdx.x * 256 + threadIdx.x;      // over NPAD*DM
    int n = idx >> 10;                              // DM = 1024
    float v = (n < DPROJ) ? W[(size_t)n * DM + (idx & 1023)] : 0.f;
    Wb[idx] = f2b(v);
}
__global__ __launch_bounds__(256) void k_cvt_wout(const float* __restrict__ W, u16* __restrict__ Wb) {
    int idx = blockIdx.x * 256 + threadIdx.x;      // over DM*DIN
    Wb[idx] = f2b(W[idx]);
}
__global__ __launch_bounds__(256) void k_cvt_fcd(const float* __restrict__ W, u16* __restrict__ Wb) {
    int idx = blockIdx.x * 256 + threadIdx.x;      // over NH*DIN
    Wb[idx] = f2b(W[idx]);
}

// ---------- layernorm -> bf16 ----------
__global__ __launch_bounds__(256) void k_ln(const float* __restrict__ x, const float* __restrict__ g,
                                            const float* __restrict__ be, u16* __restrict__ u) {
    int row = blockIdx.x, tid = threadIdx.x;
    const float4* xr = (const float4*)(x + (size_t)row * DM);
    float4 v = xr[tid];
    float s1 = v.x + v.y + v.z + v.w;
    float s2 = v.x * v.x + v.y * v.y + v.z * v.z + v.w * v.w;
    for (int o = 32; o; o >>= 1) { s1 += __shfl_down(s1, o); s2 += __shfl_down(s2, o); }
    __shared__ float ls1[4], ls2[4];
    int w = tid >> 6;
    if ((tid & 63) == 0) { ls1[w] = s1; ls2[w] = s2; }
    __syncthreads();
    float t1 = ls1[0] + ls1[1] + ls1[2] + ls1[3];
    float t2 = ls2[0] + ls2[1] + ls2[2] + ls2[3];
    float mu = t1 * (1.f / DM);
    float var = t2 * (1.f / DM) - mu * mu;
    float rs = rsqrtf(var + EPS);
    float4 gv = ((const float4*)g)[tid];
    float4 bv = ((const float4*)be)[tid];
    float o0 = (v.x - mu) * rs * gv.x + bv.x;
    float o1 = (v.y - mu) * rs * gv.y + bv.y;
    float o2 = (v.z - mu) * rs * gv.z + bv.z;
    float o3 = (v.w - mu) * rs * gv.w + bv.w;
    uint2 p;
    p.x = (u32)f2b(o0) | ((u32)f2b(o1) << 16);
    p.y = (u32)f2b(o2) | ((u32)f2b(o3) << 16);
    ((uint2*)(u + (size_t)row * DM))[tid] = p;
}

// ---------- bf16 MFMA GEMM, C[m,n] = sum_k A[m,k]*B[n,k]  (B^T layout) ----------
// BK=64: halves barrier-drain frequency vs BK=32 (the m97-structure stall).
// global_load_lds width=16 staging + XOR swizzle over 8 granules:
//   LDS slot (row, kc) holds global chunk kc ^ (row&7); reads un-swizzle.
__global__ __launch_bounds__(256) void k_gemm_bt(const u16* __restrict__ A, const u16* __restrict__ Bw,
                                                 int M, int N, int K, int out_bf16,
                                                 u16* __restrict__ obf, int ldo,
                                                 float* __restrict__ ofp, const float* __restrict__ res) {
    __shared__ __align__(16) u16 As[128 * 64];
    __shared__ __align__(16) u16 Bs[128 * 64];
    int tid = threadIdx.x;
    int m0 = blockIdx.y * 128, n0 = blockIdx.x * 128;
    int w = tid >> 6, lane = tid & 63;
    int wm = (w >> 1) * 64, wn = (w & 1) * 64;
    int lr = lane & 15, lq = lane >> 4;

    f32x4 acc[4][4];
    #pragma unroll
    for (int i = 0; i < 4; i++)
        #pragma unroll
        for (int j = 0; j < 4; j++) acc[i][j] = (f32x4){0.f, 0.f, 0.f, 0.f};

    for (int kt = 0; kt < K; kt += 64) {
        #pragma unroll
        for (int it = 0; it < 4; it++) {
            int s_idx = it * 256 + tid;
            int row = s_idx >> 3;
            int kcg = (s_idx & 7) ^ (row & 7);            // swizzled source chunk
            u16* lbase_a = &As[(it * 256 + w * 64) * 8];  // wave-uniform
            u16* lbase_b = &Bs[(it * 256 + w * 64) * 8];
            gload_lds16(A + (size_t)(m0 + row) * K + kt + kcg * 8, lbase_a);
            gload_lds16(Bw + (size_t)(n0 + row) * K + kt + kcg * 8, lbase_b);
        }
        __syncthreads();
        #pragma unroll
        for (int kk = 0; kk < 2; kk++) {
            bf16x8 af[4], bfr[4];
            #pragma unroll
            for (int i = 0; i < 4; i++) {
                int row = wm + 16 * i + lr;
                af[i] = *(const bf16x8*)&As[row * 64 + (((kk * 4 + lq)) ^ (row & 7)) * 8];
            }
            #pragma unroll
            for (int j = 0; j < 4; j++) {
                int row = wn + 16 * j + lr;
                bfr[j] = *(const bf16x8*)&Bs[row * 64 + (((kk * 4 + lq)) ^ (row & 7)) * 8];
            }
            #pragma unroll
            for (int i = 0; i < 4; i++)
                #pragma unroll
                for (int j = 0; j < 4; j++)
                    acc[i][j] = __builtin_amdgcn_mfma_f32_16x16x32_bf16(af[i], bfr[j], acc[i][j], 0, 0, 0);
        }
        __syncthreads();
    }
    #pragma unroll
    for (int i = 0; i < 4; i++) {
        #pragma unroll
        for (int j = 0; j < 4; j++) {
            #pragma unroll
            for (int rr = 0; rr < 4; rr++) {
                int m = m0 + wm + 16 * i + lq * 4 + rr;
                int n = n0 + wn + 16 * j + lr;
                float v = acc[i][j][rr];
                if (out_bf16) obf[(size_t)m * ldo + n] = f2b(v);
                else          ofp[(size_t)m * ldo + n] = v + res[(size_t)m * ldo + n];
            }
        }
    }
}

// ---------- D-projection GEMM: Dd[m][h] = dot(xs[m,:], fc_D_w[h,:]) + Dv[h] ----------
__global__ __launch_bounds__(256) void k_dproj(const u16* __restrict__ xs, const u16* __restrict__ fcb,
                                               const float* __restrict__ Dv, float* __restrict__ Dd) {
    __shared__ __align__(16) u16 As[32 * 72];
    __shared__ __align__(16) u16 Bs[32 * 72];
    int tid = threadIdx.x;
    int m0 = blockIdx.x * 32;
    int w = tid >> 6, lane = tid & 63, lr = lane & 15, lq = lane >> 4;
    int mt = (w & 1) * 16, nt = (w >> 1) * 16;
    int r = tid >> 3, kc = tid & 7;
    f32x4 acc = (f32x4){0.f, 0.f, 0.f, 0.f};
    for (int kt = 0; kt < DIN; kt += 64) {
        *(uint4*)&As[r * 72 + kc * 8] = *(const uint4*)(xs + (size_t)(m0 + r) * DIN + kt + kc * 8);
        *(uint4*)&Bs[r * 72 + kc * 8] = *(const uint4*)(fcb + (size_t)r * DIN + kt + kc * 8);
        __syncthreads();
        #pragma unroll
        for (int ks = 0; ks < 2; ks++) {
            bf16x8 a = *(const bf16x8*)&As[(mt + lr) * 72 + ks * 32 + lq * 8];
            bf16x8 b = *(const bf16x8*)&Bs[(nt + lr) * 72 + ks * 32 + lq * 8];
            acc = __builtin_amdgcn_mfma_f32_16x16x32_bf16(a, b, acc, 0, 0, 0);
        }
        __syncthreads();
    }
    #pragma unroll
    for (int rr = 0; rr < 4; rr++) {
        int m = m0 + mt + lq * 4 + rr;
        int n = nt + lr;
        Dd[(size_t)m * 32 + n] = acc[rr] + Dv[n];
    }
}

// ---------- depthwise conv7 (same-pad) + bias + SiLU, split xs / BC(bf16) ----------
__global__ __launch_bounds__(256) void k_conv(const u16* __restrict__ zx, const float* __restrict__ cw,
                                              const float* __restrict__ cb, u16* __restrict__ xs,
                                              u16* __restrict__ BCb) {
    __shared__ u16 sh[262 * 64];
    int c0 = blockIdx.x * 64, t0 = blockIdx.y * 256, b = blockIdx.z;
    int tid = threadIdx.x;
    int c = tid & 63, tg = tid >> 6;
    for (int it = 0; it < 66; it++) {
        int r = it * 4 + tg;
        if (r < 262) {
            int t = t0 + r - 3;
            u16 v = 0;
            if (t >= 0 && t < L_) v = zx[(size_t)(b * L_ + t) * NPAD + DIN + c0 + c];
            sh[r * 64 + c] = v;
        }
    }
    float wgt[7];
    #pragma unroll
    for (int k = 0; k < 7; k++) wgt[k] = cw[(c0 + c) * 7 + k];
    float bias = cb[c0 + c];
    __syncthreads();
    int cg = c0 + c;
    for (int tt = 0; tt < 64; tt++) {
        int tl = tt * 4 + tg;
        float a = bias;
        #pragma unroll
        for (int k = 0; k < 7; k++) a += b2f(sh[(tl + k) * 64 + c]) * wgt[k];
        float v = a / (1.f + __expf(-a));   // silu
        size_t row = (size_t)b * L_ + (t0 + tl);
        if (cg < DIN) xs[row * DIN + cg] = f2b(v);
        else          BCb[row * 128 + (cg - DIN)] = f2b(v);   // B at [0,64), C at [64,128), bf16
    }
}

// ---------- dt2 / log-dA precompute ----------
__global__ __launch_bounds__(256) void k_dt(const u16* __restrict__ zx, const float* __restrict__ dt_bias,
                                            const float* __restrict__ A_log, float* __restrict__ dtA) {
    int idx = blockIdx.x * 256 + threadIdx.x;   // over BL*64
    int row = idx >> 6, j = idx & 63;
    float draw = b2f(zx[(size_t)row * NPAD + (DIN + CONV_DIM) + j]);
    float xb = draw + dt_bias[j & 31];
    float dt2 = (xb > 20.f) ? xb : log1pf(__expf(xb));
    dtA[(size_t)idx * 2]     = dt2;
    dtA[(size_t)idx * 2 + 1] = -__expf(A_log[j & 31]) * dt2;   // log dA
}

// ======================================================================
// Chunked SSD scan (merged intra-chunk + chunk-state): block = (dir,b,h,chunk).
// G=C*B^T ; S=M.*G ; Y_intra=S*X ; S_c=(wend*X)^T*B ; writes Y_intra, scb, exp(cum), decay
// ======================================================================
__global__ __launch_bounds__(256) void k_chunk(const u16* __restrict__ xs, const u16* __restrict__ BCb,
                                               const float* __restrict__ dtA, u16* __restrict__ y0,
                                               u16* __restrict__ y1, float* __restrict__ wout,
                                               float* __restrict__ decay, u16* __restrict__ scb) {
    __shared__ __align__(16) u16 ab[18432];      // Cs [0,9216) stride 72, Bs [9216,18432); S overlays, stride 136
    __shared__ __align__(16) u16 XT[64 * 136];   // X^T [p][s]
    __shared__ __align__(16) u16 BT[64 * 136];   // B^T [n][s]
    __shared__ __align__(16) float dts_s[128];
    __shared__ __align__(16) float lda_s[128];
    __shared__ __align__(16) float wend[128];
    __shared__ __align__(16) double cumd[128];

    const int blk = blockIdx.x;
    const int c = blk & 15, dbh = blk >> 4;
    const int h = dbh & 31, b = (dbh >> 5) & 3, dir = dbh >> 7;
    const int tid = threadIdx.x, w = tid >> 6, lane = tid & 63, lr = lane & 15, lq = lane >> 4;
    const int s0 = c * QC;
    u16* yo = dir ? y1 : y0;

    if (tid < 128) {
        int s = s0 + tid;
        int t = dir ? (L_ - 1 - s) : s;
        size_t di = ((size_t)(b * L_ + t) * 64 + dir * 32 + h) * 2;
        dts_s[tid] = dtA[di];
        lda_s[tid] = dtA[di + 1];
    }
    {   // stage Cs, Bs (bf16 row-major), BT, XT (transposed)
        int sl0 = tid >> 3, ng = (tid & 7) * 8;
        #pragma unroll
        for (int it = 0; it < 4; it++) {
            int sl = sl0 + it * 32;
            int s = s0 + sl;
            int t = dir ? (L_ - 1 - s) : s;
            size_t row = (size_t)b * L_ + t;
            const u16* bcr = BCb + row * 128;
            uint4 cv = *(const uint4*)(bcr + 64 + ng);
            *(uint4*)&ab[sl * 72 + ng] = cv;
            uint4 pb = *(const uint4*)(bcr + ng);
            *(uint4*)&ab[9216 + sl * 72 + ng] = pb;
            u16 bh[8] = {(u16)(pb.x & 0xffffu), (u16)(pb.x >> 16), (u16)(pb.y & 0xffffu), (u16)(pb.y >> 16),
                         (u16)(pb.z & 0xffffu), (u16)(pb.z >> 16), (u16)(pb.w & 0xffffu), (u16)(pb.w >> 16)};
            #pragma unroll
            for (int i = 0; i < 8; i++) BT[(ng + i) * 136 + sl] = bh[i];
            uint4 xv = *(const uint4*)(xs + row * DIN + h * 64 + ng);
            u16 xh[8] = {(u16)(xv.x & 0xffffu), (u16)(xv.x >> 16), (u16)(xv.y & 0xffffu), (u16)(xv.y >> 16),
                         (u16)(xv.z & 0xffffu), (u16)(xv.z >> 16), (u16)(xv.w & 0xffffu), (u16)(xv.w >> 16)};
            #pragma unroll
            for (int i = 0; i < 8; i++) XT[(ng + i) * 136 + sl] = xh[i];
        }
    }
    __syncthreads();
    if (w == 0) {   // double-precision inclusive prefix of log-dA (wave 0)
        double v0 = (double)lda_s[lane];
        double v1 = (double)lda_s[64 + lane];
        #pragma unroll
        for (int o = 1; o < 64; o <<= 1) {
            double t0 = __shfl_up(v0, o);
            double t1 = __shfl_up(v1, o);
            if (lane >= o) { v0 += t0; v1 += t1; }
        }
        double tot0 = __shfl(v0, 63);
        cumd[lane] = v0;
        cumd[64 + lane] = tot0 + v1;
    }
    // G = C * B^T  (wave w owns t-rows [w*32, w*32+32))
    bf16x8 af[2][2];
    #pragma unroll
    for (int ti = 0; ti < 2; ti++)
        #pragma unroll
        for (int ks = 0; ks < 2; ks++)
            af[ti][ks] = *(const bf16x8*)&ab[(w * 32 + ti * 16 + lr) * 72 + ks * 32 + lq * 8];
    f32x4 accg[2][8];
    #pragma unroll
    for (int ti = 0; ti < 2; ti++)
        #pragma unroll
        for (int si = 0; si < 8; si++) accg[ti][si] = (f32x4){0.f, 0.f, 0.f, 0.f};
    #pragma unroll
    for (int si = 0; si < 8; si++)
        #pragma unroll
        for (int ks = 0; ks < 2; ks++) {
            bf16x8 bf = *(const bf16x8*)&ab[9216 + (si * 16 + lr) * 72 + ks * 32 + lq * 8];
            accg[0][si] = __builtin_amdgcn_mfma_f32_16x16x32_bf16(af[0][ks], bf, accg[0][si], 0, 0, 0);
            accg[1][si] = __builtin_amdgcn_mfma_f32_16x16x32_bf16(af[1][ks], bf, accg[1][si], 0, 0, 0);
        }
    __syncthreads();   // all G frag reads done; cumd ready
    // wend[s] = exp(cum[127]-cum[s])*dt[s]  (for chunk-state); visible after next barrier
    if (tid < 128) wend[tid] = __expf((float)(cumd[127] - cumd[tid])) * dts_s[tid];
    // S = M .* G  -> overlay into ab (stride 136)
    {
        double cumt_d[8];
        #pragma unroll
        for (int ti = 0; ti < 2; ti++)
            #pragma unroll
            for (int r = 0; r < 4; r++) cumt_d[ti * 4 + r] = cumd[w * 32 + ti * 16 + lq * 4 + r];
        double cums_d[8]; float dts_l[8];
        #pragma unroll
        for (int si = 0; si < 8; si++) { cums_d[si] = cumd[si * 16 + lr]; dts_l[si] = dts_s[si * 16 + lr]; }
        #pragma unroll
        for (int ti = 0; ti < 2; ti++)
            #pragma unroll
            for (int si = 0; si < 8; si++)
                #pragma unroll
                for (int r = 0; r < 4; r++) {
                    int t_l = w * 32 + ti * 16 + lq * 4 + r;
                    int s_l = si * 16 + lr;
                    float v = 0.f;
                    if (s_l <= t_l)
                        v = __expf((float)(cumt_d[ti * 4 + r] - cums_d[si])) * dts_l[si] * accg[ti][si][r];
                    ab[t_l * 136 + s_l] = f2b(v);
                }
    }
    __syncthreads();
    // Y_intra = S * X^T
    f32x4 acc[2][4];
    #pragma unroll
    for (int ti = 0; ti < 2; ti++)
        #pragma unroll
        for (int pj = 0; pj < 4; pj++) acc[ti][pj] = (f32x4){0.f, 0.f, 0.f, 0.f};
    #pragma unroll
    for (int ks = 0; ks < 4; ks++) {
        bf16x8 a0 = *(const bf16x8*)&ab[(w * 32 + lr) * 136 + ks * 32 + lq * 8];
        bf16x8 a1 = *(const bf16x8*)&ab[(w * 32 + 16 + lr) * 136 + ks * 32 + lq * 8];
        #pragma unroll
        for (int pj = 0; pj < 4; pj++) {
            bf16x8 bf = *(const bf16x8*)&XT[(pj * 16 + lr) * 136 + ks * 32 + lq * 8];
            acc[0][pj] = __builtin_amdgcn_mfma_f32_16x16x32_bf16(a0, bf, acc[0][pj], 0, 0, 0);
            acc[1][pj] = __builtin_amdgcn_mfma_f32_16x16x32_bf16(a1, bf, acc[1][pj], 0, 0, 0);
        }
    }
    #pragma unroll
    for (int ti = 0; ti < 2; ti++)
        #pragma unroll
        for (int pj = 0; pj < 4; pj++)
            #pragma unroll
            for (int r = 0; r < 4; r++) {
                int t_l = w * 32 + ti * 16 + lq * 4 + r;
                int s = s0 + t_l;
                int t = dir ? (L_ - 1 - s) : s;
                yo[((size_t)b * L_ + t) * DIN + h * 64 + pj * 16 + lr] = f2b(acc[ti][pj][r]);
            }
    // chunk state S_c[p][n] = sum_s wend[s]*x[s][p]*B[s][n]  (wave w owns p-rows [w*16,w*16+16))
    f32x4 accs[4];
    #pragma unroll
    for (int nj = 0; nj < 4; nj++) accs[nj] = (f32x4){0.f, 0.f, 0.f, 0.f};
    #pragma unroll
    for (int ks = 0; ks < 4; ks++) {
        uint4 xv = *(const uint4*)&XT[(w * 16 + lr) * 136 + ks * 32 + lq * 8];
        float xf[8]; unpack8(xv, xf);
        float4 w0 = *(const float4*)&wend[ks * 32 + lq * 8];
        float4 w1 = *(const float4*)&wend[ks * 32 + lq * 8 + 4];
        float fs[8] = {xf[0]*w0.x, xf[1]*w0.y, xf[2]*w0.z, xf[3]*w0.w,
                       xf[4]*w1.x, xf[5]*w1.y, xf[6]*w1.z, xf[7]*w1.w};
        bf16x8 a = __builtin_bit_cast(bf16x8, pack8(fs));
        #pragma unroll
        for (int nj = 0; nj < 4; nj++) {
            bf16x8 bb = *(const bf16x8*)&BT[(nj * 16 + lr) * 136 + ks * 32 + lq * 8];
            accs[nj] = __builtin_amdgcn_mfma_f32_16x16x32_bf16(a, bb, accs[nj], 0, 0, 0);
        }
    }
    #pragma unroll
    for (int nj = 0; nj < 4; nj++)
        #pragma unroll
        for (int r = 0; r < 4; r++) {
            int p = w * 16 + lq * 4 + r, n = nj * 16 + lr;
            scb[(size_t)blk * 4096 + p * 64 + n] = f2b(accs[nj][r]);
        }
    if (tid < 128) wout[dbh * 2048 + s0 + tid] = __expf((float)cumd[tid]);
    if (tid == 0)  decay[blk] = __expf((float)cumd[127]);
}

// k_carry: sequential over 16 chunks: y_full = Y_intra + exp(cum)*C*h ; shift; h = decay*h + S_c
__global__ __launch_bounds__(256) void k_carry(const u16* __restrict__ BCb, const float* __restrict__ wout,
                                               const float* __restrict__ decay, const u16* __restrict__ scb,
                                               u16* __restrict__ y0, u16* __restrict__ y1) {
    __shared__ __align__(16) float hsh[64 * 68];     // h[p][n], row stride 68
    __shared__ __align__(16) u16 Csc[128 * 72];      // exp(cum[s])*C[s][n]
    __shared__ __align__(16) u16 ybs[128 * 72];      // y_full rows (bf16)
    __shared__ __align__(16) u16 prevu[72];
    const int dbh = blockIdx.x;
    const int h = dbh & 31, b = (dbh >> 5) & 3, dir = dbh >> 7;
    const int tid = threadIdx.x, w = tid >> 6, lane = tid & 63, lr = lane & 15, lq = lane >> 4;
    u16* yo = dir ? y1 : y0;

    for (int i = tid; i < 64 * 68; i += 256) hsh[i] = 0.f;
    if (tid < 72) prevu[tid] = 0;
    __syncthreads();
    const int sl0 = tid >> 3, ng = (tid & 7) * 8;
    for (int c = 0; c < NCH; c++) {
        #pragma unroll
        for (int it = 0; it < 4; it++) {
            int sl = sl0 + it * 32;
            int s = c * QC + sl;
            int t = dir ? (L_ - 1 - s) : s;
            const u16* bcr = BCb + ((size_t)b * L_ + t) * 128 + 64 + ng;
            float sc = wout[dbh * 2048 + s];
            uint4 cv = *(const uint4*)bcr;
            float cf[8]; unpack8(cv, cf);
            float f[8] = {cf[0]*sc, cf[1]*sc, cf[2]*sc, cf[3]*sc, cf[4]*sc, cf[5]*sc, cf[6]*sc, cf[7]*sc};
            *(uint4*)&Csc[sl * 72 + ng] = pack8(f);
        }
        bf16x8 hb[4][2];
        #pragma unroll
        for (int pj = 0; pj < 4; pj++)
            #pragma unroll
            for (int ks = 0; ks < 2; ks++) {
                const float* hp = &hsh[(pj * 16 + lr) * 68 + ks * 32 + lq * 8];
                float4 a0 = *(const float4*)hp;
                float4 a1 = *(const float4*)(hp + 4);
                float f[8] = {a0.x, a0.y, a0.z, a0.w, a1.x, a1.y, a1.z, a1.w};
                hb[pj][ks] = __builtin_bit_cast(bf16x8, pack8(f));
            }
        __syncthreads();
        f32x4 acc[2][4];
        #pragma unroll
        for (int ti = 0; ti < 2; ti++)
            #pragma unroll
            for (int pj = 0; pj < 4; pj++) acc[ti][pj] = (f32x4){0.f, 0.f, 0.f, 0.f};
        #pragma unroll
        for (int ks = 0; ks < 2; ks++) {
            bf16x8 a0 = *(const bf16x8*)&Csc[(w * 32 + lr) * 72 + ks * 32 + lq * 8];
            bf16x8 a1 = *(const bf16x8*)&Csc[(w * 32 + 16 + lr) * 72 + ks * 32 + lq * 8];
            #pragma unroll
            for (int pj = 0; pj < 4; pj++) {
                acc[0][pj] = __builtin_amdgcn_mfma_f32_16x16x32_bf16(a0, hb[pj][ks], acc[0][pj], 0, 0, 0);
                acc[1][pj] = __builtin_amdgcn_mfma_f32_16x16x32_bf16(a1, hb[pj][ks], acc[1][pj], 0, 0, 0);
            }
        }
        #pragma unroll
        for (int ti = 0; ti < 2; ti++)
            #pragma unroll
            for (int pj = 0; pj < 4; pj++)
                #pragma unroll
                for (int r = 0; r < 4; r++) {
                    int t_l = w * 32 + ti * 16 + lq * 4 + r;
                    int s = c * QC + t_l;
                    int t = dir ? (L_ - 1 - s) : s;
                    float yv = acc[ti][pj][r] + b2f(yo[((size_t)b * L_ + t) * DIN + h * 64 + pj * 16 + lr]);
                    ybs[t_l * 72 + pj * 16 + lr] = f2b(yv);
                }
        {   // h = decay*h + S_c
            float dk = decay[dbh * 16 + c];
            const u16* sg = scb + ((size_t)(dbh * 16 + c)) * 4096 + tid * 16;
            uint4 q0 = *(const uint4*)sg;
            uint4 q1 = *(const uint4*)(sg + 8);
            float sf[16]; unpack8(q0, sf); unpack8(q1, sf + 8);
            int p = (tid * 16) >> 6, n0 = (tid * 16) & 63;
            float* hp = &hsh[p * 68 + n0];
            #pragma unroll
            for (int i = 0; i < 16; i++) hp[i] = dk * hp[i] + sf[i];
        }
        __syncthreads();
        #pragma unroll
        for (int it = 0; it < 4; it++) {
            int sl = sl0 + it * 32;
            int s = c * QC + sl;
            int t = dir ? (L_ - 1 - s) : s;
            const u16* src = (sl == 0) ? (prevu + ng) : &ybs[(sl - 1) * 72 + ng];
            *(uint4*)&yo[((size_t)b * L_ + t) * DIN + h * 64 + ng] = *(const uint4*)src;
        }
        __syncthreads();
        if (tid < 8) *(uint4*)&prevu[tid * 8] = *(const uint4*)&ybs[127 * 72 + tid * 8];
    }
}

// ---------- gate + RMSNorm -> bf16 ----------
__global__ __launch_bounds__(256) void k_gate(const u16* __restrict__ xs, const u16* __restrict__ zx,
                                              const u16* __restrict__ y0, const u16* __restrict__ y1,
                                              const float* __restrict__ Dd,
                                              const float* __restrict__ nw, u16* __restrict__ yn) {
    int row = blockIdx.x, tid = threadIdx.x;
    __shared__ float red[4];
    size_t base = (size_t)row * DIN;
    uint4 xv = ((const uint4*)(xs + base))[tid];
    uint4 zv = ((const uint4*)(zx + (size_t)row * NPAD))[tid];
    uint4 a0 = ((const uint4*)(y0 + base))[tid];
    uint4 a1 = ((const uint4*)(y1 + base))[tid];
    float sD = Dd[(size_t)row * 32 + (tid >> 3)];    // head = (tid*8)>>6
    float xf[8], zf[8], f0[8], f1[8];
    unpack8(xv, xf); unpack8(zv, zf); unpack8(a0, f0); unpack8(a1, f1);
    int d0 = tid * 8;
    float g[8]; float ss = 0.f;
    #pragma unroll
    for (int i = 0; i < 8; i++) {
        float yv = f0[i] + f1[i] + xf[i] * sD;
        float z = zf[i];
        float gg = yv * (z / (1.f + __expf(-z)));
        g[i] = gg; ss += gg * gg;
    }
    for (int o = 32; o; o >>= 1) ss += __shfl_down(ss, o);
    if ((tid & 63) == 0) red[tid >> 6] = ss;
    __syncthreads();
    float tot = red[0] + red[1] + red[2] + red[3];
    float r = rsqrtf(tot * (1.f / DIN) + EPS);
    float o8[8];
    #pragma unroll
    for (int i = 0; i < 8; i++) o8[i] = g[i] * r * nw[d0 + i];
    ((uint4*)(yn + base))[tid] = pack8(o8);
}

// ---------- workspace layout (bytes) ----------
#define OFF_U     ((size_t)0)                       // BL*DM bf16 (dead after GEMM1)
#define OFF_WIN   ((size_t)16777216)                // NPAD*DM bf16
#define OFF_WOUT  ((size_t)25690112)                // DM*DIN bf16
#define OFF_ZX    ((size_t)29884416)                // BL*NPAD bf16
#define OFF_XS    ((size_t)101187584)               // BL*DIN bf16
#define OFF_BC    ((size_t)134742016)               // BL*128 bf16 = 2 MB (half used)
#define OFF_DTA   ((size_t)138936320)               // BL*64*2 f32
#define OFF_Y0    ((size_t)143130624)               // BL*DIN bf16
#define OFF_Y1    ((size_t)176685056)               // BL*DIN bf16
#define OFF_YN    ((size_t)210239488)               // BL*DIN bf16 (gate out); scb aliases earlier
// aliases inside dead OFF_U region (all used only after GEMM1):
#define OFF_WO2   OFF_U                             // 256*2048 f32 = 2 MB
#define OFF_DEC   (OFF_U + 2097152)                 // 4096 f32
#define OFF_FCB   (OFF_U + 2113536)                 // NH*DIN bf16 = 128 KB
#define OFF_DD    (OFF_U + 2244608)                 // BL*32 f32 = 1 MB
#define OFF_SCB   OFF_YN                            // 4096*4096 bf16 = 33.5 MB
// total 243,793,920 bytes

extern "C" void kernel_launch(void* const* d_in, const int* in_sizes, int n_in,
                              void* d_out, int out_size, void* d_ws, size_t ws_size,
                              hipStream_t stream) {
    const float* x       = (const float*)d_in[0];
    const float* ln_g    = (const float*)d_in[1];
    const float* ln_b    = (const float*)d_in[2];
    const float* W_in    = (const float*)d_in[3];
    const float* conv_w  = (const float*)d_in[4];
    const float* conv_b  = (const float*)d_in[5];
    const float* dt_bias = (const float*)d_in[6];
    const float* A_log   = (const float*)d_in[7];
    const float* fc_D_w  = (const float*)d_in[8];
    const float* Dv      = (const float*)d_in[9];
    const float* norm_w  = (const float*)d_in[10];
    const float* W_out   = (const float*)d_in[11];

    char* ws = (char*)d_ws;
    u16*   u_bf  = (u16*)(ws + OFF_U);
    u16*   winb  = (u16*)(ws + OFF_WIN);
    u16*   woutb = (u16*)(ws + OFF_WOUT);
    u16*   zx    = (u16*)(ws + OFF_ZX);
    u16*   xs    = (u16*)(ws + OFF_XS);
    u16*   BCb   = (u16*)(ws + OFF_BC);
    float* dtA   = (float*)(ws + OFF_DTA);
    u16*   y0b   = (u16*)(ws + OFF_Y0);
    u16*   y1b   = (u16*)(ws + OFF_Y1);
    u16*   ynb   = (u16*)(ws + OFF_YN);
    float* wo2   = (float*)(ws + OFF_WO2);
    float* dec   = (float*)(ws + OFF_DEC);
    u16*   fcb   = (u16*)(ws + OFF_FCB);
    float* Dd    = (float*)(ws + OFF_DD);
    u16*   scb   = (u16*)(ws + OFF_SCB);

    k_cvt_win <<<(NPAD * DM) / 256, 256, 0, stream>>>(W_in, winb);
    k_cvt_wout<<<(DM * DIN) / 256, 256, 0, stream>>>(W_out, woutb);
    k_ln      <<<BL, 256, 0, stream>>>(x, ln_g, ln_b, u_bf);
    k_gemm_bt <<<dim3(NPAD / 128, BL / 128), 256, 0, stream>>>(u_bf, winb, BL, NPAD, DM, 1, zx, NPAD, nullptr, nullptr);
    k_cvt_fcd <<<(NH * DIN) / 256, 256, 0, stream>>>(fc_D_w, fcb);   // after GEMM1 (aliases u_bf region)
    k_conv    <<<dim3(CONV_DIM / 64, L_ / 256, B_), 256, 0, stream>>>(zx, conv_w, conv_b, xs, BCb);
    k_dt      <<<(BL * 64) / 256, 256, 0, stream>>>(zx, dt_bias, A_log, dtA);
    k_dproj   <<<BL / 32, 256, 0, stream>>>(xs, fcb, Dv, Dd);
    k_chunk   <<<4096, 256, 0, stream>>>(xs, BCb, dtA, y0b, y1b, wo2, dec, scb);
    k_carry   <<<256, 256, 0, stream>>>(BCb, wo2, dec, scb, y0b, y1b);
    k_gate    <<<BL, 256, 0, stream>>>(xs, zx, y0b, y1b, Dd, norm_w, ynb);
    k_gemm_bt <<<dim3(DM / 128, BL / 128), 256, 0, stream>>>(ynb, woutb, BL, DM, DIN, 0, nullptr, DM, (float*)d_out, x);
}

// Round 6
// 522.024 us; speedup vs baseline: 3.8398x; 1.0455x over previous
//
#include <hip/hip_runtime.h>
#include <stdint.h>

// ---- problem constants ----
#define B_   4
#define L_   2048
#define DM   1024
#define DIN  2048
#define NH   32
#define HD   64
#define DSTATE 64
#define DCONV  7
#define CONV_DIM 2176            // DIN + 2*DSTATE
#define DPROJ 4288               // 2*DIN + 2*DSTATE + 2*NH
#define NPAD 4352                // DPROJ padded to 128
#define BL   8192                // B_*L_
#define EPS  1e-5f
#define QC   128                 // scan chunk length
#define NCH  16                  // chunks per sequence

typedef unsigned short u16;
typedef unsigned int   u32;
typedef __bf16 bf16x8 __attribute__((ext_vector_type(8)));
typedef float  f32x4  __attribute__((ext_vector_type(4)));

__device__ __forceinline__ float b2f(u32 b) { return __uint_as_float(b << 16); }
__device__ __forceinline__ u16 f2b(float f) {
    u32 u = __float_as_uint(f);
    u32 r = (u + 0x7fffu + ((u >> 16) & 1u)) >> 16;
    return (u16)r;
}
__device__ __forceinline__ void unpack8(uint4 v, float* f) {
    f[0] = b2f(v.x & 0xffffu); f[1] = b2f(v.x >> 16);
    f[2] = b2f(v.y & 0xffffu); f[3] = b2f(v.y >> 16);
    f[4] = b2f(v.z & 0xffffu); f[5] = b2f(v.z >> 16);
    f[6] = b2f(v.w & 0xffffu); f[7] = b2f(v.w >> 16);
}
__device__ __forceinline__ uint4 pack8(const float* f) {
    uint4 v;
    v.x = (u32)f2b(f[0]) | ((u32)f2b(f[1]) << 16);
    v.y = (u32)f2b(f[2]) | ((u32)f2b(f[3]) << 16);
    v.z = (u32)f2b(f[4]) | ((u32)f2b(f[5]) << 16);
    v.w = (u32)f2b(f[6]) | ((u32)f2b(f[7]) << 16);
    return v;
}
// skewed LDS index for transposed tiles: row-stride 136 u16 + 8-u16 skew per 8 rows.
// Breaks the 16-way bank alias on column (transpose) writes; b128 reads stay 16B-aligned.
__device__ __forceinline__ int xts(int p, int s) { return p * 136 + ((p >> 3) << 3) + s; }
// async global->LDS, 16B per lane; lds base must be wave-uniform (HW adds lane*16)
__device__ __forceinline__ void gload_lds16(const u16* g, u16* l) {
    __builtin_amdgcn_global_load_lds((const __attribute__((address_space(1))) void*)g,
                                     (__attribute__((address_space(3))) void*)l, 16, 0, 0);
}

// ---------- weight conversion ----------
__global__ __launch_bounds__(256) void k_cvt_win(const float* __restrict__ W, u16* __restrict__ Wb) {
    int idx = blockIdx.x * 256 + threadIdx.x;      // over NPAD*DM
    int n = idx >> 10;                              // DM = 1024
    float v = (n < DPROJ) ? W[(size_t)n * DM + (idx & 1023)] : 0.f;
    Wb[idx] = f2b(v);
}
__global__ __launch_bounds__(256) void k_cvt_wout(const float* __restrict__ W, u16* __restrict__ Wb) {
    int idx = blockIdx.x * 256 + threadIdx.x;      // over DM*DIN
    Wb[idx] = f2b(W[idx]);
}
__global__ __launch_bounds__(256) void k_cvt_fcd(const float* __restrict__ W, u16* __restrict__ Wb) {
    int idx = blockIdx.x * 256 + threadIdx.x;      // over NH*DIN
    Wb[idx] = f2b(W[idx]);
}

// ---------- layernorm -> bf16 ----------
__global__ __launch_bounds__(256) void k_ln(const float* __restrict__ x, const float* __restrict__ g,
                                            const float* __restrict__ be, u16* __restrict__ u) {
    int row = blockIdx.x, tid = threadIdx.x;
    const float4* xr = (const float4*)(x + (size_t)row * DM);
    float4 v = xr[tid];
    float s1 = v.x + v.y + v.z + v.w;
    float s2 = v.x * v.x + v.y * v.y + v.z * v.z + v.w * v.w;
    for (int o = 32; o; o >>= 1) { s1 += __shfl_down(s1, o); s2 += __shfl_down(s2, o); }
    __shared__ float ls1[4], ls2[4];
    int w = tid >> 6;
    if ((tid & 63) == 0) { ls1[w] = s1; ls2[w] = s2; }
    __syncthreads();
    float t1 = ls1[0] + ls1[1] + ls1[2] + ls1[3];
    float t2 = ls2[0] + ls2[1] + ls2[2] + ls2[3];
    float mu = t1 * (1.f / DM);
    float var = t2 * (1.f / DM) - mu * mu;
    float rs = rsqrtf(var + EPS);
    float4 gv = ((const float4*)g)[tid];
    float4 bv = ((const float4*)be)[tid];
    float o0 = (v.x - mu) * rs * gv.x + bv.x;
    float o1 = (v.y - mu) * rs * gv.y + bv.y;
    float o2 = (v.z - mu) * rs * gv.z + bv.z;
    float o3 = (v.w - mu) * rs * gv.w + bv.w;
    uint2 p;
    p.x = (u32)f2b(o0) | ((u32)f2b(o1) << 16);
    p.y = (u32)f2b(o2) | ((u32)f2b(o3) << 16);
    ((uint2*)(u + (size_t)row * DM))[tid] = p;
}

// ---------- bf16 MFMA GEMM, C[m,n] = sum_k A[m,k]*B[n,k]  (B^T layout) ----------
// BK=64: halves barrier-drain frequency vs BK=32 (the m97-structure stall).
// global_load_lds width=16 staging + XOR swizzle over 8 granules:
//   LDS slot (row, kc) holds global chunk kc ^ (row&7); reads un-swizzle.
__global__ __launch_bounds__(256) void k_gemm_bt(const u16* __restrict__ A, const u16* __restrict__ Bw,
                                                 int M, int N, int K, int out_bf16,
                                                 u16* __restrict__ obf, int ldo,
                                                 float* __restrict__ ofp, const float* __restrict__ res) {
    __shared__ __align__(16) u16 As[128 * 64];
    __shared__ __align__(16) u16 Bs[128 * 64];
    int tid = threadIdx.x;
    int m0 = blockIdx.y * 128, n0 = blockIdx.x * 128;
    int w = tid >> 6, lane = tid & 63;
    int wm = (w >> 1) * 64, wn = (w & 1) * 64;
    int lr = lane & 15, lq = lane >> 4;

    f32x4 acc[4][4];
    #pragma unroll
    for (int i = 0; i < 4; i++)
        #pragma unroll
        for (int j = 0; j < 4; j++) acc[i][j] = (f32x4){0.f, 0.f, 0.f, 0.f};

    for (int kt = 0; kt < K; kt += 64) {
        #pragma unroll
        for (int it = 0; it < 4; it++) {
            int s_idx = it * 256 + tid;
            int row = s_idx >> 3;
            int kcg = (s_idx & 7) ^ (row & 7);            // swizzled source chunk
            u16* lbase_a = &As[(it * 256 + w * 64) * 8];  // wave-uniform
            u16* lbase_b = &Bs[(it * 256 + w * 64) * 8];
            gload_lds16(A + (size_t)(m0 + row) * K + kt + kcg * 8, lbase_a);
            gload_lds16(Bw + (size_t)(n0 + row) * K + kt + kcg * 8, lbase_b);
        }
        __syncthreads();
        #pragma unroll
        for (int kk = 0; kk < 2; kk++) {
            bf16x8 af[4], bfr[4];
            #pragma unroll
            for (int i = 0; i < 4; i++) {
                int row = wm + 16 * i + lr;
                af[i] = *(const bf16x8*)&As[row * 64 + (((kk * 4 + lq)) ^ (row & 7)) * 8];
            }
            #pragma unroll
            for (int j = 0; j < 4; j++) {
                int row = wn + 16 * j + lr;
                bfr[j] = *(const bf16x8*)&Bs[row * 64 + (((kk * 4 + lq)) ^ (row & 7)) * 8];
            }
            #pragma unroll
            for (int i = 0; i < 4; i++)
                #pragma unroll
                for (int j = 0; j < 4; j++)
                    acc[i][j] = __builtin_amdgcn_mfma_f32_16x16x32_bf16(af[i], bfr[j], acc[i][j], 0, 0, 0);
        }
        __syncthreads();
    }
    #pragma unroll
    for (int i = 0; i < 4; i++) {
        #pragma unroll
        for (int j = 0; j < 4; j++) {
            #pragma unroll
            for (int rr = 0; rr < 4; rr++) {
                int m = m0 + wm + 16 * i + lq * 4 + rr;
                int n = n0 + wn + 16 * j + lr;
                float v = acc[i][j][rr];
                if (out_bf16) obf[(size_t)m * ldo + n] = f2b(v);
                else          ofp[(size_t)m * ldo + n] = v + res[(size_t)m * ldo + n];
            }
        }
    }
}

// ---------- D-projection GEMM: Dd[m][h] = dot(xs[m,:], fc_D_w[h,:]) + Dv[h] ----------
__global__ __launch_bounds__(256) void k_dproj(const u16* __restrict__ xs, const u16* __restrict__ fcb,
                                               const float* __restrict__ Dv, float* __restrict__ Dd) {
    __shared__ __align__(16) u16 As[32 * 72];
    __shared__ __align__(16) u16 Bs[32 * 72];
    int tid = threadIdx.x;
    int m0 = blockIdx.x * 32;
    int w = tid >> 6, lane = tid & 63, lr = lane & 15, lq = lane >> 4;
    int mt = (w & 1) * 16, nt = (w >> 1) * 16;
    int r = tid >> 3, kc = tid & 7;
    f32x4 acc = (f32x4){0.f, 0.f, 0.f, 0.f};
    for (int kt = 0; kt < DIN; kt += 64) {
        *(uint4*)&As[r * 72 + kc * 8] = *(const uint4*)(xs + (size_t)(m0 + r) * DIN + kt + kc * 8);
        *(uint4*)&Bs[r * 72 + kc * 8] = *(const uint4*)(fcb + (size_t)r * DIN + kt + kc * 8);
        __syncthreads();
        #pragma unroll
        for (int ks = 0; ks < 2; ks++) {
            bf16x8 a = *(const bf16x8*)&As[(mt + lr) * 72 + ks * 32 + lq * 8];
            bf16x8 b = *(const bf16x8*)&Bs[(nt + lr) * 72 + ks * 32 + lq * 8];
            acc = __builtin_amdgcn_mfma_f32_16x16x32_bf16(a, b, acc, 0, 0, 0);
        }
        __syncthreads();
    }
    #pragma unroll
    for (int rr = 0; rr < 4; rr++) {
        int m = m0 + mt + lq * 4 + rr;
        int n = nt + lr;
        Dd[(size_t)m * 32 + n] = acc[rr] + Dv[n];
    }
}

// ---------- depthwise conv7 (same-pad) + bias + SiLU, split xs / BC(bf16) ----------
__global__ __launch_bounds__(256) void k_conv(const u16* __restrict__ zx, const float* __restrict__ cw,
                                              const float* __restrict__ cb, u16* __restrict__ xs,
                                              u16* __restrict__ BCb) {
    __shared__ u16 sh[262 * 64];
    int c0 = blockIdx.x * 64, t0 = blockIdx.y * 256, b = blockIdx.z;
    int tid = threadIdx.x;
    int c = tid & 63, tg = tid >> 6;
    for (int it = 0; it < 66; it++) {
        int r = it * 4 + tg;
        if (r < 262) {
            int t = t0 + r - 3;
            u16 v = 0;
            if (t >= 0 && t < L_) v = zx[(size_t)(b * L_ + t) * NPAD + DIN + c0 + c];
            sh[r * 64 + c] = v;
        }
    }
    float wgt[7];
    #pragma unroll
    for (int k = 0; k < 7; k++) wgt[k] = cw[(c0 + c) * 7 + k];
    float bias = cb[c0 + c];
    __syncthreads();
    int cg = c0 + c;
    for (int tt = 0; tt < 64; tt++) {
        int tl = tt * 4 + tg;
        float a = bias;
        #pragma unroll
        for (int k = 0; k < 7; k++) a += b2f(sh[(tl + k) * 64 + c]) * wgt[k];
        float v = a / (1.f + __expf(-a));   // silu
        size_t row = (size_t)b * L_ + (t0 + tl);
        if (cg < DIN) xs[row * DIN + cg] = f2b(v);
        else          BCb[row * 128 + (cg - DIN)] = f2b(v);   // B at [0,64), C at [64,128), bf16
    }
}

// ======================================================================
// Chunked SSD scan (intra-chunk + chunk-state + inline dt): block = (dir,b,h,chunk).
// dt2/logdA from zx inline; G=C*B^T ; S=M.*G ; Y_intra=S*X ; S_c=(wend*X)^T*B
// Skewed LDS layouts (xts) keep all transpose writes ~2-way bank-clean.
// ======================================================================
__global__ __launch_bounds__(256) void k_chunk(const u16* __restrict__ xs, const u16* __restrict__ BCb,
                                               const u16* __restrict__ zx, const float* __restrict__ dt_bias,
                                               const float* __restrict__ A_log, u16* __restrict__ y0,
                                               u16* __restrict__ y1, float* __restrict__ wout,
                                               float* __restrict__ decay, u16* __restrict__ scb) {
    __shared__ __align__(16) u16 ab[18432];      // Cs [0,9216) stride 72, Bs [9216,18432); S overlays (skewed 136)
    __shared__ __align__(16) u16 XT[8768];       // X^T [p][s] skewed
    __shared__ __align__(16) u16 BT[8768];       // B^T [n][s] skewed
    __shared__ __align__(16) float dts_s[128];
    __shared__ __align__(16) float lda_s[128];
    __shared__ __align__(16) float wend[128];
    __shared__ __align__(16) double cumd[128];

    const int blk = blockIdx.x;
    const int c = blk & 15, dbh = blk >> 4;
    const int h = dbh & 31, b = (dbh >> 5) & 3, dir = dbh >> 7;
    const int tid = threadIdx.x, w = tid >> 6, lane = tid & 63, lr = lane & 15, lq = lane >> 4;
    const int s0 = c * QC;
    u16* yo = dir ? y1 : y0;

    if (tid < 128) {   // inline dt2 / log-dA (was k_dt)
        int s = s0 + tid;
        int t = dir ? (L_ - 1 - s) : s;
        float draw = b2f(zx[(size_t)(b * L_ + t) * NPAD + (DIN + CONV_DIM) + dir * 32 + h]);
        float xb = draw + dt_bias[h];
        float dt2 = (xb > 20.f) ? xb : log1pf(__expf(xb));
        dts_s[tid] = dt2;
        lda_s[tid] = -__expf(A_log[h]) * dt2;
    }
    {   // stage Cs, Bs (bf16 row-major), BT, XT (transposed, skewed)
        int sl0 = tid >> 3, ng = (tid & 7) * 8;
        #pragma unroll
        for (int it = 0; it < 4; it++) {
            int sl = sl0 + it * 32;
            int s = s0 + sl;
            int t = dir ? (L_ - 1 - s) : s;
            size_t row = (size_t)b * L_ + t;
            const u16* bcr = BCb + row * 128;
            uint4 cv = *(const uint4*)(bcr + 64 + ng);
            *(uint4*)&ab[sl * 72 + ng] = cv;
            uint4 pb = *(const uint4*)(bcr + ng);
            *(uint4*)&ab[9216 + sl * 72 + ng] = pb;
            u16 bh[8] = {(u16)(pb.x & 0xffffu), (u16)(pb.x >> 16), (u16)(pb.y & 0xffffu), (u16)(pb.y >> 16),
                         (u16)(pb.z & 0xffffu), (u16)(pb.z >> 16), (u16)(pb.w & 0xffffu), (u16)(pb.w >> 16)};
            #pragma unroll
            for (int i = 0; i < 8; i++) BT[(ng + i) * 136 + ng + sl] = bh[i];   // skew = ng
            uint4 xv = *(const uint4*)(xs + row * DIN + h * 64 + ng);
            u16 xh[8] = {(u16)(xv.x & 0xffffu), (u16)(xv.x >> 16), (u16)(xv.y & 0xffffu), (u16)(xv.y >> 16),
                         (u16)(xv.z & 0xffffu), (u16)(xv.z >> 16), (u16)(xv.w & 0xffffu), (u16)(xv.w >> 16)};
            #pragma unroll
            for (int i = 0; i < 8; i++) XT[(ng + i) * 136 + ng + sl] = xh[i];   // skew = ng
        }
    }
    __syncthreads();
    if (w == 0) {   // double-precision inclusive prefix of log-dA (wave 0)
        double v0 = (double)lda_s[lane];
        double v1 = (double)lda_s[64 + lane];
        #pragma unroll
        for (int o = 1; o < 64; o <<= 1) {
            double t0 = __shfl_up(v0, o);
            double t1 = __shfl_up(v1, o);
            if (lane >= o) { v0 += t0; v1 += t1; }
        }
        double tot0 = __shfl(v0, 63);
        cumd[lane] = v0;
        cumd[64 + lane] = tot0 + v1;
    }
    // G = C * B^T  (wave w owns t-rows [w*32, w*32+32))
    bf16x8 af[2][2];
    #pragma unroll
    for (int ti = 0; ti < 2; ti++)
        #pragma unroll
        for (int ks = 0; ks < 2; ks++)
            af[ti][ks] = *(const bf16x8*)&ab[(w * 32 + ti * 16 + lr) * 72 + ks * 32 + lq * 8];
    f32x4 accg[2][8];
    #pragma unroll
    for (int ti = 0; ti < 2; ti++)
        #pragma unroll
        for (int si = 0; si < 8; si++) accg[ti][si] = (f32x4){0.f, 0.f, 0.f, 0.f};
    #pragma unroll
    for (int si = 0; si < 8; si++)
        #pragma unroll
        for (int ks = 0; ks < 2; ks++) {
            bf16x8 bf = *(const bf16x8*)&ab[9216 + (si * 16 + lr) * 72 + ks * 32 + lq * 8];
            accg[0][si] = __builtin_amdgcn_mfma_f32_16x16x32_bf16(af[0][ks], bf, accg[0][si], 0, 0, 0);
            accg[1][si] = __builtin_amdgcn_mfma_f32_16x16x32_bf16(af[1][ks], bf, accg[1][si], 0, 0, 0);
        }
    __syncthreads();   // all G frag reads done; cumd ready
    // wend[s] = exp(cum[127]-cum[s])*dt[s]  (for chunk-state); visible after next barrier
    if (tid < 128) wend[tid] = __expf((float)(cumd[127] - cumd[tid])) * dts_s[tid];
    // S = M .* G  -> overlay into ab (skewed stride 136)
    {
        double cumt_d[8];
        #pragma unroll
        for (int ti = 0; ti < 2; ti++)
            #pragma unroll
            for (int r = 0; r < 4; r++) cumt_d[ti * 4 + r] = cumd[w * 32 + ti * 16 + lq * 4 + r];
        double cums_d[8]; float dts_l[8];
        #pragma unroll
        for (int si = 0; si < 8; si++) { cums_d[si] = cumd[si * 16 + lr]; dts_l[si] = dts_s[si * 16 + lr]; }
        #pragma unroll
        for (int ti = 0; ti < 2; ti++)
            #pragma unroll
            for (int si = 0; si < 8; si++)
                #pragma unroll
                for (int r = 0; r < 4; r++) {
                    int t_l = w * 32 + ti * 16 + lq * 4 + r;
                    int s_l = si * 16 + lr;
                    float v = 0.f;
                    if (s_l <= t_l)
                        v = __expf((float)(cumt_d[ti * 4 + r] - cums_d[si])) * dts_l[si] * accg[ti][si][r];
                    ab[xts(t_l, s_l)] = f2b(v);
                }
    }
    __syncthreads();
    // Y_intra = S * X^T
    f32x4 acc[2][4];
    #pragma unroll
    for (int ti = 0; ti < 2; ti++)
        #pragma unroll
        for (int pj = 0; pj < 4; pj++) acc[ti][pj] = (f32x4){0.f, 0.f, 0.f, 0.f};
    #pragma unroll
    for (int ks = 0; ks < 4; ks++) {
        bf16x8 a0 = *(const bf16x8*)&ab[xts(w * 32 + lr, ks * 32 + lq * 8)];
        bf16x8 a1 = *(const bf16x8*)&ab[xts(w * 32 + 16 + lr, ks * 32 + lq * 8)];
        #pragma unroll
        for (int pj = 0; pj < 4; pj++) {
            bf16x8 bf = *(const bf16x8*)&XT[xts(pj * 16 + lr, ks * 32 + lq * 8)];
            acc[0][pj] = __builtin_amdgcn_mfma_f32_16x16x32_bf16(a0, bf, acc[0][pj], 0, 0, 0);
            acc[1][pj] = __builtin_amdgcn_mfma_f32_16x16x32_bf16(a1, bf, acc[1][pj], 0, 0, 0);
        }
    }
    #pragma unroll
    for (int ti = 0; ti < 2; ti++)
        #pragma unroll
        for (int pj = 0; pj < 4; pj++)
            #pragma unroll
            for (int r = 0; r < 4; r++) {
                int t_l = w * 32 + ti * 16 + lq * 4 + r;
                int s = s0 + t_l;
                int t = dir ? (L_ - 1 - s) : s;
                yo[((size_t)b * L_ + t) * DIN + h * 64 + pj * 16 + lr] = f2b(acc[ti][pj][r]);
            }
    // chunk state S_c[p][n] = sum_s wend[s]*x[s][p]*B[s][n]  (wave w owns p-rows [w*16,w*16+16))
    f32x4 accs[4];
    #pragma unroll
    for (int nj = 0; nj < 4; nj++) accs[nj] = (f32x4){0.f, 0.f, 0.f, 0.f};
    #pragma unroll
    for (int ks = 0; ks < 4; ks++) {
        uint4 xv = *(const uint4*)&XT[xts(w * 16 + lr, ks * 32 + lq * 8)];
        float xf[8]; unpack8(xv, xf);
        float4 w0 = *(const float4*)&wend[ks * 32 + lq * 8];
        float4 w1 = *(const float4*)&wend[ks * 32 + lq * 8 + 4];
        float fs[8] = {xf[0]*w0.x, xf[1]*w0.y, xf[2]*w0.z, xf[3]*w0.w,
                       xf[4]*w1.x, xf[5]*w1.y, xf[6]*w1.z, xf[7]*w1.w};
        bf16x8 a = __builtin_bit_cast(bf16x8, pack8(fs));
        #pragma unroll
        for (int nj = 0; nj < 4; nj++) {
            bf16x8 bb = *(const bf16x8*)&BT[xts(nj * 16 + lr, ks * 32 + lq * 8)];
            accs[nj] = __builtin_amdgcn_mfma_f32_16x16x32_bf16(a, bb, accs[nj], 0, 0, 0);
        }
    }
    #pragma unroll
    for (int nj = 0; nj < 4; nj++)
        #pragma unroll
        for (int r = 0; r < 4; r++) {
            int p = w * 16 + lq * 4 + r, n = nj * 16 + lr;
            scb[(size_t)blk * 4096 + p * 64 + n] = f2b(accs[nj][r]);
        }
    if (tid < 128) wout[dbh * 2048 + s0 + tid] = __expf((float)cumd[tid]);
    if (tid == 0)  decay[blk] = __expf((float)cumd[127]);
}

// k_carry: sequential over 16 chunks: y_full = Y_intra + exp(cum)*C*h ; shift; h = decay*h + S_c
__global__ __launch_bounds__(256) void k_carry(const u16* __restrict__ BCb, const float* __restrict__ wout,
                                               const float* __restrict__ decay, const u16* __restrict__ scb,
                                               u16* __restrict__ y0, u16* __restrict__ y1) {
    __shared__ __align__(16) float hsh[64 * 68];     // h[p][n], row stride 68
    __shared__ __align__(16) u16 Csc[128 * 72];      // exp(cum[s])*C[s][n]
    __shared__ __align__(16) u16 ybs[128 * 72];      // y_full rows (bf16)
    __shared__ __align__(16) u16 prevu[72];
    const int dbh = blockIdx.x;
    const int h = dbh & 31, b = (dbh >> 5) & 3, dir = dbh >> 7;
    const int tid = threadIdx.x, w = tid >> 6, lane = tid & 63, lr = lane & 15, lq = lane >> 4;
    u16* yo = dir ? y1 : y0;

    for (int i = tid; i < 64 * 68; i += 256) hsh[i] = 0.f;
    if (tid < 72) prevu[tid] = 0;
    __syncthreads();
    const int sl0 = tid >> 3, ng = (tid & 7) * 8;
    for (int c = 0; c < NCH; c++) {
        #pragma unroll
        for (int it = 0; it < 4; it++) {
            int sl = sl0 + it * 32;
            int s = c * QC + sl;
            int t = dir ? (L_ - 1 - s) : s;
            const u16* bcr = BCb + ((size_t)b * L_ + t) * 128 + 64 + ng;
            float sc = wout[dbh * 2048 + s];
            uint4 cv = *(const uint4*)bcr;
            float cf[8]; unpack8(cv, cf);
            float f[8] = {cf[0]*sc, cf[1]*sc, cf[2]*sc, cf[3]*sc, cf[4]*sc, cf[5]*sc, cf[6]*sc, cf[7]*sc};
            *(uint4*)&Csc[sl * 72 + ng] = pack8(f);
        }
        bf16x8 hb[4][2];
        #pragma unroll
        for (int pj = 0; pj < 4; pj++)
            #pragma unroll
            for (int ks = 0; ks < 2; ks++) {
                const float* hp = &hsh[(pj * 16 + lr) * 68 + ks * 32 + lq * 8];
                float4 a0 = *(const float4*)hp;
                float4 a1 = *(const float4*)(hp + 4);
                float f[8] = {a0.x, a0.y, a0.z, a0.w, a1.x, a1.y, a1.z, a1.w};
                hb[pj][ks] = __builtin_bit_cast(bf16x8, pack8(f));
            }
        __syncthreads();
        f32x4 acc[2][4];
        #pragma unroll
        for (int ti = 0; ti < 2; ti++)
            #pragma unroll
            for (int pj = 0; pj < 4; pj++) acc[ti][pj] = (f32x4){0.f, 0.f, 0.f, 0.f};
        #pragma unroll
        for (int ks = 0; ks < 2; ks++) {
            bf16x8 a0 = *(const bf16x8*)&Csc[(w * 32 + lr) * 72 + ks * 32 + lq * 8];
            bf16x8 a1 = *(const bf16x8*)&Csc[(w * 32 + 16 + lr) * 72 + ks * 32 + lq * 8];
            #pragma unroll
            for (int pj = 0; pj < 4; pj++) {
                acc[0][pj] = __builtin_amdgcn_mfma_f32_16x16x32_bf16(a0, hb[pj][ks], acc[0][pj], 0, 0, 0);
                acc[1][pj] = __builtin_amdgcn_mfma_f32_16x16x32_bf16(a1, hb[pj][ks], acc[1][pj], 0, 0, 0);
            }
        }
        #pragma unroll
        for (int ti = 0; ti < 2; ti++)
            #pragma unroll
            for (int pj = 0; pj < 4; pj++)
                #pragma unroll
                for (int r = 0; r < 4; r++) {
                    int t_l = w * 32 + ti * 16 + lq * 4 + r;
                    int s = c * QC + t_l;
                    int t = dir ? (L_ - 1 - s) : s;
                    float yv = acc[ti][pj][r] + b2f(yo[((size_t)b * L_ + t) * DIN + h * 64 + pj * 16 + lr]);
                    ybs[t_l * 72 + pj * 16 + lr] = f2b(yv);
                }
        {   // h = decay*h + S_c
            float dk = decay[dbh * 16 + c];
            const u16* sg = scb + ((size_t)(dbh * 16 + c)) * 4096 + tid * 16;
            uint4 q0 = *(const uint4*)sg;
            uint4 q1 = *(const uint4*)(sg + 8);
            float sf[16]; unpack8(q0, sf); unpack8(q1, sf + 8);
            int p = (tid * 16) >> 6, n0 = (tid * 16) & 63;
            float* hp = &hsh[p * 68 + n0];
            #pragma unroll
            for (int i = 0; i < 16; i++) hp[i] = dk * hp[i] + sf[i];
        }
        __syncthreads();
        #pragma unroll
        for (int it = 0; it < 4; it++) {
            int sl = sl0 + it * 32;
            int s = c * QC + sl;
            int t = dir ? (L_ - 1 - s) : s;
            const u16* src = (sl == 0) ? (prevu + ng) : &ybs[(sl - 1) * 72 + ng];
            *(uint4*)&yo[((size_t)b * L_ + t) * DIN + h * 64 + ng] = *(const uint4*)src;
        }
        __syncthreads();
        if (tid < 8) *(uint4*)&prevu[tid * 8] = *(const uint4*)&ybs[127 * 72 + tid * 8];
    }
}

// ---------- gate + RMSNorm -> bf16 ----------
__global__ __launch_bounds__(256) void k_gate(const u16* __restrict__ xs, const u16* __restrict__ zx,
                                              const u16* __restrict__ y0, const u16* __restrict__ y1,
                                              const float* __restrict__ Dd,
                                              const float* __restrict__ nw, u16* __restrict__ yn) {
    int row = blockIdx.x, tid = threadIdx.x;
    __shared__ float red[4];
    size_t base = (size_t)row * DIN;
    uint4 xv = ((const uint4*)(xs + base))[tid];
    uint4 zv = ((const uint4*)(zx + (size_t)row * NPAD))[tid];
    uint4 a0 = ((const uint4*)(y0 + base))[tid];
    uint4 a1 = ((const uint4*)(y1 + base))[tid];
    float sD = Dd[(size_t)row * 32 + (tid >> 3)];    // head = (tid*8)>>6
    float xf[8], zf[8], f0[8], f1[8];
    unpack8(xv, xf); unpack8(zv, zf); unpack8(a0, f0); unpack8(a1, f1);
    int d0 = tid * 8;
    float g[8]; float ss = 0.f;
    #pragma unroll
    for (int i = 0; i < 8; i++) {
        float yv = f0[i] + f1[i] + xf[i] * sD;
        float z = zf[i];
        float gg = yv * (z / (1.f + __expf(-z)));
        g[i] = gg; ss += gg * gg;
    }
    for (int o = 32; o; o >>= 1) ss += __shfl_down(ss, o);
    if ((tid & 63) == 0) red[tid >> 6] = ss;
    __syncthreads();
    float tot = red[0] + red[1] + red[2] + red[3];
    float r = rsqrtf(tot * (1.f / DIN) + EPS);
    float o8[8];
    #pragma unroll
    for (int i = 0; i < 8; i++) o8[i] = g[i] * r * nw[d0 + i];
    ((uint4*)(yn + base))[tid] = pack8(o8);
}

// ---------- workspace layout (bytes) ----------
#define OFF_U     ((size_t)0)                       // BL*DM bf16 (dead after GEMM1)
#define OFF_WIN   ((size_t)16777216)                // NPAD*DM bf16
#define OFF_WOUT  ((size_t)25690112)                // DM*DIN bf16
#define OFF_ZX    ((size_t)29884416)                // BL*NPAD bf16
#define OFF_XS    ((size_t)101187584)               // BL*DIN bf16
#define OFF_BC    ((size_t)134742016)               // BL*128 bf16 = 2 MB
#define OFF_DTA   ((size_t)138936320)               // (unused since R6 — dt folded into k_chunk)
#define OFF_Y0    ((size_t)143130624)               // BL*DIN bf16
#define OFF_Y1    ((size_t)176685056)               // BL*DIN bf16
#define OFF_YN    ((size_t)210239488)               // BL*DIN bf16 (gate out); scb aliases earlier
// aliases inside dead OFF_U region (all used only after GEMM1):
#define OFF_WO2   OFF_U                             // 256*2048 f32 = 2 MB
#define OFF_DEC   (OFF_U + 2097152)                 // 4096 f32
#define OFF_FCB   (OFF_U + 2113536)                 // NH*DIN bf16 = 128 KB
#define OFF_DD    (OFF_U + 2244608)                 // BL*32 f32 = 1 MB
#define OFF_SCB   OFF_YN                            // 4096*4096 bf16 = 33.5 MB
// total 243,793,920 bytes

extern "C" void kernel_launch(void* const* d_in, const int* in_sizes, int n_in,
                              void* d_out, int out_size, void* d_ws, size_t ws_size,
                              hipStream_t stream) {
    const float* x       = (const float*)d_in[0];
    const float* ln_g    = (const float*)d_in[1];
    const float* ln_b    = (const float*)d_in[2];
    const float* W_in    = (const float*)d_in[3];
    const float* conv_w  = (const float*)d_in[4];
    const float* conv_b  = (const float*)d_in[5];
    const float* dt_bias = (const float*)d_in[6];
    const float* A_log   = (const float*)d_in[7];
    const float* fc_D_w  = (const float*)d_in[8];
    const float* Dv      = (const float*)d_in[9];
    const float* norm_w  = (const float*)d_in[10];
    const float* W_out   = (const float*)d_in[11];

    char* ws = (char*)d_ws;
    u16*   u_bf  = (u16*)(ws + OFF_U);
    u16*   winb  = (u16*)(ws + OFF_WIN);
    u16*   woutb = (u16*)(ws + OFF_WOUT);
    u16*   zx    = (u16*)(ws + OFF_ZX);
    u16*   xs    = (u16*)(ws + OFF_XS);
    u16*   BCb   = (u16*)(ws + OFF_BC);
    u16*   y0b   = (u16*)(ws + OFF_Y0);
    u16*   y1b   = (u16*)(ws + OFF_Y1);
    u16*   ynb   = (u16*)(ws + OFF_YN);
    float* wo2   = (float*)(ws + OFF_WO2);
    float* dec   = (float*)(ws + OFF_DEC);
    u16*   fcb   = (u16*)(ws + OFF_FCB);
    float* Dd    = (float*)(ws + OFF_DD);
    u16*   scb   = (u16*)(ws + OFF_SCB);

    k_cvt_win <<<(NPAD * DM) / 256, 256, 0, stream>>>(W_in, winb);
    k_cvt_wout<<<(DM * DIN) / 256, 256, 0, stream>>>(W_out, woutb);
    k_ln      <<<BL, 256, 0, stream>>>(x, ln_g, ln_b, u_bf);
    k_gemm_bt <<<dim3(NPAD / 128, BL / 128), 256, 0, stream>>>(u_bf, winb, BL, NPAD, DM, 1, zx, NPAD, nullptr, nullptr);
    k_cvt_fcd <<<(NH * DIN) / 256, 256, 0, stream>>>(fc_D_w, fcb);   // after GEMM1 (aliases u_bf region)
    k_conv    <<<dim3(CONV_DIM / 64, L_ / 256, B_), 256, 0, stream>>>(zx, conv_w, conv_b, xs, BCb);
    k_dproj   <<<BL / 32, 256, 0, stream>>>(xs, fcb, Dv, Dd);
    k_chunk   <<<4096, 256, 0, stream>>>(xs, BCb, zx, dt_bias, A_log, y0b, y1b, wo2, dec, scb);
    k_carry   <<<256, 256, 0, stream>>>(BCb, wo2, dec, scb, y0b, y1b);
    k_gate    <<<BL, 256, 0, stream>>>(xs, zx, y0b, y1b, Dd, norm_w, ynb);
    k_gemm_bt <<<dim3(DM / 128, BL / 128), 256, 0, stream>>>(ynb, woutb, BL, DM, DIN, 0, nullptr, DM, (float*)d_out, x);
}

// Round 7
// 518.196 us; speedup vs baseline: 3.8682x; 1.0074x over previous
//
#include <hip/hip_runtime.h>
#include <stdint.h>

// ---- problem constants ----
#define B_   4
#define L_   2048
#define DM   1024
#define DIN  2048
#define NH   32
#define HD   64
#define DSTATE 64
#define DCONV  7
#define CONV_DIM 2176            // DIN + 2*DSTATE
#define DPROJ 4288               // 2*DIN + 2*DSTATE + 2*NH
#define NPAD 4352                // DPROJ padded to 128
#define BL   8192                // B_*L_
#define EPS  1e-5f
#define QC   128                 // scan chunk length
#define NCH  16                  // chunks per sequence

typedef unsigned short u16;
typedef unsigned int   u32;
typedef __bf16 bf16x8 __attribute__((ext_vector_type(8)));
typedef float  f32x4  __attribute__((ext_vector_type(4)));

__device__ __forceinline__ float b2f(u32 b) { return __uint_as_float(b << 16); }
__device__ __forceinline__ u16 f2b(float f) {
    u32 u = __float_as_uint(f);
    u32 r = (u + 0x7fffu + ((u >> 16) & 1u)) >> 16;
    return (u16)r;
}
__device__ __forceinline__ void unpack8(uint4 v, float* f) {
    f[0] = b2f(v.x & 0xffffu); f[1] = b2f(v.x >> 16);
    f[2] = b2f(v.y & 0xffffu); f[3] = b2f(v.y >> 16);
    f[4] = b2f(v.z & 0xffffu); f[5] = b2f(v.z >> 16);
    f[6] = b2f(v.w & 0xffffu); f[7] = b2f(v.w >> 16);
}
__device__ __forceinline__ uint4 pack8(const float* f) {
    uint4 v;
    v.x = (u32)f2b(f[0]) | ((u32)f2b(f[1]) << 16);
    v.y = (u32)f2b(f[2]) | ((u32)f2b(f[3]) << 16);
    v.z = (u32)f2b(f[4]) | ((u32)f2b(f[5]) << 16);
    v.w = (u32)f2b(f[6]) | ((u32)f2b(f[7]) << 16);
    return v;
}
// skewed LDS index for transposed tiles: row-stride 136 u16 + 8-u16 skew per 8 rows.
__device__ __forceinline__ int xts(int p, int s) { return p * 136 + ((p >> 3) << 3) + s; }
// async global->LDS, 16B per lane; lds base must be wave-uniform (HW adds lane*16)
__device__ __forceinline__ void gload_lds16(const u16* g, u16* l) {
    __builtin_amdgcn_global_load_lds((const __attribute__((address_space(1))) void*)g,
                                     (__attribute__((address_space(3))) void*)l, 16, 0, 0);
}

// ---------- weight conversion ----------
__global__ __launch_bounds__(256) void k_cvt_win(const float* __restrict__ W, u16* __restrict__ Wb) {
    int idx = blockIdx.x * 256 + threadIdx.x;      // over NPAD*DM
    int n = idx >> 10;                              // DM = 1024
    float v = (n < DPROJ) ? W[(size_t)n * DM + (idx & 1023)] : 0.f;
    Wb[idx] = f2b(v);
}
__global__ __launch_bounds__(256) void k_cvt_wout(const float* __restrict__ W, u16* __restrict__ Wb) {
    int idx = blockIdx.x * 256 + threadIdx.x;      // over DM*DIN
    Wb[idx] = f2b(W[idx]);
}
__global__ __launch_bounds__(256) void k_cvt_fcd(const float* __restrict__ W, u16* __restrict__ Wb) {
    int idx = blockIdx.x * 256 + threadIdx.x;      // over NH*DIN
    Wb[idx] = f2b(W[idx]);
}

// ---------- layernorm -> bf16 ----------
__global__ __launch_bounds__(256) void k_ln(const float* __restrict__ x, const float* __restrict__ g,
                                            const float* __restrict__ be, u16* __restrict__ u) {
    int row = blockIdx.x, tid = threadIdx.x;
    const float4* xr = (const float4*)(x + (size_t)row * DM);
    float4 v = xr[tid];
    float s1 = v.x + v.y + v.z + v.w;
    float s2 = v.x * v.x + v.y * v.y + v.z * v.z + v.w * v.w;
    for (int o = 32; o; o >>= 1) { s1 += __shfl_down(s1, o); s2 += __shfl_down(s2, o); }
    __shared__ float ls1[4], ls2[4];
    int w = tid >> 6;
    if ((tid & 63) == 0) { ls1[w] = s1; ls2[w] = s2; }
    __syncthreads();
    float t1 = ls1[0] + ls1[1] + ls1[2] + ls1[3];
    float t2 = ls2[0] + ls2[1] + ls2[2] + ls2[3];
    float mu = t1 * (1.f / DM);
    float var = t2 * (1.f / DM) - mu * mu;
    float rs = rsqrtf(var + EPS);
    float4 gv = ((const float4*)g)[tid];
    float4 bv = ((const float4*)be)[tid];
    float o0 = (v.x - mu) * rs * gv.x + bv.x;
    float o1 = (v.y - mu) * rs * gv.y + bv.y;
    float o2 = (v.z - mu) * rs * gv.z + bv.z;
    float o3 = (v.w - mu) * rs * gv.w + bv.w;
    uint2 p;
    p.x = (u32)f2b(o0) | ((u32)f2b(o1) << 16);
    p.y = (u32)f2b(o2) | ((u32)f2b(o3) << 16);
    ((uint2*)(u + (size_t)row * DM))[tid] = p;
}

// ---------- bf16 MFMA GEMM, C[m,n] = sum_k A[m,k]*B[n,k]  (B^T layout) ----------
__global__ __launch_bounds__(256) void k_gemm_bt(const u16* __restrict__ A, const u16* __restrict__ Bw,
                                                 int M, int N, int K, int out_bf16,
                                                 u16* __restrict__ obf, int ldo,
                                                 float* __restrict__ ofp, const float* __restrict__ res) {
    __shared__ __align__(16) u16 As[128 * 64];
    __shared__ __align__(16) u16 Bs[128 * 64];
    int tid = threadIdx.x;
    int m0 = blockIdx.y * 128, n0 = blockIdx.x * 128;
    int w = tid >> 6, lane = tid & 63;
    int wm = (w >> 1) * 64, wn = (w & 1) * 64;
    int lr = lane & 15, lq = lane >> 4;

    f32x4 acc[4][4];
    #pragma unroll
    for (int i = 0; i < 4; i++)
        #pragma unroll
        for (int j = 0; j < 4; j++) acc[i][j] = (f32x4){0.f, 0.f, 0.f, 0.f};

    for (int kt = 0; kt < K; kt += 64) {
        #pragma unroll
        for (int it = 0; it < 4; it++) {
            int s_idx = it * 256 + tid;
            int row = s_idx >> 3;
            int kcg = (s_idx & 7) ^ (row & 7);            // swizzled source chunk
            u16* lbase_a = &As[(it * 256 + w * 64) * 8];  // wave-uniform
            u16* lbase_b = &Bs[(it * 256 + w * 64) * 8];
            gload_lds16(A + (size_t)(m0 + row) * K + kt + kcg * 8, lbase_a);
            gload_lds16(Bw + (size_t)(n0 + row) * K + kt + kcg * 8, lbase_b);
        }
        __syncthreads();
        #pragma unroll
        for (int kk = 0; kk < 2; kk++) {
            bf16x8 af[4], bfr[4];
            #pragma unroll
            for (int i = 0; i < 4; i++) {
                int row = wm + 16 * i + lr;
                af[i] = *(const bf16x8*)&As[row * 64 + (((kk * 4 + lq)) ^ (row & 7)) * 8];
            }
            #pragma unroll
            for (int j = 0; j < 4; j++) {
                int row = wn + 16 * j + lr;
                bfr[j] = *(const bf16x8*)&Bs[row * 64 + (((kk * 4 + lq)) ^ (row & 7)) * 8];
            }
            #pragma unroll
            for (int i = 0; i < 4; i++)
                #pragma unroll
                for (int j = 0; j < 4; j++)
                    acc[i][j] = __builtin_amdgcn_mfma_f32_16x16x32_bf16(af[i], bfr[j], acc[i][j], 0, 0, 0);
        }
        __syncthreads();
    }
    #pragma unroll
    for (int i = 0; i < 4; i++) {
        #pragma unroll
        for (int j = 0; j < 4; j++) {
            #pragma unroll
            for (int rr = 0; rr < 4; rr++) {
                int m = m0 + wm + 16 * i + lq * 4 + rr;
                int n = n0 + wn + 16 * j + lr;
                float v = acc[i][j][rr];
                if (out_bf16) obf[(size_t)m * ldo + n] = f2b(v);
                else          ofp[(size_t)m * ldo + n] = v + res[(size_t)m * ldo + n];
            }
        }
    }
}

// ---------- D-projection GEMM: Dd[m][h] = dot(xs[m,:], fc_D_w[h,:]) + Dv[h] ----------
__global__ __launch_bounds__(256) void k_dproj(const u16* __restrict__ xs, const u16* __restrict__ fcb,
                                               const float* __restrict__ Dv, float* __restrict__ Dd) {
    __shared__ __align__(16) u16 As[32 * 72];
    __shared__ __align__(16) u16 Bs[32 * 72];
    int tid = threadIdx.x;
    int m0 = blockIdx.x * 32;
    int w = tid >> 6, lane = tid & 63, lr = lane & 15, lq = lane >> 4;
    int mt = (w & 1) * 16, nt = (w >> 1) * 16;
    int r = tid >> 3, kc = tid & 7;
    f32x4 acc = (f32x4){0.f, 0.f, 0.f, 0.f};
    for (int kt = 0; kt < DIN; kt += 64) {
        *(uint4*)&As[r * 72 + kc * 8] = *(const uint4*)(xs + (size_t)(m0 + r) * DIN + kt + kc * 8);
        *(uint4*)&Bs[r * 72 + kc * 8] = *(const uint4*)(fcb + (size_t)r * DIN + kt + kc * 8);
        __syncthreads();
        #pragma unroll
        for (int ks = 0; ks < 2; ks++) {
            bf16x8 a = *(const bf16x8*)&As[(mt + lr) * 72 + ks * 32 + lq * 8];
            bf16x8 b = *(const bf16x8*)&Bs[(nt + lr) * 72 + ks * 32 + lq * 8];
            acc = __builtin_amdgcn_mfma_f32_16x16x32_bf16(a, b, acc, 0, 0, 0);
        }
        __syncthreads();
    }
    #pragma unroll
    for (int rr = 0; rr < 4; rr++) {
        int m = m0 + mt + lq * 4 + rr;
        int n = nt + lr;
        Dd[(size_t)m * 32 + n] = acc[rr] + Dv[n];
    }
}

// ---------- depthwise conv7 (same-pad) + bias + SiLU, split xs / BC(bf16) ----------
__global__ __launch_bounds__(256) void k_conv(const u16* __restrict__ zx, const float* __restrict__ cw,
                                              const float* __restrict__ cb, u16* __restrict__ xs,
                                              u16* __restrict__ BCb) {
    __shared__ u16 sh[262 * 64];
    int c0 = blockIdx.x * 64, t0 = blockIdx.y * 256, b = blockIdx.z;
    int tid = threadIdx.x;
    int c = tid & 63, tg = tid >> 6;
    for (int it = 0; it < 66; it++) {
        int r = it * 4 + tg;
        if (r < 262) {
            int t = t0 + r - 3;
            u16 v = 0;
            if (t >= 0 && t < L_) v = zx[(size_t)(b * L_ + t) * NPAD + DIN + c0 + c];
            sh[r * 64 + c] = v;
        }
    }
    float wgt[7];
    #pragma unroll
    for (int k = 0; k < 7; k++) wgt[k] = cw[(c0 + c) * 7 + k];
    float bias = cb[c0 + c];
    __syncthreads();
    int cg = c0 + c;
    for (int tt = 0; tt < 64; tt++) {
        int tl = tt * 4 + tg;
        float a = bias;
        #pragma unroll
        for (int k = 0; k < 7; k++) a += b2f(sh[(tl + k) * 64 + c]) * wgt[k];
        float v = a / (1.f + __expf(-a));   // silu
        size_t row = (size_t)b * L_ + (t0 + tl);
        if (cg < DIN) xs[row * DIN + cg] = f2b(v);
        else          BCb[row * 128 + (cg - DIN)] = f2b(v);   // B at [0,64), C at [64,128), bf16
    }
}

// ======================================================================
// Chunked SSD scan (intra-chunk + chunk-state + inline dt): block = (dir,b,h,chunk).
// ======================================================================
__global__ __launch_bounds__(256) void k_chunk(const u16* __restrict__ xs, const u16* __restrict__ BCb,
                                               const u16* __restrict__ zx, const float* __restrict__ dt_bias,
                                               const float* __restrict__ A_log, u16* __restrict__ y0,
                                               u16* __restrict__ y1, float* __restrict__ wout,
                                               float* __restrict__ decay, u16* __restrict__ scb) {
    __shared__ __align__(16) u16 ab[18432];      // Cs [0,9216) stride 72, Bs [9216,18432); S overlays (skewed 136)
    __shared__ __align__(16) u16 XT[8768];       // X^T [p][s] skewed
    __shared__ __align__(16) u16 BT[8768];       // B^T [n][s] skewed
    __shared__ __align__(16) float dts_s[128];
    __shared__ __align__(16) float lda_s[128];
    __shared__ __align__(16) float wend[128];
    __shared__ __align__(16) double cumd[128];

    const int blk = blockIdx.x;
    const int c = blk & 15, dbh = blk >> 4;
    const int h = dbh & 31, b = (dbh >> 5) & 3, dir = dbh >> 7;
    const int tid = threadIdx.x, w = tid >> 6, lane = tid & 63, lr = lane & 15, lq = lane >> 4;
    const int s0 = c * QC;
    u16* yo = dir ? y1 : y0;

    if (tid < 128) {   // inline dt2 / log-dA
        int s = s0 + tid;
        int t = dir ? (L_ - 1 - s) : s;
        float draw = b2f(zx[(size_t)(b * L_ + t) * NPAD + (DIN + CONV_DIM) + dir * 32 + h]);
        float xb = draw + dt_bias[h];
        float dt2 = (xb > 20.f) ? xb : log1pf(__expf(xb));
        dts_s[tid] = dt2;
        lda_s[tid] = -__expf(A_log[h]) * dt2;
    }
    {   // stage Cs, Bs (bf16 row-major), BT, XT (transposed, skewed)
        int sl0 = tid >> 3, ng = (tid & 7) * 8;
        #pragma unroll
        for (int it = 0; it < 4; it++) {
            int sl = sl0 + it * 32;
            int s = s0 + sl;
            int t = dir ? (L_ - 1 - s) : s;
            size_t row = (size_t)b * L_ + t;
            const u16* bcr = BCb + row * 128;
            uint4 cv = *(const uint4*)(bcr + 64 + ng);
            *(uint4*)&ab[sl * 72 + ng] = cv;
            uint4 pb = *(const uint4*)(bcr + ng);
            *(uint4*)&ab[9216 + sl * 72 + ng] = pb;
            u16 bh[8] = {(u16)(pb.x & 0xffffu), (u16)(pb.x >> 16), (u16)(pb.y & 0xffffu), (u16)(pb.y >> 16),
                         (u16)(pb.z & 0xffffu), (u16)(pb.z >> 16), (u16)(pb.w & 0xffffu), (u16)(pb.w >> 16)};
            #pragma unroll
            for (int i = 0; i < 8; i++) BT[(ng + i) * 136 + ng + sl] = bh[i];   // skew = ng
            uint4 xv = *(const uint4*)(xs + row * DIN + h * 64 + ng);
            u16 xh[8] = {(u16)(xv.x & 0xffffu), (u16)(xv.x >> 16), (u16)(xv.y & 0xffffu), (u16)(xv.y >> 16),
                         (u16)(xv.z & 0xffffu), (u16)(xv.z >> 16), (u16)(xv.w & 0xffffu), (u16)(xv.w >> 16)};
            #pragma unroll
            for (int i = 0; i < 8; i++) XT[(ng + i) * 136 + ng + sl] = xh[i];   // skew = ng
        }
    }
    __syncthreads();
    if (w == 0) {   // double-precision inclusive prefix of log-dA (wave 0)
        double v0 = (double)lda_s[lane];
        double v1 = (double)lda_s[64 + lane];
        #pragma unroll
        for (int o = 1; o < 64; o <<= 1) {
            double t0 = __shfl_up(v0, o);
            double t1 = __shfl_up(v1, o);
            if (lane >= o) { v0 += t0; v1 += t1; }
        }
        double tot0 = __shfl(v0, 63);
        cumd[lane] = v0;
        cumd[64 + lane] = tot0 + v1;
    }
    // G = C * B^T  (wave w owns t-rows [w*32, w*32+32))
    bf16x8 af[2][2];
    #pragma unroll
    for (int ti = 0; ti < 2; ti++)
        #pragma unroll
        for (int ks = 0; ks < 2; ks++)
            af[ti][ks] = *(const bf16x8*)&ab[(w * 32 + ti * 16 + lr) * 72 + ks * 32 + lq * 8];
    f32x4 accg[2][8];
    #pragma unroll
    for (int ti = 0; ti < 2; ti++)
        #pragma unroll
        for (int si = 0; si < 8; si++) accg[ti][si] = (f32x4){0.f, 0.f, 0.f, 0.f};
    #pragma unroll
    for (int si = 0; si < 8; si++)
        #pragma unroll
        for (int ks = 0; ks < 2; ks++) {
            bf16x8 bf = *(const bf16x8*)&ab[9216 + (si * 16 + lr) * 72 + ks * 32 + lq * 8];
            accg[0][si] = __builtin_amdgcn_mfma_f32_16x16x32_bf16(af[0][ks], bf, accg[0][si], 0, 0, 0);
            accg[1][si] = __builtin_amdgcn_mfma_f32_16x16x32_bf16(af[1][ks], bf, accg[1][si], 0, 0, 0);
        }
    __syncthreads();   // all G frag reads done; cumd ready
    // wend[s] = exp(cum[127]-cum[s])*dt[s]  (for chunk-state); visible after next barrier
    if (tid < 128) wend[tid] = __expf((float)(cumd[127] - cumd[tid])) * dts_s[tid];
    // S = M .* G  -> overlay into ab (skewed stride 136)
    {
        double cumt_d[8];
        #pragma unroll
        for (int ti = 0; ti < 2; ti++)
            #pragma unroll
            for (int r = 0; r < 4; r++) cumt_d[ti * 4 + r] = cumd[w * 32 + ti * 16 + lq * 4 + r];
        double cums_d[8]; float dts_l[8];
        #pragma unroll
        for (int si = 0; si < 8; si++) { cums_d[si] = cumd[si * 16 + lr]; dts_l[si] = dts_s[si * 16 + lr]; }
        #pragma unroll
        for (int ti = 0; ti < 2; ti++)
            #pragma unroll
            for (int si = 0; si < 8; si++)
                #pragma unroll
                for (int r = 0; r < 4; r++) {
                    int t_l = w * 32 + ti * 16 + lq * 4 + r;
                    int s_l = si * 16 + lr;
                    float v = 0.f;
                    if (s_l <= t_l)
                        v = __expf((float)(cumt_d[ti * 4 + r] - cums_d[si])) * dts_l[si] * accg[ti][si][r];
                    ab[xts(t_l, s_l)] = f2b(v);
                }
    }
    __syncthreads();
    // Y_intra = S * X^T
    f32x4 acc[2][4];
    #pragma unroll
    for (int ti = 0; ti < 2; ti++)
        #pragma unroll
        for (int pj = 0; pj < 4; pj++) acc[ti][pj] = (f32x4){0.f, 0.f, 0.f, 0.f};
    #pragma unroll
    for (int ks = 0; ks < 4; ks++) {
        bf16x8 a0 = *(const bf16x8*)&ab[xts(w * 32 + lr, ks * 32 + lq * 8)];
        bf16x8 a1 = *(const bf16x8*)&ab[xts(w * 32 + 16 + lr, ks * 32 + lq * 8)];
        #pragma unroll
        for (int pj = 0; pj < 4; pj++) {
            bf16x8 bf = *(const bf16x8*)&XT[xts(pj * 16 + lr, ks * 32 + lq * 8)];
            acc[0][pj] = __builtin_amdgcn_mfma_f32_16x16x32_bf16(a0, bf, acc[0][pj], 0, 0, 0);
            acc[1][pj] = __builtin_amdgcn_mfma_f32_16x16x32_bf16(a1, bf, acc[1][pj], 0, 0, 0);
        }
    }
    #pragma unroll
    for (int ti = 0; ti < 2; ti++)
        #pragma unroll
        for (int pj = 0; pj < 4; pj++)
            #pragma unroll
            for (int r = 0; r < 4; r++) {
                int t_l = w * 32 + ti * 16 + lq * 4 + r;
                int s = s0 + t_l;
                int t = dir ? (L_ - 1 - s) : s;
                yo[((size_t)b * L_ + t) * DIN + h * 64 + pj * 16 + lr] = f2b(acc[ti][pj][r]);
            }
    // chunk state S_c[p][n] = sum_s wend[s]*x[s][p]*B[s][n]
    f32x4 accs[4];
    #pragma unroll
    for (int nj = 0; nj < 4; nj++) accs[nj] = (f32x4){0.f, 0.f, 0.f, 0.f};
    #pragma unroll
    for (int ks = 0; ks < 4; ks++) {
        uint4 xv = *(const uint4*)&XT[xts(w * 16 + lr, ks * 32 + lq * 8)];
        float xf[8]; unpack8(xv, xf);
        float4 w0 = *(const float4*)&wend[ks * 32 + lq * 8];
        float4 w1 = *(const float4*)&wend[ks * 32 + lq * 8 + 4];
        float fs[8] = {xf[0]*w0.x, xf[1]*w0.y, xf[2]*w0.z, xf[3]*w0.w,
                       xf[4]*w1.x, xf[5]*w1.y, xf[6]*w1.z, xf[7]*w1.w};
        bf16x8 a = __builtin_bit_cast(bf16x8, pack8(fs));
        #pragma unroll
        for (int nj = 0; nj < 4; nj++) {
            bf16x8 bb = *(const bf16x8*)&BT[xts(nj * 16 + lr, ks * 32 + lq * 8)];
            accs[nj] = __builtin_amdgcn_mfma_f32_16x16x32_bf16(a, bb, accs[nj], 0, 0, 0);
        }
    }
    #pragma unroll
    for (int nj = 0; nj < 4; nj++)
        #pragma unroll
        for (int r = 0; r < 4; r++) {
            int p = w * 16 + lq * 4 + r, n = nj * 16 + lr;
            scb[(size_t)blk * 4096 + p * 64 + n] = f2b(accs[nj][r]);
        }
    if (tid < 128) wout[dbh * 2048 + s0 + tid] = __expf((float)cumd[tid]);
    if (tid == 0)  decay[blk] = __expf((float)cumd[127]);
}

// ---------- h-state scan (barrier-free): rewrites scb slots in place with h_in per chunk ----------
// thread owns 16 (p,n) elements; the recurrence h = decay*h + S_c is elementwise.
__global__ __launch_bounds__(256) void k_hscan(const float* __restrict__ decay, u16* __restrict__ scb) {
    int dbh = blockIdx.x, tid = threadIdx.x;
    u16* base = scb + (size_t)dbh * 16 * 4096 + tid * 16;
    float hcur[16];
    #pragma unroll
    for (int i = 0; i < 16; i++) hcur[i] = 0.f;
    for (int c = 0; c < NCH; c++) {
        u16* sg = base + (size_t)c * 4096;
        uint4 q0 = *(const uint4*)sg;
        uint4 q1 = *(const uint4*)(sg + 8);
        float sf[16]; unpack8(q0, sf); unpack8(q1, sf + 8);
        *(uint4*)sg       = pack8(hcur);       // h entering chunk c
        *(uint4*)(sg + 8) = pack8(hcur + 8);
        float dk = decay[dbh * 16 + c];
        #pragma unroll
        for (int i = 0; i < 16; i++) hcur[i] = dk * hcur[i] + sf[i];
    }
}

// ---------- inter-chunk contribution (parallel): y += (wout.*C) * h_in^T ----------
__global__ __launch_bounds__(256) void k_inter(const u16* __restrict__ BCb, const float* __restrict__ wout,
                                               const u16* __restrict__ hin, u16* __restrict__ y0,
                                               u16* __restrict__ y1) {
    __shared__ __align__(16) u16 Csc[128 * 72];      // wout[s]*C[s][n]
    __shared__ __align__(16) u16 hs[64 * 72];        // h_in[p][n], padded
    const int blk = blockIdx.x;
    const int c = blk & 15, dbh = blk >> 4;
    const int h = dbh & 31, b = (dbh >> 5) & 3, dir = dbh >> 7;
    const int tid = threadIdx.x, w = tid >> 6, lane = tid & 63, lr = lane & 15, lq = lane >> 4;
    u16* yo = dir ? y1 : y0;

    {   // stage h_in (p-major 64x64 -> padded rows)
        int g = tid * 16, p = g >> 6, n = g & 63;
        const u16* hg = hin + (size_t)blk * 4096 + g;
        *(uint4*)&hs[p * 72 + n]     = *(const uint4*)hg;
        *(uint4*)&hs[p * 72 + n + 8] = *(const uint4*)(hg + 8);
    }
    const int sl0 = tid >> 3, ng = (tid & 7) * 8;
    #pragma unroll
    for (int it = 0; it < 4; it++) {
        int sl = sl0 + it * 32;
        int s = c * QC + sl;
        int t = dir ? (L_ - 1 - s) : s;
        const u16* bcr = BCb + ((size_t)b * L_ + t) * 128 + 64 + ng;
        float sc = wout[dbh * 2048 + s];
        uint4 cv = *(const uint4*)bcr;
        float cf[8]; unpack8(cv, cf);
        float f[8] = {cf[0]*sc, cf[1]*sc, cf[2]*sc, cf[3]*sc, cf[4]*sc, cf[5]*sc, cf[6]*sc, cf[7]*sc};
        *(uint4*)&Csc[sl * 72 + ng] = pack8(f);
    }
    __syncthreads();
    f32x4 acc[2][4];
    #pragma unroll
    for (int ti = 0; ti < 2; ti++)
        #pragma unroll
        for (int pj = 0; pj < 4; pj++) acc[ti][pj] = (f32x4){0.f, 0.f, 0.f, 0.f};
    #pragma unroll
    for (int ks = 0; ks < 2; ks++) {
        bf16x8 a0 = *(const bf16x8*)&Csc[(w * 32 + lr) * 72 + ks * 32 + lq * 8];
        bf16x8 a1 = *(const bf16x8*)&Csc[(w * 32 + 16 + lr) * 72 + ks * 32 + lq * 8];
        #pragma unroll
        for (int pj = 0; pj < 4; pj++) {
            bf16x8 bb = *(const bf16x8*)&hs[(pj * 16 + lr) * 72 + ks * 32 + lq * 8];
            acc[0][pj] = __builtin_amdgcn_mfma_f32_16x16x32_bf16(a0, bb, acc[0][pj], 0, 0, 0);
            acc[1][pj] = __builtin_amdgcn_mfma_f32_16x16x32_bf16(a1, bb, acc[1][pj], 0, 0, 0);
        }
    }
    #pragma unroll
    for (int ti = 0; ti < 2; ti++)
        #pragma unroll
        for (int pj = 0; pj < 4; pj++)
            #pragma unroll
            for (int r = 0; r < 4; r++) {
                int t_l = w * 32 + ti * 16 + lq * 4 + r;
                int s = c * QC + t_l;
                int t = dir ? (L_ - 1 - s) : s;
                u16* yp = yo + ((size_t)b * L_ + t) * DIN + h * 64 + pj * 16 + lr;
                *yp = f2b(acc[ti][pj][r] + b2f(*yp));    // RMW own rows only — no races
            }
}

// ---------- gate + RMSNorm -> bf16 (shift folded into the y reads) ----------
__global__ __launch_bounds__(256) void k_gate(const u16* __restrict__ xs, const u16* __restrict__ zx,
                                              const u16* __restrict__ y0, const u16* __restrict__ y1,
                                              const float* __restrict__ Dd,
                                              const float* __restrict__ nw, u16* __restrict__ yn) {
    int row = blockIdx.x, tid = threadIdx.x;
    int t = row & (L_ - 1);
    __shared__ float red[4];
    size_t base = (size_t)row * DIN;
    uint4 xv = ((const uint4*)(xs + base))[tid];
    uint4 zv = ((const uint4*)(zx + (size_t)row * NPAD))[tid];
    uint4 zero4 = {0u, 0u, 0u, 0u};
    uint4 a0 = (t > 0)      ? ((const uint4*)(y0 + base - DIN))[tid] : zero4;   // y_fwd[t-1]
    uint4 a1 = (t < L_ - 1) ? ((const uint4*)(y1 + base + DIN))[tid] : zero4;   // y_bwd[t+1]
    float sD = Dd[(size_t)row * 32 + (tid >> 3)];
    float xf[8], zf[8], f0[8], f1[8];
    unpack8(xv, xf); unpack8(zv, zf); unpack8(a0, f0); unpack8(a1, f1);
    int d0 = tid * 8;
    float g[8]; float ss = 0.f;
    #pragma unroll
    for (int i = 0; i < 8; i++) {
        float yv = f0[i] + f1[i] + xf[i] * sD;
        float z = zf[i];
        float gg = yv * (z / (1.f + __expf(-z)));
        g[i] = gg; ss += gg * gg;
    }
    for (int o = 32; o; o >>= 1) ss += __shfl_down(ss, o);
    if ((tid & 63) == 0) red[tid >> 6] = ss;
    __syncthreads();
    float tot = red[0] + red[1] + red[2] + red[3];
    float r = rsqrtf(tot * (1.f / DIN) + EPS);
    float o8[8];
    #pragma unroll
    for (int i = 0; i < 8; i++) o8[i] = g[i] * r * nw[d0 + i];
    ((uint4*)(yn + base))[tid] = pack8(o8);
}

// ---------- workspace layout (bytes) ----------
#define OFF_U     ((size_t)0)                       // BL*DM bf16 (dead after GEMM1)
#define OFF_WIN   ((size_t)16777216)                // NPAD*DM bf16
#define OFF_WOUT  ((size_t)25690112)                // DM*DIN bf16
#define OFF_ZX    ((size_t)29884416)                // BL*NPAD bf16
#define OFF_XS    ((size_t)101187584)               // BL*DIN bf16
#define OFF_BC    ((size_t)134742016)               // BL*128 bf16 = 2 MB
#define OFF_DTA   ((size_t)138936320)               // (unused)
#define OFF_Y0    ((size_t)143130624)               // BL*DIN bf16
#define OFF_Y1    ((size_t)176685056)               // BL*DIN bf16
#define OFF_YN    ((size_t)210239488)               // BL*DIN bf16 (gate out); scb/h_in aliases earlier
// aliases inside dead OFF_U region:
#define OFF_WO2   OFF_U                             // 256*2048 f32 = 2 MB
#define OFF_DEC   (OFF_U + 2097152)                 // 4096 f32
#define OFF_FCB   (OFF_U + 2113536)                 // NH*DIN bf16 = 128 KB
#define OFF_DD    (OFF_U + 2244608)                 // BL*32 f32 = 1 MB
#define OFF_SCB   OFF_YN                            // 4096*4096 bf16 = 33.5 MB (S_c -> h_in in place; dead before k_gate writes yn)
// total 243,793,920 bytes

extern "C" void kernel_launch(void* const* d_in, const int* in_sizes, int n_in,
                              void* d_out, int out_size, void* d_ws, size_t ws_size,
                              hipStream_t stream) {
    const float* x       = (const float*)d_in[0];
    const float* ln_g    = (const float*)d_in[1];
    const float* ln_b    = (const float*)d_in[2];
    const float* W_in    = (const float*)d_in[3];
    const float* conv_w  = (const float*)d_in[4];
    const float* conv_b  = (const float*)d_in[5];
    const float* dt_bias = (const float*)d_in[6];
    const float* A_log   = (const float*)d_in[7];
    const float* fc_D_w  = (const float*)d_in[8];
    const float* Dv      = (const float*)d_in[9];
    const float* norm_w  = (const float*)d_in[10];
    const float* W_out   = (const float*)d_in[11];

    char* ws = (char*)d_ws;
    u16*   u_bf  = (u16*)(ws + OFF_U);
    u16*   winb  = (u16*)(ws + OFF_WIN);
    u16*   woutb = (u16*)(ws + OFF_WOUT);
    u16*   zx    = (u16*)(ws + OFF_ZX);
    u16*   xs    = (u16*)(ws + OFF_XS);
    u16*   BCb   = (u16*)(ws + OFF_BC);
    u16*   y0b   = (u16*)(ws + OFF_Y0);
    u16*   y1b   = (u16*)(ws + OFF_Y1);
    u16*   ynb   = (u16*)(ws + OFF_YN);
    float* wo2   = (float*)(ws + OFF_WO2);
    float* dec   = (float*)(ws + OFF_DEC);
    u16*   fcb   = (u16*)(ws + OFF_FCB);
    float* Dd    = (float*)(ws + OFF_DD);
    u16*   scb   = (u16*)(ws + OFF_SCB);

    k_cvt_win <<<(NPAD * DM) / 256, 256, 0, stream>>>(W_in, winb);
    k_cvt_wout<<<(DM * DIN) / 256, 256, 0, stream>>>(W_out, woutb);
    k_ln      <<<BL, 256, 0, stream>>>(x, ln_g, ln_b, u_bf);
    k_gemm_bt <<<dim3(NPAD / 128, BL / 128), 256, 0, stream>>>(u_bf, winb, BL, NPAD, DM, 1, zx, NPAD, nullptr, nullptr);
    k_cvt_fcd <<<(NH * DIN) / 256, 256, 0, stream>>>(fc_D_w, fcb);
    k_conv    <<<dim3(CONV_DIM / 64, L_ / 256, B_), 256, 0, stream>>>(zx, conv_w, conv_b, xs, BCb);
    k_dproj   <<<BL / 32, 256, 0, stream>>>(xs, fcb, Dv, Dd);
    k_chunk   <<<4096, 256, 0, stream>>>(xs, BCb, zx, dt_bias, A_log, y0b, y1b, wo2, dec, scb);
    k_hscan   <<<256, 256, 0, stream>>>(dec, scb);
    k_inter   <<<4096, 256, 0, stream>>>(BCb, wo2, scb, y0b, y1b);
    k_gate    <<<BL, 256, 0, stream>>>(xs, zx, y0b, y1b, Dd, norm_w, ynb);
    k_gemm_bt <<<dim3(DM / 128, BL / 128), 256, 0, stream>>>(ynb, woutb, BL, DM, DIN, 0, nullptr, DM, (float*)d_out, x);
}